// Round 11
// baseline (213.959 us; speedup 1.0000x reference)
//
#include <hip/hip_runtime.h>
#include <cstdint>
#include <cstddef>

// ---------------------------------------------------------------------------
// Plant_Identifier CNN forward.
// R11: layer-1 BN stats computed ANALYTICALLY from input cross-correlations:
//      pad1/k2/225-out => every tap sums the full image; Sum y^2 expands into
//      w_t1*w_t2*C[ci,cj,dh,dw] with C = truncated correlations at shifts
//      {-1,0,1}^2. k_corr streams d once (42 corr + 3 sums, 16px/thread) and
//      also emits hi/lo bf16 records; conv1 = record loads + MFMA + sel-pool
//      ONLY (no stats epilogue, 14x14 grid — row/col 224 unused by pool).
// R10: sel-trick (sign(gamma) known pre-stats -> single pooled buffer).
// conv2/3: bf16 MFMA implicit-GEMM, fused stats + sel pool. fc1: zero-LDS
// MFMA K-split. All reductions deterministic (fixed-order two-stage).
// ---------------------------------------------------------------------------

typedef __attribute__((ext_vector_type(8))) short sh8_t;   // 8 x bf16
typedef __attribute__((ext_vector_type(4))) float f4_t;    // mfma acc
typedef unsigned short u16;
typedef unsigned int u32;

// workspace layout (float units)
#define WS_SEL1 ((size_t)0)          // sel1 bf16 [64,112,112,16] (6,422,528)
#define WS_X1   ((size_t)6422528)    // x1   bf16 [64,112,112,16] (6,422,528)
#define WS_X2   ((size_t)12845056)   // x2   bf16 [64,56,56,32]   (3,211,264)
#define WS_SEL2 ((size_t)16056320)   // sel2                       (3,211,264)
// rec bf16 [64,224,224,8] = 12,845,056 float slots, ALIASES [X1, X2, SEL2):
// written by k_corr, read by k_conv1; X1/X2/SEL2 are written strictly later.
#define WS_REC  WS_X1
#define WS_X3T  ((size_t)19267584)   // x3t  bf16 [64,64,28,28]   (1,605,632)
#define WS_SEL3 ((size_t)20873216)   // sel3 bf16 [64,28,28,64]   (1,605,632)
#define WS_WT1  ((size_t)22478848)   // 512
#define WS_WT2  ((size_t)22479360)   // 3,072
#define WS_WT3  ((size_t)22482432)   // 9,216
#define WS_CP   ((size_t)22491648)   // corr partials [45][12544] = 564,480
#define WS_P2   ((size_t)23056128)   // 32*2*12544 = 802,816
#define WS_P3   ((size_t)23858944)   // 64*2*3584  = 458,752
#define WS_PD   ((size_t)24317696)   // 4,096 (doubles region; pd45 + fin pd)
#define WS_ST   ((size_t)24321792)   // 224
#define WS_FCP  ((size_t)24322016)   // 917,504
#define WS_H1   ((size_t)25239520)   // 16,384
// total 25,255,904 floats = 101.0 MB

static __device__ __forceinline__ float4 ldg4(const float* p) {
  return *reinterpret_cast<const float4*>(p);
}
static __device__ __forceinline__ float bf2f(u16 u) {
  union { u32 i; float f; } c; c.i = ((u32)u) << 16; return c.f;
}
static __device__ __forceinline__ u16 f2bf(float f) {
  union { float f; u32 i; } c; c.f = f;
  const u32 x = c.i;
  return (u16)((x + 0x7fffu + ((x >> 16) & 1u)) >> 16);   // RNE
}

// ---------------- weight prep -----------------------------------------------
__global__ __launch_bounds__(256)
void k_prep_w(const float* __restrict__ w1, const float* __restrict__ w2,
              const float* __restrict__ w3, u16* __restrict__ wt1,
              u16* __restrict__ wt2, u16* __restrict__ wt3) {
  const int t = blockIdx.x * 256 + threadIdx.x;  // 25600 total
  if (t < 1024) {
    const int half = t >> 9;
    const int u = t & 511;
    const int co = u >> 5, k = u & 31;
    const int g = k >> 3, j = k & 7;
    const int kh = g >> 1, kw = g & 1;
    const int ci = (j < 4) ? j : j - 4;
    bool active = (j != 3) && (j != 7);
    if (half == 1) active = active && (j < 4);
    float val = 0.f;
    if (active) {
      const float w = w1[((co * 3 + ci) * 2 + kh) * 2 + kw];
      const u16 h = f2bf(w);
      val = (half == 0) ? bf2f(h) : (w - bf2f(h));
    }
    wt1[t] = f2bf(val);
  } else if (t < 7168) {  // wt2 [co32][kh3][kwp4][ci16], kw=3 zero-padded
    const int u = t - 1024;
    const int ci = u & 15, kwp = (u >> 4) & 3, kh = (u >> 6) % 3, co = u / 192;
    float v = 0.f;
    if (kwp < 3) v = w2[((co * 16 + ci) * 3 + kh) * 3 + kwp];
    wt2[u] = f2bf(v);
  } else {                // wt3 [co64][kh3][kw3][ci32]
    const int u = t - 7168;
    const int ci = u & 31, kw = (u >> 5) % 3, kh = (u / 96) % 3, co = u / 288;
    wt3[u] = f2bf(w3[((co * 32 + ci) * 3 + kh) * 3 + kw]);
  }
}

// ---------------- k_corr: correlations + channel sums + record emit ---------
// thread = 16 consecutive px of one row (4 chunks of 4). 784 blocks x 256 thr.
// acc[0..26]  : C[i,j,dh=1,dw]   idx = (i*3+j)*3 + (dw+1)
// acc[27..35] : C[i,j,dh=0,dw=1] idx = 27 + i*3+j
// acc[36..41] : C[i,j,0,0] i<=j  idx = 36 + i*(5-i)/2 + j
// acc[42..44] : S_ci
__global__ __launch_bounds__(256)
void k_corr(const float* __restrict__ d, u16* __restrict__ rec,
            float* __restrict__ cpart) {
  const int tid = blockIdx.x * 256 + threadIdx.x;   // 200,704 = 64*224*14
  const int n = tid / 3136;                          // 224*14
  const int rem = tid - n * 3136;
  const int ih = rem / 14, seg = rem - ih * 14;
  const int c0 = seg * 16;
  float acc[45];
  #pragma unroll
  for (int q = 0; q < 45; ++q) acc[q] = 0.f;
  const bool hasDown = (ih + 1 < 224);
  #pragma unroll
  for (int chunk = 0; chunk < 4; ++chunk) {
    const int c = c0 + chunk * 4;
    float r0[3][6], r1[3][6];
    #pragma unroll
    for (int ci = 0; ci < 3; ++ci) {
      const float* pr = d + ((size_t)(n * 3 + ci) * 224 + ih) * 224;
      const float4 v = ldg4(pr + c);
      r0[ci][1] = v.x; r0[ci][2] = v.y; r0[ci][3] = v.z; r0[ci][4] = v.w;
      r0[ci][0] = (c > 0) ? pr[c - 1] : 0.f;
      r0[ci][5] = (c + 4 < 224) ? pr[c + 4] : 0.f;
      if (hasDown) {
        const float4 w = ldg4(pr + 224 + c);
        r1[ci][1] = w.x; r1[ci][2] = w.y; r1[ci][3] = w.z; r1[ci][4] = w.w;
        r1[ci][0] = (c > 0) ? pr[224 + c - 1] : 0.f;
        r1[ci][5] = (c + 4 < 224) ? pr[224 + c + 4] : 0.f;
      } else {
        #pragma unroll
        for (int z = 0; z < 6; ++z) r1[ci][z] = 0.f;
      }
    }
    #pragma unroll
    for (int p = 0; p < 4; ++p) {
      float a[3];
      a[0] = r0[0][1 + p]; a[1] = r0[1][1 + p]; a[2] = r0[2][1 + p];
      acc[42] += a[0]; acc[43] += a[1]; acc[44] += a[2];
      acc[36] = fmaf(a[0], a[0], acc[36]);
      acc[37] = fmaf(a[0], a[1], acc[37]);
      acc[38] = fmaf(a[0], a[2], acc[38]);
      acc[39] = fmaf(a[1], a[1], acc[39]);
      acc[40] = fmaf(a[1], a[2], acc[40]);
      acc[41] = fmaf(a[2], a[2], acc[41]);
      #pragma unroll
      for (int i = 0; i < 3; ++i)
        #pragma unroll
        for (int j = 0; j < 3; ++j)
          acc[27 + i * 3 + j] = fmaf(a[i], r0[j][2 + p], acc[27 + i * 3 + j]);
      #pragma unroll
      for (int i = 0; i < 3; ++i)
        #pragma unroll
        for (int j = 0; j < 3; ++j)
          #pragma unroll
          for (int dwp = 0; dwp < 3; ++dwp)  // dwp = dw+1
            acc[(i * 3 + j) * 3 + dwp] =
                fmaf(a[i], r1[j][p + dwp], acc[(i * 3 + j) * 3 + dwp]);
    }
    // emit hi/lo records for pixels (ih, c..c+3)
    #pragma unroll
    for (int p = 0; p < 4; ++p) {
      const float v0 = r0[0][1 + p], v1 = r0[1][1 + p], v2 = r0[2][1 + p];
      const u16 h0 = f2bf(v0), h1 = f2bf(v1), h2 = f2bf(v2);
      int4 rr;
      rr.x = (u32)h0 | ((u32)h1 << 16);
      rr.y = (u32)h2;
      rr.z = (u32)f2bf(v0 - bf2f(h0)) | ((u32)f2bf(v1 - bf2f(h1)) << 16);
      rr.w = (u32)f2bf(v2 - bf2f(h2));
      *reinterpret_cast<int4*>(rec + (size_t)((n * 224 + ih) * 224 + c + p) * 8) = rr;
    }
  }
  // 16-lane group reduce
  #pragma unroll
  for (int m = 1; m < 16; m <<= 1)
    #pragma unroll
    for (int q = 0; q < 45; ++q) acc[q] += __shfl_xor(acc[q], m);
  if ((threadIdx.x & 15) == 0) {
    const int slot = blockIdx.x * 16 + (threadIdx.x >> 4);  // 12544
    #pragma unroll
    for (int q = 0; q < 45; ++q) cpart[q * 12544 + slot] = acc[q];
  }
}

// ------------- corr partials -> 45 doubles -----------------------------------
__global__ __launch_bounds__(256)
void k_corr_fin(const float* __restrict__ cpart, double* __restrict__ pd45) {
  const int q = blockIdx.x;  // 45
  const float* base = cpart + q * 12544;
  double a0 = 0, a1 = 0, a2 = 0, a3 = 0;
  for (int i = threadIdx.x * 4; i + 3 < 12544; i += 1024) {
    const float4 v = ldg4(base + i);
    a0 += v.x; a1 += v.y; a2 += v.z; a3 += v.w;
  }
  __shared__ double rs[256];
  rs[threadIdx.x] = (a0 + a1) + (a2 + a3);
  __syncthreads();
  for (int off = 128; off > 0; off >>= 1) {
    if (threadIdx.x < off) rs[threadIdx.x] += rs[threadIdx.x + off];
    __syncthreads();
  }
  if (threadIdx.x == 0) pd45[q] = rs[0];
}

// ------------- layer-1 stats: 144-term tap-pair combine (fp64) ---------------
__global__ __launch_bounds__(64)
void k_stats1(const double* __restrict__ pd45, const float* __restrict__ w1,
              const float* __restrict__ b1, const float* __restrict__ g1,
              const float* __restrict__ be1, float* __restrict__ scale,
              float* __restrict__ shift) {
  const int co = threadIdx.x;
  if (co >= 16) return;
  double w[3][2][2];
  for (int ci = 0; ci < 3; ++ci)
    for (int kh = 0; kh < 2; ++kh)
      for (int kw = 0; kw < 2; ++kw)
        w[ci][kh][kw] = (double)w1[((co * 3 + ci) * 2 + kh) * 2 + kw];
  double sum_s = 0.0;
  for (int ci = 0; ci < 3; ++ci)
    for (int kh = 0; kh < 2; ++kh)
      for (int kw = 0; kw < 2; ++kw)
        sum_s += w[ci][kh][kw] * pd45[42 + ci];
  double ss = 0.0;
  for (int i = 0; i < 3; ++i)
    for (int kh = 0; kh < 2; ++kh)
      for (int kw = 0; kw < 2; ++kw)
        for (int j = 0; j < 3; ++j)
          for (int kh2 = 0; kh2 < 2; ++kh2)
            for (int kw2 = 0; kw2 < 2; ++kw2) {
              int a = i, b2 = j, dh = kh2 - kh, dw = kw2 - kw;
              if (dh < 0 || (dh == 0 && dw < 0)) {
                const int tt = a; a = b2; b2 = tt; dh = -dh; dw = -dw;
              }
              double cv;
              if (dh == 1) cv = pd45[(a * 3 + b2) * 3 + dw + 1];
              else if (dw == 1) cv = pd45[27 + a * 3 + b2];
              else {
                const int lo = (a < b2) ? a : b2, hi = (a < b2) ? b2 : a;
                cv = pd45[36 + lo * (5 - lo) / 2 + hi];
              }
              ss += w[i][kh][kw] * w[j][kh2][kw2] * cv;
            }
  const double Npos = 3240000.0;  // 64*225*225
  const double b = (double)b1[co];
  const double mu = sum_s / Npos + b;
  const double E2 = (ss + 2.0 * b * sum_s) / Npos + b * b;
  const double var = E2 - mu * mu;
  const double rstd = 1.0 / sqrt(var + 1e-5);
  const double sc = (double)g1[co] * rstd;
  scale[co] = (float)sc;
  shift[co] = (float)((double)be1[co] - mu * sc);
}

// ---------------- conv1: record loads + MFMA + sel pool (no stats) ----------
// grid (14,14,64), 256 thr. 16x16 tile of the 224x224 pooled region.
__global__ __launch_bounds__(256)
void k_conv1(const u16* __restrict__ rec, const u16* __restrict__ wt1,
             const float* __restrict__ b1, const float* __restrict__ g1,
             u16* __restrict__ sel1) {
  const int bx = blockIdx.x, by = blockIdx.y, n = blockIdx.z;
  const int ow0 = bx * 16, oh0 = by * 16;
  const int t = threadIdx.x, lane = t & 63, wv = t >> 6;
  const int g = lane >> 4, li = lane & 15;
  const int kh = g >> 1, kw = g & 1;
  const sh8_t A1 = *reinterpret_cast<const sh8_t*>(wt1 + li * 32 + g * 8);
  const sh8_t A2 = *reinterpret_cast<const sh8_t*>(wt1 + 512 + li * 32 + g * 8);
  const int iw = ow0 + li + kw - 1;      // [-1, 223]
  const bool iwv = iw >= 0;
  f4_t acc[4];
  #pragma unroll
  for (int r = 0; r < 4; ++r) acc[r] = (f4_t)0.f;
  #pragma unroll
  for (int r = 0; r < 4; ++r) {
    const int ih = oh0 + wv * 4 + r + kh - 1;  // [-1, 223]
    sh8_t B = (sh8_t)(short)0;
    if (iwv && ih >= 0)
      B = *reinterpret_cast<const sh8_t*>(rec + (size_t)((n * 224 + ih) * 224 + iw) * 8);
    acc[r] = __builtin_amdgcn_mfma_f32_16x16x32_bf16(A1, B, acc[r], 0, 0, 0);
    acc[r] = __builtin_amdgcn_mfma_f32_16x16x32_bf16(A2, B, acc[r], 0, 0, 0);
  }
  const f4_t bias = *reinterpret_cast<const f4_t*>(b1 + 4 * g);
  const f4_t gam  = *reinterpret_cast<const f4_t*>(g1 + 4 * g);
  f4_t y[4];
  #pragma unroll
  for (int r = 0; r < 4; ++r) y[r] = acc[r] + bias;
  #pragma unroll
  for (int rp = 0; rp < 2; ++rp) {
    f4_t v;
    #pragma unroll
    for (int j = 0; j < 4; ++j) {
      const float a = y[2 * rp][j], b = y[2 * rp + 1][j];
      v[j] = (gam[j] >= 0.f) ? fmaxf(a, b) : fminf(a, b);
    }
    f4_t o;
    #pragma unroll
    for (int j = 0; j < 4; ++j) o[j] = __shfl_xor(v[j], 1);
    if ((li & 1) == 0) {
      u16 pk[4];
      #pragma unroll
      for (int j = 0; j < 4; ++j)
        pk[j] = f2bf((gam[j] >= 0.f) ? fmaxf(v[j], o[j]) : fminf(v[j], o[j]));
      const int po = 8 * by + 2 * wv + rp, qo = 8 * bx + (li >> 1);
      uint2 w;
      w.x = (u32)pk[0] | ((u32)pk[1] << 16);
      w.y = (u32)pk[2] | ((u32)pk[3] << 16);
      *reinterpret_cast<uint2*>(sel1 + ((size_t)((n * 112 + po) * 112 + qo)) * 16 + 4 * g) = w;
    }
  }
}

// ------------- BN finalize stage 1: parallel chunk reduce -------------------
__global__ __launch_bounds__(256)
void k_fin1(const float* __restrict__ part, int P, int chunk, int S,
            double* __restrict__ p2) {
  const int c = blockIdx.x, s = blockIdx.y;
  const int start = s * chunk;
  const int end = min(P, start + chunk);
  __shared__ double rs[256], rq[256];
  double accs[2];
  #pragma unroll
  for (int mom = 0; mom < 2; ++mom) {
    const float* base = part + (size_t)(c * 2 + mom) * P;
    double a0 = 0.0, a1 = 0.0, a2 = 0.0, a3 = 0.0;
    int i = start + threadIdx.x * 4;
    for (; i + 3 < end; i += 1024) {
      const float4 v = ldg4(base + i);
      a0 += v.x; a1 += v.y; a2 += v.z; a3 += v.w;
    }
    for (int j = i; j < end && j < i + 4; ++j) a0 += base[j];
    accs[mom] = (a0 + a1) + (a2 + a3);
  }
  rs[threadIdx.x] = accs[0]; rq[threadIdx.x] = accs[1];
  __syncthreads();
  for (int off = 128; off > 0; off >>= 1) {
    if (threadIdx.x < off) {
      rs[threadIdx.x] += rs[threadIdx.x + off];
      rq[threadIdx.x] += rq[threadIdx.x + off];
    }
    __syncthreads();
  }
  if (threadIdx.x == 0) {
    p2[(size_t)(c * 2 + 0) * S + s] = rs[0];
    p2[(size_t)(c * 2 + 1) * S + s] = rq[0];
  }
}

// ------------- BN finalize stage 2 ------------------------------------------
__global__ __launch_bounds__(64)
void k_fin2(const double* __restrict__ p2, int S, double count,
            const float* __restrict__ g, const float* __restrict__ bta,
            float* __restrict__ scale, float* __restrict__ shift) {
  const int c = blockIdx.x, t = threadIdx.x;
  double s = 0.0, sq = 0.0;
  if (t < S) {
    s  = p2[(size_t)(c * 2 + 0) * S + t];
    sq = p2[(size_t)(c * 2 + 1) * S + t];
  }
  #pragma unroll
  for (int m = 1; m < 64; m <<= 1) {
    s  += __shfl_xor(s, m);
    sq += __shfl_xor(sq, m);
  }
  if (t == 0) {
    const double mean = s / count;
    const double var  = sq / count - mean * mean;
    const double rstd = 1.0 / sqrt(var + 1e-5);
    const double sc = (double)g[c] * rstd;
    scale[c] = (float)sc;
    shift[c] = (float)((double)bta[c] - mean * sc);
  }
}

// ------------- bnrelu: x = relu(sc*sel + sh), NHWC ---------------------------
template<int CH, int P>
__global__ __launch_bounds__(256)
void k_bnrelu(const u16* __restrict__ sel, const float* __restrict__ scale,
              const float* __restrict__ shift, u16* __restrict__ xout) {
  constexpr int G = CH / 8;
  const int idx = blockIdx.x * 256 + threadIdx.x;
  const int cg = idx & (G - 1);
  int rest = idx / G;
  const int qo = rest % P; rest /= P;
  const int po = rest % P;
  const int n = rest / P;
  const size_t base = ((size_t)((n * P + po) * P + qo)) * CH + cg * 8;
  const int4 vs = *reinterpret_cast<const int4*>(sel + base);
  const u32* a = reinterpret_cast<const u32*>(&vs);
  u16 o[8];
  #pragma unroll
  for (int j = 0; j < 8; ++j) {
    const int c = cg * 8 + j;
    const float sc = scale[c], sh = shift[c];
    const u16 raw = (u16)(a[j >> 1] >> ((j & 1) * 16));
    o[j] = f2bf(fmaxf(fmaf(bf2f(raw), sc, sh), 0.f));
  }
  u32 pk[4];
  #pragma unroll
  for (int k = 0; k < 4; ++k) pk[k] = (u32)o[2 * k] | ((u32)o[2 * k + 1] << 16);
  *reinterpret_cast<int4*>(xout + base) = make_int4(pk[0], pk[1], pk[2], pk[3]);
}

// ------------- conv2: bf16 MFMA + stats + sel pool ---------------------------
__global__ __launch_bounds__(256)
void k_conv2(const u16* __restrict__ x1, const u16* __restrict__ wt2,
             const float* __restrict__ b2, const float* __restrict__ g2,
             u16* __restrict__ sel2, float* __restrict__ part) {
  const int ow0 = blockIdx.x * 16, oh0 = blockIdx.y * 16, n = blockIdx.z;
  const int t = threadIdx.x, lane = t & 63, wv = t >> 6;
  const int g = lane >> 4, li = lane & 15;
  __shared__ __align__(16) unsigned char tile[18 * 640];
  for (int idx = t; idx < 720; idx += 256) {
    const int rr = idx / 40, rem = idx - rr * 40, p = rem >> 1, c = rem & 1;
    const int ih = oh0 - 1 + rr, iw = ow0 - 1 + p;
    int4 v = make_int4(0, 0, 0, 0);
    if ((unsigned)ih < 112u && (unsigned)iw < 112u)
      v = *reinterpret_cast<const int4*>(x1 + ((size_t)((n * 112 + ih) * 112 + iw) * 16 + c * 8));
    *reinterpret_cast<int4*>(tile + ((rr * 640 + p * 32 + c * 16) ^ (((p >> 2) & 1) << 4))) = v;
  }
  sh8_t W[2][3][2];
  #pragma unroll
  for (int cot = 0; cot < 2; ++cot)
    #pragma unroll
    for (int kh = 0; kh < 3; ++kh)
      #pragma unroll
      for (int m = 0; m < 2; ++m)
        W[cot][kh][m] = *reinterpret_cast<const sh8_t*>(
            wt2 + ((cot * 16 + li) * 192 + kh * 64 + m * 32 + g * 8));
  f4_t acc[4][2];
  #pragma unroll
  for (int r = 0; r < 4; ++r) { acc[r][0] = (f4_t)0.f; acc[r][1] = (f4_t)0.f; }
  __syncthreads();
  const int rowb = 4 * wv;
  #pragma unroll
  for (int ihr = 0; ihr < 6; ++ihr) {
    const int row = rowb + ihr;
    #pragma unroll
    for (int m = 0; m < 2; ++m) {
      const int p = li + 2 * m + (g >> 1);
      const sh8_t B = *reinterpret_cast<const sh8_t*>(
          tile + ((row * 640 + p * 32 + (g & 1) * 16) ^ (((p >> 2) & 1) << 4)));
      #pragma unroll
      for (int kh = 0; kh < 3; ++kh) {
        const int r = ihr - kh;
        if (r >= 0 && r < 4) {
          acc[r][0] = __builtin_amdgcn_mfma_f32_16x16x32_bf16(W[0][kh][m], B, acc[r][0], 0, 0, 0);
          acc[r][1] = __builtin_amdgcn_mfma_f32_16x16x32_bf16(W[1][kh][m], B, acc[r][1], 0, 0, 0);
        }
      }
    }
  }
  f4_t bias[2], gam[2], ssum[2], ssq[2];
  bias[0] = *reinterpret_cast<const f4_t*>(b2 + 4 * g);
  bias[1] = *reinterpret_cast<const f4_t*>(b2 + 16 + 4 * g);
  gam[0]  = *reinterpret_cast<const f4_t*>(g2 + 4 * g);
  gam[1]  = *reinterpret_cast<const f4_t*>(g2 + 16 + 4 * g);
  ssum[0] = (f4_t)0.f; ssum[1] = (f4_t)0.f; ssq[0] = (f4_t)0.f; ssq[1] = (f4_t)0.f;
  #pragma unroll
  for (int r = 0; r < 4; ++r)
    #pragma unroll
    for (int cot = 0; cot < 2; ++cot) {
      acc[r][cot] += bias[cot];
      ssum[cot] += acc[r][cot];
      ssq[cot] += acc[r][cot] * acc[r][cot];
    }
  #pragma unroll
  for (int msk = 1; msk < 16; msk <<= 1)
    #pragma unroll
    for (int cot = 0; cot < 2; ++cot)
      #pragma unroll
      for (int j = 0; j < 4; ++j) {
        ssum[cot][j] += __shfl_xor(ssum[cot][j], msk);
        ssq[cot][j]  += __shfl_xor(ssq[cot][j], msk);
      }
  if (li == 0) {
    const int slot = (((n * 7 + (int)blockIdx.y) * 7 + (int)blockIdx.x)) * 4 + wv;  // 12544
    #pragma unroll
    for (int cot = 0; cot < 2; ++cot)
      #pragma unroll
      for (int j = 0; j < 4; ++j) {
        const int co = cot * 16 + 4 * g + j;
        part[(size_t)(co * 2 + 0) * 12544 + slot] = ssum[cot][j];
        part[(size_t)(co * 2 + 1) * 12544 + slot] = ssq[cot][j];
      }
  }
  const int pob = 8 * (int)blockIdx.y + 2 * wv;
  const int qo = 8 * (int)blockIdx.x + (li >> 1);
  #pragma unroll
  for (int rp = 0; rp < 2; ++rp)
    #pragma unroll
    for (int cot = 0; cot < 2; ++cot) {
      f4_t v;
      #pragma unroll
      for (int j = 0; j < 4; ++j) {
        const float a = acc[2 * rp][cot][j], b = acc[2 * rp + 1][cot][j];
        v[j] = (gam[cot][j] >= 0.f) ? fmaxf(a, b) : fminf(a, b);
      }
      f4_t o;
      #pragma unroll
      for (int j = 0; j < 4; ++j) o[j] = __shfl_xor(v[j], 1);
      if ((li & 1) == 0) {
        u16 pk[4];
        #pragma unroll
        for (int j = 0; j < 4; ++j)
          pk[j] = f2bf((gam[cot][j] >= 0.f) ? fmaxf(v[j], o[j]) : fminf(v[j], o[j]));
        const size_t off = ((size_t)((n * 56 + pob + rp) * 56 + qo)) * 32 + cot * 16 + 4 * g;
        uint2 w;
        w.x = (u32)pk[0] | ((u32)pk[1] << 16);
        w.y = (u32)pk[2] | ((u32)pk[3] << 16);
        *reinterpret_cast<uint2*>(sel2 + off) = w;
      }
    }
}

// ------------- conv3: bf16 MFMA + stats + sel pool ---------------------------
__global__ __launch_bounds__(256)
void k_conv3(const u16* __restrict__ x2, const u16* __restrict__ wt3,
             const float* __restrict__ b3, const float* __restrict__ g3,
             u16* __restrict__ sel3, float* __restrict__ part) {
  const int ow0 = blockIdx.x * 16, oh0 = blockIdx.y * 8, n = blockIdx.z;
  const int t = threadIdx.x, lane = t & 63, wv = t >> 6;
  const int rh = wv & 1, ch = wv >> 1;
  const int g = lane >> 4, li = lane & 15;
  __shared__ __align__(16) unsigned char tile[10 * 1152];
  for (int idx = t; idx < 720; idx += 256) {
    const int rr = idx / 72, rem = idx - rr * 72, p = rem >> 2, c = rem & 3;
    const int ih = oh0 - 1 + rr, iw = ow0 - 1 + p;
    int4 v = make_int4(0, 0, 0, 0);
    if ((unsigned)ih < 56u && (unsigned)iw < 56u)
      v = *reinterpret_cast<const int4*>(x2 + ((size_t)((n * 56 + ih) * 56 + iw) * 32 + c * 8));
    *reinterpret_cast<int4*>(tile + ((rr * 1152 + p * 64 + c * 16) ^ (((p >> 1) & 3) << 4))) = v;
  }
  sh8_t W[2][3][3];
  #pragma unroll
  for (int c2 = 0; c2 < 2; ++c2)
    #pragma unroll
    for (int kh = 0; kh < 3; ++kh)
      #pragma unroll
      for (int kw = 0; kw < 3; ++kw)
        W[c2][kh][kw] = *reinterpret_cast<const sh8_t*>(
            wt3 + ((size_t)(ch * 32 + c2 * 16 + li) * 288 + (kh * 3 + kw) * 32 + g * 8));
  f4_t acc[4][2];
  #pragma unroll
  for (int r = 0; r < 4; ++r) { acc[r][0] = (f4_t)0.f; acc[r][1] = (f4_t)0.f; }
  __syncthreads();
  const int rowb = 4 * rh;
  #pragma unroll
  for (int ihr = 0; ihr < 6; ++ihr) {
    const int row = rowb + ihr;
    #pragma unroll
    for (int kw = 0; kw < 3; ++kw) {
      const int p = li + kw;
      const sh8_t B = *reinterpret_cast<const sh8_t*>(
          tile + ((row * 1152 + p * 64 + g * 16) ^ (((p >> 1) & 3) << 4)));
      #pragma unroll
      for (int kh = 0; kh < 3; ++kh) {
        const int r = ihr - kh;
        if (r >= 0 && r < 4) {
          acc[r][0] = __builtin_amdgcn_mfma_f32_16x16x32_bf16(W[0][kh][kw], B, acc[r][0], 0, 0, 0);
          acc[r][1] = __builtin_amdgcn_mfma_f32_16x16x32_bf16(W[1][kh][kw], B, acc[r][1], 0, 0, 0);
        }
      }
    }
  }
  const int ow = ow0 + li;
  const bool valid = ow < 56;
  f4_t bias[2], gam[2], ssum[2], ssq[2];
  bias[0] = *reinterpret_cast<const f4_t*>(b3 + ch * 32 + 4 * g);
  bias[1] = *reinterpret_cast<const f4_t*>(b3 + ch * 32 + 16 + 4 * g);
  gam[0]  = *reinterpret_cast<const f4_t*>(g3 + ch * 32 + 4 * g);
  gam[1]  = *reinterpret_cast<const f4_t*>(g3 + ch * 32 + 16 + 4 * g);
  ssum[0] = (f4_t)0.f; ssum[1] = (f4_t)0.f; ssq[0] = (f4_t)0.f; ssq[1] = (f4_t)0.f;
  #pragma unroll
  for (int r = 0; r < 4; ++r)
    #pragma unroll
    for (int c2 = 0; c2 < 2; ++c2) {
      acc[r][c2] += bias[c2];
      if (valid) {
        ssum[c2] += acc[r][c2];
        ssq[c2] += acc[r][c2] * acc[r][c2];
      }
    }
  #pragma unroll
  for (int msk = 1; msk < 16; msk <<= 1)
    #pragma unroll
    for (int c2 = 0; c2 < 2; ++c2)
      #pragma unroll
      for (int j = 0; j < 4; ++j) {
        ssum[c2][j] += __shfl_xor(ssum[c2][j], msk);
        ssq[c2][j]  += __shfl_xor(ssq[c2][j], msk);
      }
  if (li == 0) {
    const int slot = (((n * 7 + (int)blockIdx.y) * 4 + (int)blockIdx.x)) * 2 + rh;  // 3584
    #pragma unroll
    for (int c2 = 0; c2 < 2; ++c2)
      #pragma unroll
      for (int j = 0; j < 4; ++j) {
        const int co = ch * 32 + c2 * 16 + 4 * g + j;
        part[(size_t)(co * 2 + 0) * 3584 + slot] = ssum[c2][j];
        part[(size_t)(co * 2 + 1) * 3584 + slot] = ssq[c2][j];
      }
  }
  const int pob = 4 * (int)blockIdx.y + 2 * rh;
  const int qo = 8 * (int)blockIdx.x + (li >> 1);
  #pragma unroll
  for (int rp = 0; rp < 2; ++rp)
    #pragma unroll
    for (int c2 = 0; c2 < 2; ++c2) {
      f4_t v;
      #pragma unroll
      for (int j = 0; j < 4; ++j) {
        const float a = acc[2 * rp][c2][j], b = acc[2 * rp + 1][c2][j];
        v[j] = (gam[c2][j] >= 0.f) ? fmaxf(a, b) : fminf(a, b);
      }
      f4_t o;
      #pragma unroll
      for (int j = 0; j < 4; ++j) o[j] = __shfl_xor(v[j], 1);
      if (((li & 1) == 0) && (ow + 1 < 56)) {
        u16 pk[4];
        #pragma unroll
        for (int j = 0; j < 4; ++j)
          pk[j] = f2bf((gam[c2][j] >= 0.f) ? fmaxf(v[j], o[j]) : fminf(v[j], o[j]));
        const size_t off = ((size_t)((n * 28 + pob + rp) * 28 + qo)) * 64 + ch * 32 + c2 * 16 + 4 * g;
        uint2 w;
        w.x = (u32)pk[0] | ((u32)pk[1] << 16);
        w.y = (u32)pk[2] | ((u32)pk[3] << 16);
        *reinterpret_cast<uint2*>(sel3 + off) = w;
      }
    }
}

// ------------- bnrelu3 + NHWC->NCHW transpose for fc1 -----------------------
__global__ __launch_bounds__(256)
void k_bnrelu3t(const u16* __restrict__ sel3, const float* __restrict__ scale,
                const float* __restrict__ shift, u16* __restrict__ x3t) {
  const int n = blockIdx.y;
  const int c = threadIdx.x & 63, pq = threadIdx.x >> 6;
  const int po = blockIdx.x * 4 + pq;
  const float sc = scale[c], sh = shift[c];
  const size_t row0 = ((size_t)(n * 28 + po)) * 28 * 64 + c;
  #pragma unroll
  for (int q4 = 0; q4 < 7; ++q4) {
    u16 pk[4];
    #pragma unroll
    for (int i = 0; i < 4; ++i) {
      const int qo = q4 * 4 + i;
      const u16 raw = sel3[row0 + (size_t)qo * 64];
      pk[i] = f2bf(fmaxf(fmaf(bf2f(raw), sc, sh), 0.f));
    }
    uint2 w;
    w.x = (u32)pk[0] | ((u32)pk[1] << 16);
    w.y = (u32)pk[2] | ((u32)pk[3] << 16);
    *reinterpret_cast<uint2*>(x3t + (((size_t)(n * 64 + c) * 28 + po) * 28 + q4 * 4)) = w;
  }
}

// ------------- fc1: zero-LDS MFMA K-split GEMM (56 splits x 896 k) ----------
__global__ __launch_bounds__(256)
void k_fc1(const u16* __restrict__ x3t, const float* __restrict__ w,
           float* __restrict__ partial) {
  const int kc = blockIdx.x, nt = blockIdx.y;
  const int t = threadIdx.x, lane = t & 63, wv = t >> 6;
  const int g = lane >> 4, li = lane & 15;
  const int n0 = nt * 64 + wv * 16;
  const float* wrow = w + (size_t)(n0 + li) * 50176 + kc * 896;
  const u16* xbase = x3t + kc * 896;
  f4_t acc[4];
  #pragma unroll
  for (int mf = 0; mf < 4; ++mf) acc[mf] = (f4_t)0.f;
  #pragma unroll 4
  for (int ks = 0; ks < 28; ++ks) {
    const int kb = ks * 32 + g * 8;
    const float4 wa = ldg4(wrow + kb);
    const float4 wb = ldg4(wrow + kb + 4);
    float wf[8] = {wa.x, wa.y, wa.z, wa.w, wb.x, wb.y, wb.z, wb.w};
    sh8_t hi, lo;
    #pragma unroll
    for (int j = 0; j < 8; ++j) {
      const u16 h = f2bf(wf[j]);
      hi[j] = (short)h;
      lo[j] = (short)f2bf(wf[j] - bf2f(h));
    }
    #pragma unroll
    for (int mf = 0; mf < 4; ++mf) {
      const sh8_t B = *reinterpret_cast<const sh8_t*>(
          xbase + (size_t)(mf * 16 + li) * 50176 + kb);
      acc[mf] = __builtin_amdgcn_mfma_f32_16x16x32_bf16(hi, B, acc[mf], 0, 0, 0);
      acc[mf] = __builtin_amdgcn_mfma_f32_16x16x32_bf16(lo, B, acc[mf], 0, 0, 0);
    }
  }
  float* pb = partial + (size_t)kc * 16384;
  #pragma unroll
  for (int mf = 0; mf < 4; ++mf)
    #pragma unroll
    for (int j = 0; j < 4; ++j)
      pb[(size_t)(n0 + 4 * g + j) * 64 + mf * 16 + li] = acc[mf][j];
}

__global__ __launch_bounds__(256)
void k_fc1_reduce(const float* __restrict__ partial, const float* __restrict__ b1f,
                  float* __restrict__ h1) {
  const int idx = blockIdx.x * 256 + threadIdx.x;  // 16384
  const int nn = idx >> 6, m = idx & 63;
  float a[8];
  #pragma unroll
  for (int u = 0; u < 8; ++u) a[u] = 0.f;
  #pragma unroll
  for (int k = 0; k < 56; k += 8)
    #pragma unroll
    for (int u = 0; u < 8; ++u)
      a[u] += partial[(size_t)(k + u) * 16384 + idx];
  const float s = b1f[nn] + (((a[0] + a[1]) + (a[2] + a[3])) +
                             ((a[4] + a[5]) + (a[6] + a[7])));
  h1[(size_t)m * 256 + nn] = fmaxf(s, 0.f);
}

__global__ __launch_bounds__(320)
void k_fc2(const float* __restrict__ h1, const float* __restrict__ w2f,
           const float* __restrict__ b2f, float* __restrict__ out) {
  const int t = threadIdx.x;
  const int m = t / 5, o = t - m * 5;
  const float* hr = h1 + (size_t)m * 256;
  const float* wr = w2f + (size_t)o * 256;
  float a0 = 0.f, a1 = 0.f, a2 = 0.f, a3 = 0.f;
  #pragma unroll
  for (int j = 0; j < 256; j += 16) {
    const float4 h0 = ldg4(hr + j),      w0 = ldg4(wr + j);
    const float4 h1v = ldg4(hr + j + 4),  w1v = ldg4(wr + j + 4);
    const float4 h2 = ldg4(hr + j + 8),  w2 = ldg4(wr + j + 8);
    const float4 h3 = ldg4(hr + j + 12), w3 = ldg4(wr + j + 12);
    a0 = fmaf(h0.x, w0.x, fmaf(h0.y, w0.y, fmaf(h0.z, w0.z, fmaf(h0.w, w0.w, a0))));
    a1 = fmaf(h1v.x, w1v.x, fmaf(h1v.y, w1v.y, fmaf(h1v.z, w1v.z, fmaf(h1v.w, w1v.w, a1))));
    a2 = fmaf(h2.x, w2.x, fmaf(h2.y, w2.y, fmaf(h2.z, w2.z, fmaf(h2.w, w2.w, a2))));
    a3 = fmaf(h3.x, w3.x, fmaf(h3.y, w3.y, fmaf(h3.z, w3.z, fmaf(h3.w, w3.w, a3))));
  }
  out[m * 5 + o] = b2f[o] + ((a0 + a1) + (a2 + a3));
}

// ---------------------------------------------------------------------------
extern "C" void kernel_launch(void* const* d_in, const int* in_sizes, int n_in,
                              void* d_out, int out_size, void* d_ws, size_t ws_size,
                              hipStream_t stream) {
  (void)in_sizes; (void)n_in; (void)out_size; (void)ws_size;
  const float* d   = (const float*)d_in[0];
  const float* w1  = (const float*)d_in[1];
  const float* b1  = (const float*)d_in[2];
  const float* g1  = (const float*)d_in[3];
  const float* be1 = (const float*)d_in[4];
  const float* w2  = (const float*)d_in[5];
  const float* b2  = (const float*)d_in[6];
  const float* g2  = (const float*)d_in[7];
  const float* be2 = (const float*)d_in[8];
  const float* w3  = (const float*)d_in[9];
  const float* b3  = (const float*)d_in[10];
  const float* g3  = (const float*)d_in[11];
  const float* be3 = (const float*)d_in[12];
  const float* fw1 = (const float*)d_in[13];
  const float* fb1 = (const float*)d_in[14];
  const float* fw2 = (const float*)d_in[15];
  const float* fb2 = (const float*)d_in[16];
  float* out = (float*)d_out;
  float* ws  = (float*)d_ws;

  u16* sel1 = (u16*)(ws + WS_SEL1);
  u16* x1   = (u16*)(ws + WS_X1);
  u16* rec  = (u16*)(ws + WS_REC);   // aliases X1+X2+SEL2 (all written later)
  u16* x2   = (u16*)(ws + WS_X2);
  u16* sel2 = (u16*)(ws + WS_SEL2);
  u16* x3t  = (u16*)(ws + WS_X3T);
  u16* sel3 = (u16*)(ws + WS_SEL3);
  u16* wt1  = (u16*)(ws + WS_WT1);
  u16* wt2  = (u16*)(ws + WS_WT2);
  u16* wt3  = (u16*)(ws + WS_WT3);
  float* cp = ws + WS_CP;
  float* p2 = ws + WS_P2;
  float* p3 = ws + WS_P3;
  double* pd = (double*)(ws + WS_PD);  // pd45 first, then reused by fin1
  float* st = ws + WS_ST;
  float* fcp = ws + WS_FCP;
  float* h1 = ws + WS_H1;

  k_prep_w<<<100, 256, 0, stream>>>(w1, w2, w3, wt1, wt2, wt3);
  // layer 1: corr (stats source + records), analytic stats, conv+pool, bnrelu
  k_corr<<<784, 256, 0, stream>>>(d, rec, cp);
  k_corr_fin<<<45, 256, 0, stream>>>(cp, pd);
  k_stats1<<<1, 64, 0, stream>>>(pd, w1, b1, g1, be1, st + 0, st + 16);
  k_conv1<<<dim3(14, 14, 64), 256, 0, stream>>>(rec, wt1, b1, g1, sel1);
  k_bnrelu<16, 112><<<6272, 256, 0, stream>>>(sel1, st + 0, st + 16, x1);
  // layer 2
  k_conv2<<<dim3(7, 7, 64), 256, 0, stream>>>(x1, wt2, b2, g2, sel2, p2);
  k_fin1<<<dim3(32, 16), 256, 0, stream>>>(p2, 12544, 784, 16, pd);
  k_fin2<<<32, 64, 0, stream>>>(pd, 16, 802816.0, g2, be2, st + 32, st + 64);
  k_bnrelu<32, 56><<<3136, 256, 0, stream>>>(sel2, st + 32, st + 64, x2);
  // layer 3
  k_conv3<<<dim3(4, 7, 64), 256, 0, stream>>>(x2, wt3, b3, g3, sel3, p3);
  k_fin1<<<dim3(64, 8), 256, 0, stream>>>(p3, 3584, 448, 8, pd);
  k_fin2<<<64, 64, 0, stream>>>(pd, 8, 200704.0, g3, be3, st + 96, st + 160);
  k_bnrelu3t<<<dim3(7, 64), 256, 0, stream>>>(sel3, st + 96, st + 160, x3t);
  // fc
  k_fc1<<<dim3(56, 4), 256, 0, stream>>>(x3t, fw1, fcp);
  k_fc1_reduce<<<64, 256, 0, stream>>>(fcp, fb1, h1);
  k_fc2<<<1, 320, 0, stream>>>(h1, fw2, fb2, out);
}

// Round 12
// 207.095 us; speedup vs baseline: 1.0331x; 1.0331x over previous
//
#include <hip/hip_runtime.h>
#include <cstdint>
#include <cstddef>

// ---------------------------------------------------------------------------
// Plant_Identifier CNN forward.
// R12: k_corr occupancy fix — 8px/thread (1568 blocks, was 784) to cure the
//      latency stall (Occ 26%, VALUBusy 10% at 73us). Math unchanged.
// R11: layer-1 BN stats analytic from input cross-correlations; k_corr also
//      emits hi/lo records; conv1 = record loads + MFMA + sel-pool only.
// R10: sel-trick (sign(gamma) known pre-stats -> single pooled buffer).
// conv2/3: bf16 MFMA implicit-GEMM, fused stats + sel pool. fc1: zero-LDS
// MFMA K-split. All reductions deterministic (fixed-order two-stage).
// ---------------------------------------------------------------------------

typedef __attribute__((ext_vector_type(8))) short sh8_t;   // 8 x bf16
typedef __attribute__((ext_vector_type(4))) float f4_t;    // mfma acc
typedef unsigned short u16;
typedef unsigned int u32;

// workspace layout (float units)
#define WS_SEL1 ((size_t)0)          // sel1 bf16 [64,112,112,16] (6,422,528)
#define WS_X1   ((size_t)6422528)    // x1   bf16 [64,112,112,16] (6,422,528)
#define WS_X2   ((size_t)12845056)   // x2   bf16 [64,56,56,32]   (3,211,264)
#define WS_SEL2 ((size_t)16056320)   // sel2                       (3,211,264)
// rec bf16 [64,224,224,8] = 12,845,056 float slots, ALIASES [X1, X2, SEL2):
// written by k_corr, read by k_conv1; X1/X2/SEL2 are written strictly later.
#define WS_REC  WS_X1
#define WS_X3T  ((size_t)19267584)   // x3t  bf16 [64,64,28,28]   (1,605,632)
#define WS_SEL3 ((size_t)20873216)   // sel3 bf16 [64,28,28,64]   (1,605,632)
#define WS_WT1  ((size_t)22478848)   // 512
#define WS_WT2  ((size_t)22479360)   // 3,072
#define WS_WT3  ((size_t)22482432)   // 9,216
#define WS_CP   ((size_t)22491648)   // corr partials [45][25088] = 1,128,960
#define WS_P2   ((size_t)23620608)   // 32*2*12544 = 802,816
#define WS_P3   ((size_t)24423424)   // 64*2*3584  = 458,752
#define WS_PD   ((size_t)24882176)   // 4,096 (doubles region; pd45 + fin pd)
#define WS_ST   ((size_t)24886272)   // 224
#define WS_FCP  ((size_t)24886496)   // 917,504
#define WS_H1   ((size_t)25804000)   // 16,384
// total 25,820,384 floats = 103.3 MB

static __device__ __forceinline__ float4 ldg4(const float* p) {
  return *reinterpret_cast<const float4*>(p);
}
static __device__ __forceinline__ float bf2f(u16 u) {
  union { u32 i; float f; } c; c.i = ((u32)u) << 16; return c.f;
}
static __device__ __forceinline__ u16 f2bf(float f) {
  union { float f; u32 i; } c; c.f = f;
  const u32 x = c.i;
  return (u16)((x + 0x7fffu + ((x >> 16) & 1u)) >> 16);   // RNE
}

// ---------------- weight prep -----------------------------------------------
__global__ __launch_bounds__(256)
void k_prep_w(const float* __restrict__ w1, const float* __restrict__ w2,
              const float* __restrict__ w3, u16* __restrict__ wt1,
              u16* __restrict__ wt2, u16* __restrict__ wt3) {
  const int t = blockIdx.x * 256 + threadIdx.x;  // 25600 total
  if (t < 1024) {
    const int half = t >> 9;
    const int u = t & 511;
    const int co = u >> 5, k = u & 31;
    const int g = k >> 3, j = k & 7;
    const int kh = g >> 1, kw = g & 1;
    const int ci = (j < 4) ? j : j - 4;
    bool active = (j != 3) && (j != 7);
    if (half == 1) active = active && (j < 4);
    float val = 0.f;
    if (active) {
      const float w = w1[((co * 3 + ci) * 2 + kh) * 2 + kw];
      const u16 h = f2bf(w);
      val = (half == 0) ? bf2f(h) : (w - bf2f(h));
    }
    wt1[t] = f2bf(val);
  } else if (t < 7168) {  // wt2 [co32][kh3][kwp4][ci16], kw=3 zero-padded
    const int u = t - 1024;
    const int ci = u & 15, kwp = (u >> 4) & 3, kh = (u >> 6) % 3, co = u / 192;
    float v = 0.f;
    if (kwp < 3) v = w2[((co * 16 + ci) * 3 + kh) * 3 + kwp];
    wt2[u] = f2bf(v);
  } else {                // wt3 [co64][kh3][kw3][ci32]
    const int u = t - 7168;
    const int ci = u & 31, kw = (u >> 5) % 3, kh = (u / 96) % 3, co = u / 288;
    wt3[u] = f2bf(w3[((co * 32 + ci) * 3 + kh) * 3 + kw]);
  }
}

// ---------------- k_corr: correlations + channel sums + record emit ---------
// R12: thread = 8 consecutive px of one row (2 chunks of 4). 1568 blocks.
// acc[0..26]  : C[i,j,dh=1,dw]   idx = (i*3+j)*3 + (dw+1)
// acc[27..35] : C[i,j,dh=0,dw=1] idx = 27 + i*3+j
// acc[36..41] : C[i,j,0,0] i<=j  idx = 36 + i*(5-i)/2 + j
// acc[42..44] : S_ci
__global__ __launch_bounds__(256)
void k_corr(const float* __restrict__ d, u16* __restrict__ rec,
            float* __restrict__ cpart) {
  const int tid = blockIdx.x * 256 + threadIdx.x;   // 401,408 = 64*224*28
  const int n = tid / 6272;                          // 224*28
  const int rem = tid - n * 6272;
  const int ih = rem / 28, seg = rem - ih * 28;
  const int c0 = seg * 8;
  float acc[45];
  #pragma unroll
  for (int q = 0; q < 45; ++q) acc[q] = 0.f;
  const bool hasDown = (ih + 1 < 224);
  #pragma unroll
  for (int chunk = 0; chunk < 2; ++chunk) {
    const int c = c0 + chunk * 4;
    float r0[3][6], r1[3][6];
    #pragma unroll
    for (int ci = 0; ci < 3; ++ci) {
      const float* pr = d + ((size_t)(n * 3 + ci) * 224 + ih) * 224;
      const float4 v = ldg4(pr + c);
      r0[ci][1] = v.x; r0[ci][2] = v.y; r0[ci][3] = v.z; r0[ci][4] = v.w;
      r0[ci][0] = (c > 0) ? pr[c - 1] : 0.f;
      r0[ci][5] = (c + 4 < 224) ? pr[c + 4] : 0.f;
      if (hasDown) {
        const float4 w = ldg4(pr + 224 + c);
        r1[ci][1] = w.x; r1[ci][2] = w.y; r1[ci][3] = w.z; r1[ci][4] = w.w;
        r1[ci][0] = (c > 0) ? pr[224 + c - 1] : 0.f;
        r1[ci][5] = (c + 4 < 224) ? pr[224 + c + 4] : 0.f;
      } else {
        #pragma unroll
        for (int z = 0; z < 6; ++z) r1[ci][z] = 0.f;
      }
    }
    #pragma unroll
    for (int p = 0; p < 4; ++p) {
      float a[3];
      a[0] = r0[0][1 + p]; a[1] = r0[1][1 + p]; a[2] = r0[2][1 + p];
      acc[42] += a[0]; acc[43] += a[1]; acc[44] += a[2];
      acc[36] = fmaf(a[0], a[0], acc[36]);
      acc[37] = fmaf(a[0], a[1], acc[37]);
      acc[38] = fmaf(a[0], a[2], acc[38]);
      acc[39] = fmaf(a[1], a[1], acc[39]);
      acc[40] = fmaf(a[1], a[2], acc[40]);
      acc[41] = fmaf(a[2], a[2], acc[41]);
      #pragma unroll
      for (int i = 0; i < 3; ++i)
        #pragma unroll
        for (int j = 0; j < 3; ++j)
          acc[27 + i * 3 + j] = fmaf(a[i], r0[j][2 + p], acc[27 + i * 3 + j]);
      #pragma unroll
      for (int i = 0; i < 3; ++i)
        #pragma unroll
        for (int j = 0; j < 3; ++j)
          #pragma unroll
          for (int dwp = 0; dwp < 3; ++dwp)  // dwp = dw+1
            acc[(i * 3 + j) * 3 + dwp] =
                fmaf(a[i], r1[j][p + dwp], acc[(i * 3 + j) * 3 + dwp]);
    }
    // emit hi/lo records for pixels (ih, c..c+3)
    #pragma unroll
    for (int p = 0; p < 4; ++p) {
      const float v0 = r0[0][1 + p], v1 = r0[1][1 + p], v2 = r0[2][1 + p];
      const u16 h0 = f2bf(v0), h1 = f2bf(v1), h2 = f2bf(v2);
      int4 rr;
      rr.x = (u32)h0 | ((u32)h1 << 16);
      rr.y = (u32)h2;
      rr.z = (u32)f2bf(v0 - bf2f(h0)) | ((u32)f2bf(v1 - bf2f(h1)) << 16);
      rr.w = (u32)f2bf(v2 - bf2f(h2));
      *reinterpret_cast<int4*>(rec + (size_t)((n * 224 + ih) * 224 + c + p) * 8) = rr;
    }
  }
  // 16-lane group reduce
  #pragma unroll
  for (int m = 1; m < 16; m <<= 1)
    #pragma unroll
    for (int q = 0; q < 45; ++q) acc[q] += __shfl_xor(acc[q], m);
  if ((threadIdx.x & 15) == 0) {
    const int slot = blockIdx.x * 16 + (threadIdx.x >> 4);  // 25088
    #pragma unroll
    for (int q = 0; q < 45; ++q) cpart[q * 25088 + slot] = acc[q];
  }
}

// ------------- corr partials -> 45 doubles -----------------------------------
__global__ __launch_bounds__(256)
void k_corr_fin(const float* __restrict__ cpart, double* __restrict__ pd45) {
  const int q = blockIdx.x;  // 45
  const float* base = cpart + (size_t)q * 25088;
  double a0 = 0, a1 = 0, a2 = 0, a3 = 0;
  for (int i = threadIdx.x * 4; i + 3 < 25088; i += 1024) {
    const float4 v = ldg4(base + i);
    a0 += v.x; a1 += v.y; a2 += v.z; a3 += v.w;
  }
  __shared__ double rs[256];
  rs[threadIdx.x] = (a0 + a1) + (a2 + a3);
  __syncthreads();
  for (int off = 128; off > 0; off >>= 1) {
    if (threadIdx.x < off) rs[threadIdx.x] += rs[threadIdx.x + off];
    __syncthreads();
  }
  if (threadIdx.x == 0) pd45[q] = rs[0];
}

// ------------- layer-1 stats: 144-term tap-pair combine (fp64) ---------------
__global__ __launch_bounds__(64)
void k_stats1(const double* __restrict__ pd45, const float* __restrict__ w1,
              const float* __restrict__ b1, const float* __restrict__ g1,
              const float* __restrict__ be1, float* __restrict__ scale,
              float* __restrict__ shift) {
  const int co = threadIdx.x;
  if (co >= 16) return;
  double w[3][2][2];
  for (int ci = 0; ci < 3; ++ci)
    for (int kh = 0; kh < 2; ++kh)
      for (int kw = 0; kw < 2; ++kw)
        w[ci][kh][kw] = (double)w1[((co * 3 + ci) * 2 + kh) * 2 + kw];
  double sum_s = 0.0;
  for (int ci = 0; ci < 3; ++ci)
    for (int kh = 0; kh < 2; ++kh)
      for (int kw = 0; kw < 2; ++kw)
        sum_s += w[ci][kh][kw] * pd45[42 + ci];
  double ss = 0.0;
  for (int i = 0; i < 3; ++i)
    for (int kh = 0; kh < 2; ++kh)
      for (int kw = 0; kw < 2; ++kw)
        for (int j = 0; j < 3; ++j)
          for (int kh2 = 0; kh2 < 2; ++kh2)
            for (int kw2 = 0; kw2 < 2; ++kw2) {
              int a = i, b2 = j, dh = kh2 - kh, dw = kw2 - kw;
              if (dh < 0 || (dh == 0 && dw < 0)) {
                const int tt = a; a = b2; b2 = tt; dh = -dh; dw = -dw;
              }
              double cv;
              if (dh == 1) cv = pd45[(a * 3 + b2) * 3 + dw + 1];
              else if (dw == 1) cv = pd45[27 + a * 3 + b2];
              else {
                const int lo = (a < b2) ? a : b2, hi = (a < b2) ? b2 : a;
                cv = pd45[36 + lo * (5 - lo) / 2 + hi];
              }
              ss += w[i][kh][kw] * w[j][kh2][kw2] * cv;
            }
  const double Npos = 3240000.0;  // 64*225*225
  const double b = (double)b1[co];
  const double mu = sum_s / Npos + b;
  const double E2 = (ss + 2.0 * b * sum_s) / Npos + b * b;
  const double var = E2 - mu * mu;
  const double rstd = 1.0 / sqrt(var + 1e-5);
  const double sc = (double)g1[co] * rstd;
  scale[co] = (float)sc;
  shift[co] = (float)((double)be1[co] - mu * sc);
}

// ---------------- conv1: record loads + MFMA + sel pool (no stats) ----------
// grid (14,14,64), 256 thr. 16x16 tile of the 224x224 pooled region.
__global__ __launch_bounds__(256)
void k_conv1(const u16* __restrict__ rec, const u16* __restrict__ wt1,
             const float* __restrict__ b1, const float* __restrict__ g1,
             u16* __restrict__ sel1) {
  const int bx = blockIdx.x, by = blockIdx.y, n = blockIdx.z;
  const int ow0 = bx * 16, oh0 = by * 16;
  const int t = threadIdx.x, lane = t & 63, wv = t >> 6;
  const int g = lane >> 4, li = lane & 15;
  const int kh = g >> 1, kw = g & 1;
  const sh8_t A1 = *reinterpret_cast<const sh8_t*>(wt1 + li * 32 + g * 8);
  const sh8_t A2 = *reinterpret_cast<const sh8_t*>(wt1 + 512 + li * 32 + g * 8);
  const int iw = ow0 + li + kw - 1;      // [-1, 223]
  const bool iwv = iw >= 0;
  f4_t acc[4];
  #pragma unroll
  for (int r = 0; r < 4; ++r) acc[r] = (f4_t)0.f;
  #pragma unroll
  for (int r = 0; r < 4; ++r) {
    const int ih = oh0 + wv * 4 + r + kh - 1;  // [-1, 223]
    sh8_t B = (sh8_t)(short)0;
    if (iwv && ih >= 0)
      B = *reinterpret_cast<const sh8_t*>(rec + (size_t)((n * 224 + ih) * 224 + iw) * 8);
    acc[r] = __builtin_amdgcn_mfma_f32_16x16x32_bf16(A1, B, acc[r], 0, 0, 0);
    acc[r] = __builtin_amdgcn_mfma_f32_16x16x32_bf16(A2, B, acc[r], 0, 0, 0);
  }
  const f4_t bias = *reinterpret_cast<const f4_t*>(b1 + 4 * g);
  const f4_t gam  = *reinterpret_cast<const f4_t*>(g1 + 4 * g);
  f4_t y[4];
  #pragma unroll
  for (int r = 0; r < 4; ++r) y[r] = acc[r] + bias;
  #pragma unroll
  for (int rp = 0; rp < 2; ++rp) {
    f4_t v;
    #pragma unroll
    for (int j = 0; j < 4; ++j) {
      const float a = y[2 * rp][j], b = y[2 * rp + 1][j];
      v[j] = (gam[j] >= 0.f) ? fmaxf(a, b) : fminf(a, b);
    }
    f4_t o;
    #pragma unroll
    for (int j = 0; j < 4; ++j) o[j] = __shfl_xor(v[j], 1);
    if ((li & 1) == 0) {
      u16 pk[4];
      #pragma unroll
      for (int j = 0; j < 4; ++j)
        pk[j] = f2bf((gam[j] >= 0.f) ? fmaxf(v[j], o[j]) : fminf(v[j], o[j]));
      const int po = 8 * by + 2 * wv + rp, qo = 8 * bx + (li >> 1);
      uint2 w;
      w.x = (u32)pk[0] | ((u32)pk[1] << 16);
      w.y = (u32)pk[2] | ((u32)pk[3] << 16);
      *reinterpret_cast<uint2*>(sel1 + ((size_t)((n * 112 + po) * 112 + qo)) * 16 + 4 * g) = w;
    }
  }
}

// ------------- BN finalize stage 1: parallel chunk reduce -------------------
__global__ __launch_bounds__(256)
void k_fin1(const float* __restrict__ part, int P, int chunk, int S,
            double* __restrict__ p2) {
  const int c = blockIdx.x, s = blockIdx.y;
  const int start = s * chunk;
  const int end = min(P, start + chunk);
  __shared__ double rs[256], rq[256];
  double accs[2];
  #pragma unroll
  for (int mom = 0; mom < 2; ++mom) {
    const float* base = part + (size_t)(c * 2 + mom) * P;
    double a0 = 0.0, a1 = 0.0, a2 = 0.0, a3 = 0.0;
    int i = start + threadIdx.x * 4;
    for (; i + 3 < end; i += 1024) {
      const float4 v = ldg4(base + i);
      a0 += v.x; a1 += v.y; a2 += v.z; a3 += v.w;
    }
    for (int j = i; j < end && j < i + 4; ++j) a0 += base[j];
    accs[mom] = (a0 + a1) + (a2 + a3);
  }
  rs[threadIdx.x] = accs[0]; rq[threadIdx.x] = accs[1];
  __syncthreads();
  for (int off = 128; off > 0; off >>= 1) {
    if (threadIdx.x < off) {
      rs[threadIdx.x] += rs[threadIdx.x + off];
      rq[threadIdx.x] += rq[threadIdx.x + off];
    }
    __syncthreads();
  }
  if (threadIdx.x == 0) {
    p2[(size_t)(c * 2 + 0) * S + s] = rs[0];
    p2[(size_t)(c * 2 + 1) * S + s] = rq[0];
  }
}

// ------------- BN finalize stage 2 ------------------------------------------
__global__ __launch_bounds__(64)
void k_fin2(const double* __restrict__ p2, int S, double count,
            const float* __restrict__ g, const float* __restrict__ bta,
            float* __restrict__ scale, float* __restrict__ shift) {
  const int c = blockIdx.x, t = threadIdx.x;
  double s = 0.0, sq = 0.0;
  if (t < S) {
    s  = p2[(size_t)(c * 2 + 0) * S + t];
    sq = p2[(size_t)(c * 2 + 1) * S + t];
  }
  #pragma unroll
  for (int m = 1; m < 64; m <<= 1) {
    s  += __shfl_xor(s, m);
    sq += __shfl_xor(sq, m);
  }
  if (t == 0) {
    const double mean = s / count;
    const double var  = sq / count - mean * mean;
    const double rstd = 1.0 / sqrt(var + 1e-5);
    const double sc = (double)g[c] * rstd;
    scale[c] = (float)sc;
    shift[c] = (float)((double)bta[c] - mean * sc);
  }
}

// ------------- bnrelu: x = relu(sc*sel + sh), NHWC ---------------------------
template<int CH, int P>
__global__ __launch_bounds__(256)
void k_bnrelu(const u16* __restrict__ sel, const float* __restrict__ scale,
              const float* __restrict__ shift, u16* __restrict__ xout) {
  constexpr int G = CH / 8;
  const int idx = blockIdx.x * 256 + threadIdx.x;
  const int cg = idx & (G - 1);
  int rest = idx / G;
  const int qo = rest % P; rest /= P;
  const int po = rest % P;
  const int n = rest / P;
  const size_t base = ((size_t)((n * P + po) * P + qo)) * CH + cg * 8;
  const int4 vs = *reinterpret_cast<const int4*>(sel + base);
  const u32* a = reinterpret_cast<const u32*>(&vs);
  u16 o[8];
  #pragma unroll
  for (int j = 0; j < 8; ++j) {
    const int c = cg * 8 + j;
    const float sc = scale[c], sh = shift[c];
    const u16 raw = (u16)(a[j >> 1] >> ((j & 1) * 16));
    o[j] = f2bf(fmaxf(fmaf(bf2f(raw), sc, sh), 0.f));
  }
  u32 pk[4];
  #pragma unroll
  for (int k = 0; k < 4; ++k) pk[k] = (u32)o[2 * k] | ((u32)o[2 * k + 1] << 16);
  *reinterpret_cast<int4*>(xout + base) = make_int4(pk[0], pk[1], pk[2], pk[3]);
}

// ------------- conv2: bf16 MFMA + stats + sel pool ---------------------------
__global__ __launch_bounds__(256)
void k_conv2(const u16* __restrict__ x1, const u16* __restrict__ wt2,
             const float* __restrict__ b2, const float* __restrict__ g2,
             u16* __restrict__ sel2, float* __restrict__ part) {
  const int ow0 = blockIdx.x * 16, oh0 = blockIdx.y * 16, n = blockIdx.z;
  const int t = threadIdx.x, lane = t & 63, wv = t >> 6;
  const int g = lane >> 4, li = lane & 15;
  __shared__ __align__(16) unsigned char tile[18 * 640];
  for (int idx = t; idx < 720; idx += 256) {
    const int rr = idx / 40, rem = idx - rr * 40, p = rem >> 1, c = rem & 1;
    const int ih = oh0 - 1 + rr, iw = ow0 - 1 + p;
    int4 v = make_int4(0, 0, 0, 0);
    if ((unsigned)ih < 112u && (unsigned)iw < 112u)
      v = *reinterpret_cast<const int4*>(x1 + ((size_t)((n * 112 + ih) * 112 + iw) * 16 + c * 8));
    *reinterpret_cast<int4*>(tile + ((rr * 640 + p * 32 + c * 16) ^ (((p >> 2) & 1) << 4))) = v;
  }
  sh8_t W[2][3][2];
  #pragma unroll
  for (int cot = 0; cot < 2; ++cot)
    #pragma unroll
    for (int kh = 0; kh < 3; ++kh)
      #pragma unroll
      for (int m = 0; m < 2; ++m)
        W[cot][kh][m] = *reinterpret_cast<const sh8_t*>(
            wt2 + ((cot * 16 + li) * 192 + kh * 64 + m * 32 + g * 8));
  f4_t acc[4][2];
  #pragma unroll
  for (int r = 0; r < 4; ++r) { acc[r][0] = (f4_t)0.f; acc[r][1] = (f4_t)0.f; }
  __syncthreads();
  const int rowb = 4 * wv;
  #pragma unroll
  for (int ihr = 0; ihr < 6; ++ihr) {
    const int row = rowb + ihr;
    #pragma unroll
    for (int m = 0; m < 2; ++m) {
      const int p = li + 2 * m + (g >> 1);
      const sh8_t B = *reinterpret_cast<const sh8_t*>(
          tile + ((row * 640 + p * 32 + (g & 1) * 16) ^ (((p >> 2) & 1) << 4)));
      #pragma unroll
      for (int kh = 0; kh < 3; ++kh) {
        const int r = ihr - kh;
        if (r >= 0 && r < 4) {
          acc[r][0] = __builtin_amdgcn_mfma_f32_16x16x32_bf16(W[0][kh][m], B, acc[r][0], 0, 0, 0);
          acc[r][1] = __builtin_amdgcn_mfma_f32_16x16x32_bf16(W[1][kh][m], B, acc[r][1], 0, 0, 0);
        }
      }
    }
  }
  f4_t bias[2], gam[2], ssum[2], ssq[2];
  bias[0] = *reinterpret_cast<const f4_t*>(b2 + 4 * g);
  bias[1] = *reinterpret_cast<const f4_t*>(b2 + 16 + 4 * g);
  gam[0]  = *reinterpret_cast<const f4_t*>(g2 + 4 * g);
  gam[1]  = *reinterpret_cast<const f4_t*>(g2 + 16 + 4 * g);
  ssum[0] = (f4_t)0.f; ssum[1] = (f4_t)0.f; ssq[0] = (f4_t)0.f; ssq[1] = (f4_t)0.f;
  #pragma unroll
  for (int r = 0; r < 4; ++r)
    #pragma unroll
    for (int cot = 0; cot < 2; ++cot) {
      acc[r][cot] += bias[cot];
      ssum[cot] += acc[r][cot];
      ssq[cot] += acc[r][cot] * acc[r][cot];
    }
  #pragma unroll
  for (int msk = 1; msk < 16; msk <<= 1)
    #pragma unroll
    for (int cot = 0; cot < 2; ++cot)
      #pragma unroll
      for (int j = 0; j < 4; ++j) {
        ssum[cot][j] += __shfl_xor(ssum[cot][j], msk);
        ssq[cot][j]  += __shfl_xor(ssq[cot][j], msk);
      }
  if (li == 0) {
    const int slot = (((n * 7 + (int)blockIdx.y) * 7 + (int)blockIdx.x)) * 4 + wv;  // 12544
    #pragma unroll
    for (int cot = 0; cot < 2; ++cot)
      #pragma unroll
      for (int j = 0; j < 4; ++j) {
        const int co = cot * 16 + 4 * g + j;
        part[(size_t)(co * 2 + 0) * 12544 + slot] = ssum[cot][j];
        part[(size_t)(co * 2 + 1) * 12544 + slot] = ssq[cot][j];
      }
  }
  const int pob = 8 * (int)blockIdx.y + 2 * wv;
  const int qo = 8 * (int)blockIdx.x + (li >> 1);
  #pragma unroll
  for (int rp = 0; rp < 2; ++rp)
    #pragma unroll
    for (int cot = 0; cot < 2; ++cot) {
      f4_t v;
      #pragma unroll
      for (int j = 0; j < 4; ++j) {
        const float a = acc[2 * rp][cot][j], b = acc[2 * rp + 1][cot][j];
        v[j] = (gam[cot][j] >= 0.f) ? fmaxf(a, b) : fminf(a, b);
      }
      f4_t o;
      #pragma unroll
      for (int j = 0; j < 4; ++j) o[j] = __shfl_xor(v[j], 1);
      if ((li & 1) == 0) {
        u16 pk[4];
        #pragma unroll
        for (int j = 0; j < 4; ++j)
          pk[j] = f2bf((gam[cot][j] >= 0.f) ? fmaxf(v[j], o[j]) : fminf(v[j], o[j]));
        const size_t off = ((size_t)((n * 56 + pob + rp) * 56 + qo)) * 32 + cot * 16 + 4 * g;
        uint2 w;
        w.x = (u32)pk[0] | ((u32)pk[1] << 16);
        w.y = (u32)pk[2] | ((u32)pk[3] << 16);
        *reinterpret_cast<uint2*>(sel2 + off) = w;
      }
    }
}

// ------------- conv3: bf16 MFMA + stats + sel pool ---------------------------
__global__ __launch_bounds__(256)
void k_conv3(const u16* __restrict__ x2, const u16* __restrict__ wt3,
             const float* __restrict__ b3, const float* __restrict__ g3,
             u16* __restrict__ sel3, float* __restrict__ part) {
  const int ow0 = blockIdx.x * 16, oh0 = blockIdx.y * 8, n = blockIdx.z;
  const int t = threadIdx.x, lane = t & 63, wv = t >> 6;
  const int rh = wv & 1, ch = wv >> 1;
  const int g = lane >> 4, li = lane & 15;
  __shared__ __align__(16) unsigned char tile[10 * 1152];
  for (int idx = t; idx < 720; idx += 256) {
    const int rr = idx / 72, rem = idx - rr * 72, p = rem >> 2, c = rem & 3;
    const int ih = oh0 - 1 + rr, iw = ow0 - 1 + p;
    int4 v = make_int4(0, 0, 0, 0);
    if ((unsigned)ih < 56u && (unsigned)iw < 56u)
      v = *reinterpret_cast<const int4*>(x2 + ((size_t)((n * 56 + ih) * 56 + iw) * 32 + c * 8));
    *reinterpret_cast<int4*>(tile + ((rr * 1152 + p * 64 + c * 16) ^ (((p >> 1) & 3) << 4))) = v;
  }
  sh8_t W[2][3][3];
  #pragma unroll
  for (int c2 = 0; c2 < 2; ++c2)
    #pragma unroll
    for (int kh = 0; kh < 3; ++kh)
      #pragma unroll
      for (int kw = 0; kw < 3; ++kw)
        W[c2][kh][kw] = *reinterpret_cast<const sh8_t*>(
            wt3 + ((size_t)(ch * 32 + c2 * 16 + li) * 288 + (kh * 3 + kw) * 32 + g * 8));
  f4_t acc[4][2];
  #pragma unroll
  for (int r = 0; r < 4; ++r) { acc[r][0] = (f4_t)0.f; acc[r][1] = (f4_t)0.f; }
  __syncthreads();
  const int rowb = 4 * rh;
  #pragma unroll
  for (int ihr = 0; ihr < 6; ++ihr) {
    const int row = rowb + ihr;
    #pragma unroll
    for (int kw = 0; kw < 3; ++kw) {
      const int p = li + kw;
      const sh8_t B = *reinterpret_cast<const sh8_t*>(
          tile + ((row * 1152 + p * 64 + g * 16) ^ (((p >> 1) & 3) << 4)));
      #pragma unroll
      for (int kh = 0; kh < 3; ++kh) {
        const int r = ihr - kh;
        if (r >= 0 && r < 4) {
          acc[r][0] = __builtin_amdgcn_mfma_f32_16x16x32_bf16(W[0][kh][kw], B, acc[r][0], 0, 0, 0);
          acc[r][1] = __builtin_amdgcn_mfma_f32_16x16x32_bf16(W[1][kh][kw], B, acc[r][1], 0, 0, 0);
        }
      }
    }
  }
  const int ow = ow0 + li;
  const bool valid = ow < 56;
  f4_t bias[2], gam[2], ssum[2], ssq[2];
  bias[0] = *reinterpret_cast<const f4_t*>(b3 + ch * 32 + 4 * g);
  bias[1] = *reinterpret_cast<const f4_t*>(b3 + ch * 32 + 16 + 4 * g);
  gam[0]  = *reinterpret_cast<const f4_t*>(g3 + ch * 32 + 4 * g);
  gam[1]  = *reinterpret_cast<const f4_t*>(g3 + ch * 32 + 16 + 4 * g);
  ssum[0] = (f4_t)0.f; ssum[1] = (f4_t)0.f; ssq[0] = (f4_t)0.f; ssq[1] = (f4_t)0.f;
  #pragma unroll
  for (int r = 0; r < 4; ++r)
    #pragma unroll
    for (int c2 = 0; c2 < 2; ++c2) {
      acc[r][c2] += bias[c2];
      if (valid) {
        ssum[c2] += acc[r][c2];
        ssq[c2] += acc[r][c2] * acc[r][c2];
      }
    }
  #pragma unroll
  for (int msk = 1; msk < 16; msk <<= 1)
    #pragma unroll
    for (int c2 = 0; c2 < 2; ++c2)
      #pragma unroll
      for (int j = 0; j < 4; ++j) {
        ssum[c2][j] += __shfl_xor(ssum[c2][j], msk);
        ssq[c2][j]  += __shfl_xor(ssq[c2][j], msk);
      }
  if (li == 0) {
    const int slot = (((n * 7 + (int)blockIdx.y) * 4 + (int)blockIdx.x)) * 2 + rh;  // 3584
    #pragma unroll
    for (int c2 = 0; c2 < 2; ++c2)
      #pragma unroll
      for (int j = 0; j < 4; ++j) {
        const int co = ch * 32 + c2 * 16 + 4 * g + j;
        part[(size_t)(co * 2 + 0) * 3584 + slot] = ssum[c2][j];
        part[(size_t)(co * 2 + 1) * 3584 + slot] = ssq[c2][j];
      }
  }
  const int pob = 4 * (int)blockIdx.y + 2 * rh;
  const int qo = 8 * (int)blockIdx.x + (li >> 1);
  #pragma unroll
  for (int rp = 0; rp < 2; ++rp)
    #pragma unroll
    for (int c2 = 0; c2 < 2; ++c2) {
      f4_t v;
      #pragma unroll
      for (int j = 0; j < 4; ++j) {
        const float a = acc[2 * rp][c2][j], b = acc[2 * rp + 1][c2][j];
        v[j] = (gam[c2][j] >= 0.f) ? fmaxf(a, b) : fminf(a, b);
      }
      f4_t o;
      #pragma unroll
      for (int j = 0; j < 4; ++j) o[j] = __shfl_xor(v[j], 1);
      if (((li & 1) == 0) && (ow + 1 < 56)) {
        u16 pk[4];
        #pragma unroll
        for (int j = 0; j < 4; ++j)
          pk[j] = f2bf((gam[c2][j] >= 0.f) ? fmaxf(v[j], o[j]) : fminf(v[j], o[j]));
        const size_t off = ((size_t)((n * 28 + pob + rp) * 28 + qo)) * 64 + ch * 32 + c2 * 16 + 4 * g;
        uint2 w;
        w.x = (u32)pk[0] | ((u32)pk[1] << 16);
        w.y = (u32)pk[2] | ((u32)pk[3] << 16);
        *reinterpret_cast<uint2*>(sel3 + off) = w;
      }
    }
}

// ------------- bnrelu3 + NHWC->NCHW transpose for fc1 -----------------------
__global__ __launch_bounds__(256)
void k_bnrelu3t(const u16* __restrict__ sel3, const float* __restrict__ scale,
                const float* __restrict__ shift, u16* __restrict__ x3t) {
  const int n = blockIdx.y;
  const int c = threadIdx.x & 63, pq = threadIdx.x >> 6;
  const int po = blockIdx.x * 4 + pq;
  const float sc = scale[c], sh = shift[c];
  const size_t row0 = ((size_t)(n * 28 + po)) * 28 * 64 + c;
  #pragma unroll
  for (int q4 = 0; q4 < 7; ++q4) {
    u16 pk[4];
    #pragma unroll
    for (int i = 0; i < 4; ++i) {
      const int qo = q4 * 4 + i;
      const u16 raw = sel3[row0 + (size_t)qo * 64];
      pk[i] = f2bf(fmaxf(fmaf(bf2f(raw), sc, sh), 0.f));
    }
    uint2 w;
    w.x = (u32)pk[0] | ((u32)pk[1] << 16);
    w.y = (u32)pk[2] | ((u32)pk[3] << 16);
    *reinterpret_cast<uint2*>(x3t + (((size_t)(n * 64 + c) * 28 + po) * 28 + q4 * 4)) = w;
  }
}

// ------------- fc1: zero-LDS MFMA K-split GEMM (56 splits x 896 k) ----------
__global__ __launch_bounds__(256)
void k_fc1(const u16* __restrict__ x3t, const float* __restrict__ w,
           float* __restrict__ partial) {
  const int kc = blockIdx.x, nt = blockIdx.y;
  const int t = threadIdx.x, lane = t & 63, wv = t >> 6;
  const int g = lane >> 4, li = lane & 15;
  const int n0 = nt * 64 + wv * 16;
  const float* wrow = w + (size_t)(n0 + li) * 50176 + kc * 896;
  const u16* xbase = x3t + kc * 896;
  f4_t acc[4];
  #pragma unroll
  for (int mf = 0; mf < 4; ++mf) acc[mf] = (f4_t)0.f;
  #pragma unroll 4
  for (int ks = 0; ks < 28; ++ks) {
    const int kb = ks * 32 + g * 8;
    const float4 wa = ldg4(wrow + kb);
    const float4 wb = ldg4(wrow + kb + 4);
    float wf[8] = {wa.x, wa.y, wa.z, wa.w, wb.x, wb.y, wb.z, wb.w};
    sh8_t hi, lo;
    #pragma unroll
    for (int j = 0; j < 8; ++j) {
      const u16 h = f2bf(wf[j]);
      hi[j] = (short)h;
      lo[j] = (short)f2bf(wf[j] - bf2f(h));
    }
    #pragma unroll
    for (int mf = 0; mf < 4; ++mf) {
      const sh8_t B = *reinterpret_cast<const sh8_t*>(
          xbase + (size_t)(mf * 16 + li) * 50176 + kb);
      acc[mf] = __builtin_amdgcn_mfma_f32_16x16x32_bf16(hi, B, acc[mf], 0, 0, 0);
      acc[mf] = __builtin_amdgcn_mfma_f32_16x16x32_bf16(lo, B, acc[mf], 0, 0, 0);
    }
  }
  float* pb = partial + (size_t)kc * 16384;
  #pragma unroll
  for (int mf = 0; mf < 4; ++mf)
    #pragma unroll
    for (int j = 0; j < 4; ++j)
      pb[(size_t)(n0 + 4 * g + j) * 64 + mf * 16 + li] = acc[mf][j];
}

__global__ __launch_bounds__(256)
void k_fc1_reduce(const float* __restrict__ partial, const float* __restrict__ b1f,
                  float* __restrict__ h1) {
  const int idx = blockIdx.x * 256 + threadIdx.x;  // 16384
  const int nn = idx >> 6, m = idx & 63;
  float a[8];
  #pragma unroll
  for (int u = 0; u < 8; ++u) a[u] = 0.f;
  #pragma unroll
  for (int k = 0; k < 56; k += 8)
    #pragma unroll
    for (int u = 0; u < 8; ++u)
      a[u] += partial[(size_t)(k + u) * 16384 + idx];
  const float s = b1f[nn] + (((a[0] + a[1]) + (a[2] + a[3])) +
                             ((a[4] + a[5]) + (a[6] + a[7])));
  h1[(size_t)m * 256 + nn] = fmaxf(s, 0.f);
}

__global__ __launch_bounds__(320)
void k_fc2(const float* __restrict__ h1, const float* __restrict__ w2f,
           const float* __restrict__ b2f, float* __restrict__ out) {
  const int t = threadIdx.x;
  const int m = t / 5, o = t - m * 5;
  const float* hr = h1 + (size_t)m * 256;
  const float* wr = w2f + (size_t)o * 256;
  float a0 = 0.f, a1 = 0.f, a2 = 0.f, a3 = 0.f;
  #pragma unroll
  for (int j = 0; j < 256; j += 16) {
    const float4 h0 = ldg4(hr + j),      w0 = ldg4(wr + j);
    const float4 h1v = ldg4(hr + j + 4),  w1v = ldg4(wr + j + 4);
    const float4 h2 = ldg4(hr + j + 8),  w2 = ldg4(wr + j + 8);
    const float4 h3 = ldg4(hr + j + 12), w3 = ldg4(wr + j + 12);
    a0 = fmaf(h0.x, w0.x, fmaf(h0.y, w0.y, fmaf(h0.z, w0.z, fmaf(h0.w, w0.w, a0))));
    a1 = fmaf(h1v.x, w1v.x, fmaf(h1v.y, w1v.y, fmaf(h1v.z, w1v.z, fmaf(h1v.w, w1v.w, a1))));
    a2 = fmaf(h2.x, w2.x, fmaf(h2.y, w2.y, fmaf(h2.z, w2.z, fmaf(h2.w, w2.w, a2))));
    a3 = fmaf(h3.x, w3.x, fmaf(h3.y, w3.y, fmaf(h3.z, w3.z, fmaf(h3.w, w3.w, a3))));
  }
  out[m * 5 + o] = b2f[o] + ((a0 + a1) + (a2 + a3));
}

// ---------------------------------------------------------------------------
extern "C" void kernel_launch(void* const* d_in, const int* in_sizes, int n_in,
                              void* d_out, int out_size, void* d_ws, size_t ws_size,
                              hipStream_t stream) {
  (void)in_sizes; (void)n_in; (void)out_size; (void)ws_size;
  const float* d   = (const float*)d_in[0];
  const float* w1  = (const float*)d_in[1];
  const float* b1  = (const float*)d_in[2];
  const float* g1  = (const float*)d_in[3];
  const float* be1 = (const float*)d_in[4];
  const float* w2  = (const float*)d_in[5];
  const float* b2  = (const float*)d_in[6];
  const float* g2  = (const float*)d_in[7];
  const float* be2 = (const float*)d_in[8];
  const float* w3  = (const float*)d_in[9];
  const float* b3  = (const float*)d_in[10];
  const float* g3  = (const float*)d_in[11];
  const float* be3 = (const float*)d_in[12];
  const float* fw1 = (const float*)d_in[13];
  const float* fb1 = (const float*)d_in[14];
  const float* fw2 = (const float*)d_in[15];
  const float* fb2 = (const float*)d_in[16];
  float* out = (float*)d_out;
  float* ws  = (float*)d_ws;

  u16* sel1 = (u16*)(ws + WS_SEL1);
  u16* x1   = (u16*)(ws + WS_X1);
  u16* rec  = (u16*)(ws + WS_REC);   // aliases X1+X2+SEL2 (all written later)
  u16* x2   = (u16*)(ws + WS_X2);
  u16* sel2 = (u16*)(ws + WS_SEL2);
  u16* x3t  = (u16*)(ws + WS_X3T);
  u16* sel3 = (u16*)(ws + WS_SEL3);
  u16* wt1  = (u16*)(ws + WS_WT1);
  u16* wt2  = (u16*)(ws + WS_WT2);
  u16* wt3  = (u16*)(ws + WS_WT3);
  float* cp = ws + WS_CP;
  float* p2 = ws + WS_P2;
  float* p3 = ws + WS_P3;
  double* pd = (double*)(ws + WS_PD);  // pd45 first, then reused by fin1
  float* st = ws + WS_ST;
  float* fcp = ws + WS_FCP;
  float* h1 = ws + WS_H1;

  k_prep_w<<<100, 256, 0, stream>>>(w1, w2, w3, wt1, wt2, wt3);
  // layer 1: corr (stats source + records), analytic stats, conv+pool, bnrelu
  k_corr<<<1568, 256, 0, stream>>>(d, rec, cp);
  k_corr_fin<<<45, 256, 0, stream>>>(cp, pd);
  k_stats1<<<1, 64, 0, stream>>>(pd, w1, b1, g1, be1, st + 0, st + 16);
  k_conv1<<<dim3(14, 14, 64), 256, 0, stream>>>(rec, wt1, b1, g1, sel1);
  k_bnrelu<16, 112><<<6272, 256, 0, stream>>>(sel1, st + 0, st + 16, x1);
  // layer 2
  k_conv2<<<dim3(7, 7, 64), 256, 0, stream>>>(x1, wt2, b2, g2, sel2, p2);
  k_fin1<<<dim3(32, 16), 256, 0, stream>>>(p2, 12544, 784, 16, pd);
  k_fin2<<<32, 64, 0, stream>>>(pd, 16, 802816.0, g2, be2, st + 32, st + 64);
  k_bnrelu<32, 56><<<3136, 256, 0, stream>>>(sel2, st + 32, st + 64, x2);
  // layer 3
  k_conv3<<<dim3(4, 7, 64), 256, 0, stream>>>(x2, wt3, b3, g3, sel3, p3);
  k_fin1<<<dim3(64, 8), 256, 0, stream>>>(p3, 3584, 448, 8, pd);
  k_fin2<<<64, 64, 0, stream>>>(pd, 8, 200704.0, g3, be3, st + 96, st + 160);
  k_bnrelu3t<<<dim3(7, 64), 256, 0, stream>>>(sel3, st + 96, st + 160, x3t);
  // fc
  k_fc1<<<dim3(56, 4), 256, 0, stream>>>(x3t, fw1, fcp);
  k_fc1_reduce<<<64, 256, 0, stream>>>(fcp, fb1, h1);
  k_fc2<<<1, 320, 0, stream>>>(h1, fw2, fb2, out);
}

// Round 13
// 205.857 us; speedup vs baseline: 1.0394x; 1.0060x over previous
//
#include <hip/hip_runtime.h>
#include <cstdint>
#include <cstddef>

// ---------------------------------------------------------------------------
// Plant_Identifier CNN forward.
// R13: k_corr write-path fix — partials transposed through LDS so each block
//      writes 45 coalesced 64B runs instead of 720 scattered 4B stores
//      (WRITE_SIZE showed ~70MB amplification). Unused left-halo loads of the
//      top row dropped. Math bit-identical.
// R11/12: layer-1 BN stats analytic from input cross-correlations; k_corr
//      emits hi/lo records; conv1 = record loads + MFMA + sel-pool only.
// R10: sel-trick (sign(gamma) known pre-stats -> single pooled buffer).
// conv2/3: bf16 MFMA implicit-GEMM, fused stats + sel pool. fc1: zero-LDS
// MFMA K-split. All reductions deterministic (fixed-order two-stage).
// ---------------------------------------------------------------------------

typedef __attribute__((ext_vector_type(8))) short sh8_t;   // 8 x bf16
typedef __attribute__((ext_vector_type(4))) float f4_t;    // mfma acc
typedef unsigned short u16;
typedef unsigned int u32;

// workspace layout (float units)
#define WS_SEL1 ((size_t)0)          // sel1 bf16 [64,112,112,16] (6,422,528)
#define WS_X1   ((size_t)6422528)    // x1   bf16 [64,112,112,16] (6,422,528)
#define WS_X2   ((size_t)12845056)   // x2   bf16 [64,56,56,32]   (3,211,264)
#define WS_SEL2 ((size_t)16056320)   // sel2                       (3,211,264)
// rec bf16 [64,224,224,8] = 12,845,056 float slots, ALIASES [X1, X2, SEL2):
// written by k_corr, read by k_conv1; X1/X2/SEL2 are written strictly later.
#define WS_REC  WS_X1
#define WS_X3T  ((size_t)19267584)   // x3t  bf16 [64,64,28,28]   (1,605,632)
#define WS_SEL3 ((size_t)20873216)   // sel3 bf16 [64,28,28,64]   (1,605,632)
#define WS_WT1  ((size_t)22478848)   // 512
#define WS_WT2  ((size_t)22479360)   // 3,072
#define WS_WT3  ((size_t)22482432)   // 9,216
#define WS_CP   ((size_t)22491648)   // corr partials [45][25088] = 1,128,960
#define WS_P2   ((size_t)23620608)   // 32*2*12544 = 802,816
#define WS_P3   ((size_t)24423424)   // 64*2*3584  = 458,752
#define WS_PD   ((size_t)24882176)   // 4,096 (doubles region; pd45 + fin pd)
#define WS_ST   ((size_t)24886272)   // 224
#define WS_FCP  ((size_t)24886496)   // 917,504
#define WS_H1   ((size_t)25804000)   // 16,384
// total 25,820,384 floats = 103.3 MB

static __device__ __forceinline__ float4 ldg4(const float* p) {
  return *reinterpret_cast<const float4*>(p);
}
static __device__ __forceinline__ float bf2f(u16 u) {
  union { u32 i; float f; } c; c.i = ((u32)u) << 16; return c.f;
}
static __device__ __forceinline__ u16 f2bf(float f) {
  union { float f; u32 i; } c; c.f = f;
  const u32 x = c.i;
  return (u16)((x + 0x7fffu + ((x >> 16) & 1u)) >> 16);   // RNE
}

// ---------------- weight prep -----------------------------------------------
__global__ __launch_bounds__(256)
void k_prep_w(const float* __restrict__ w1, const float* __restrict__ w2,
              const float* __restrict__ w3, u16* __restrict__ wt1,
              u16* __restrict__ wt2, u16* __restrict__ wt3) {
  const int t = blockIdx.x * 256 + threadIdx.x;  // 25600 total
  if (t < 1024) {
    const int half = t >> 9;
    const int u = t & 511;
    const int co = u >> 5, k = u & 31;
    const int g = k >> 3, j = k & 7;
    const int kh = g >> 1, kw = g & 1;
    const int ci = (j < 4) ? j : j - 4;
    bool active = (j != 3) && (j != 7);
    if (half == 1) active = active && (j < 4);
    float val = 0.f;
    if (active) {
      const float w = w1[((co * 3 + ci) * 2 + kh) * 2 + kw];
      const u16 h = f2bf(w);
      val = (half == 0) ? bf2f(h) : (w - bf2f(h));
    }
    wt1[t] = f2bf(val);
  } else if (t < 7168) {  // wt2 [co32][kh3][kwp4][ci16], kw=3 zero-padded
    const int u = t - 1024;
    const int ci = u & 15, kwp = (u >> 4) & 3, kh = (u >> 6) % 3, co = u / 192;
    float v = 0.f;
    if (kwp < 3) v = w2[((co * 16 + ci) * 3 + kh) * 3 + kwp];
    wt2[u] = f2bf(v);
  } else {                // wt3 [co64][kh3][kw3][ci32]
    const int u = t - 7168;
    const int ci = u & 31, kw = (u >> 5) % 3, kh = (u / 96) % 3, co = u / 288;
    wt3[u] = f2bf(w3[((co * 32 + ci) * 3 + kh) * 3 + kw]);
  }
}

// ---------------- k_corr: correlations + channel sums + record emit ---------
// thread = 8 consecutive px of one row (2 chunks of 4). 1568 blocks.
// acc[0..26]  : C[i,j,dh=1,dw]   idx = (i*3+j)*3 + (dw+1)
// acc[27..35] : C[i,j,dh=0,dw=1] idx = 27 + i*3+j
// acc[36..41] : C[i,j,0,0] i<=j  idx = 36 + i*(5-i)/2 + j
// acc[42..44] : S_ci
// R13: partial writes transposed through LDS (coalesced 64B runs per q).
__global__ __launch_bounds__(256)
void k_corr(const float* __restrict__ d, u16* __restrict__ rec,
            float* __restrict__ cpart) {
  const int tid = blockIdx.x * 256 + threadIdx.x;   // 401,408 = 64*224*28
  const int n = tid / 6272;                          // 224*28
  const int rem = tid - n * 6272;
  const int ih = rem / 28, seg = rem - ih * 28;
  const int c0 = seg * 8;
  float acc[45];
  #pragma unroll
  for (int q = 0; q < 45; ++q) acc[q] = 0.f;
  const bool hasDown = (ih + 1 < 224);
  #pragma unroll
  for (int chunk = 0; chunk < 2; ++chunk) {
    const int c = c0 + chunk * 4;
    float r0[3][6], r1[3][6];
    #pragma unroll
    for (int ci = 0; ci < 3; ++ci) {
      const float* pr = d + ((size_t)(n * 3 + ci) * 224 + ih) * 224;
      const float4 v = ldg4(pr + c);
      r0[ci][1] = v.x; r0[ci][2] = v.y; r0[ci][3] = v.z; r0[ci][4] = v.w;
      r0[ci][0] = 0.f;  // unused by the math (a uses 1..4, dw=1 uses 2..5)
      r0[ci][5] = (c + 4 < 224) ? pr[c + 4] : 0.f;
      if (hasDown) {
        const float4 w = ldg4(pr + 224 + c);
        r1[ci][1] = w.x; r1[ci][2] = w.y; r1[ci][3] = w.z; r1[ci][4] = w.w;
        r1[ci][0] = (c > 0) ? pr[224 + c - 1] : 0.f;
        r1[ci][5] = (c + 4 < 224) ? pr[224 + c + 4] : 0.f;
      } else {
        #pragma unroll
        for (int z = 0; z < 6; ++z) r1[ci][z] = 0.f;
      }
    }
    #pragma unroll
    for (int p = 0; p < 4; ++p) {
      float a[3];
      a[0] = r0[0][1 + p]; a[1] = r0[1][1 + p]; a[2] = r0[2][1 + p];
      acc[42] += a[0]; acc[43] += a[1]; acc[44] += a[2];
      acc[36] = fmaf(a[0], a[0], acc[36]);
      acc[37] = fmaf(a[0], a[1], acc[37]);
      acc[38] = fmaf(a[0], a[2], acc[38]);
      acc[39] = fmaf(a[1], a[1], acc[39]);
      acc[40] = fmaf(a[1], a[2], acc[40]);
      acc[41] = fmaf(a[2], a[2], acc[41]);
      #pragma unroll
      for (int i = 0; i < 3; ++i)
        #pragma unroll
        for (int j = 0; j < 3; ++j)
          acc[27 + i * 3 + j] = fmaf(a[i], r0[j][2 + p], acc[27 + i * 3 + j]);
      #pragma unroll
      for (int i = 0; i < 3; ++i)
        #pragma unroll
        for (int j = 0; j < 3; ++j)
          #pragma unroll
          for (int dwp = 0; dwp < 3; ++dwp)  // dwp = dw+1
            acc[(i * 3 + j) * 3 + dwp] =
                fmaf(a[i], r1[j][p + dwp], acc[(i * 3 + j) * 3 + dwp]);
    }
    // emit hi/lo records for pixels (ih, c..c+3)
    #pragma unroll
    for (int p = 0; p < 4; ++p) {
      const float v0 = r0[0][1 + p], v1 = r0[1][1 + p], v2 = r0[2][1 + p];
      const u16 h0 = f2bf(v0), h1 = f2bf(v1), h2 = f2bf(v2);
      int4 rr;
      rr.x = (u32)h0 | ((u32)h1 << 16);
      rr.y = (u32)h2;
      rr.z = (u32)f2bf(v0 - bf2f(h0)) | ((u32)f2bf(v1 - bf2f(h1)) << 16);
      rr.w = (u32)f2bf(v2 - bf2f(h2));
      *reinterpret_cast<int4*>(rec + (size_t)((n * 224 + ih) * 224 + c + p) * 8) = rr;
    }
  }
  // 16-lane group reduce
  #pragma unroll
  for (int m = 1; m < 16; m <<= 1)
    #pragma unroll
    for (int q = 0; q < 45; ++q) acc[q] += __shfl_xor(acc[q], m);
  // R13: stage group results in LDS, then coalesced writes (16 slots/q run)
  __shared__ float xp[16][46];
  if ((threadIdx.x & 15) == 0) {
    const int grp = threadIdx.x >> 4;
    #pragma unroll
    for (int q = 0; q < 45; ++q) xp[grp][q] = acc[q];
  }
  __syncthreads();
  for (int idx = threadIdx.x; idx < 720; idx += 256) {
    const int q = idx >> 4, g2 = idx & 15;
    cpart[(size_t)q * 25088 + blockIdx.x * 16 + g2] = xp[g2][q];
  }
}

// ------------- corr partials -> 45 doubles -----------------------------------
__global__ __launch_bounds__(256)
void k_corr_fin(const float* __restrict__ cpart, double* __restrict__ pd45) {
  const int q = blockIdx.x;  // 45
  const float* base = cpart + (size_t)q * 25088;
  double a0 = 0, a1 = 0, a2 = 0, a3 = 0;
  for (int i = threadIdx.x * 4; i + 3 < 25088; i += 1024) {
    const float4 v = ldg4(base + i);
    a0 += v.x; a1 += v.y; a2 += v.z; a3 += v.w;
  }
  __shared__ double rs[256];
  rs[threadIdx.x] = (a0 + a1) + (a2 + a3);
  __syncthreads();
  for (int off = 128; off > 0; off >>= 1) {
    if (threadIdx.x < off) rs[threadIdx.x] += rs[threadIdx.x + off];
    __syncthreads();
  }
  if (threadIdx.x == 0) pd45[q] = rs[0];
}

// ------------- layer-1 stats: 144-term tap-pair combine (fp64) ---------------
__global__ __launch_bounds__(64)
void k_stats1(const double* __restrict__ pd45, const float* __restrict__ w1,
              const float* __restrict__ b1, const float* __restrict__ g1,
              const float* __restrict__ be1, float* __restrict__ scale,
              float* __restrict__ shift) {
  const int co = threadIdx.x;
  if (co >= 16) return;
  double w[3][2][2];
  for (int ci = 0; ci < 3; ++ci)
    for (int kh = 0; kh < 2; ++kh)
      for (int kw = 0; kw < 2; ++kw)
        w[ci][kh][kw] = (double)w1[((co * 3 + ci) * 2 + kh) * 2 + kw];
  double sum_s = 0.0;
  for (int ci = 0; ci < 3; ++ci)
    for (int kh = 0; kh < 2; ++kh)
      for (int kw = 0; kw < 2; ++kw)
        sum_s += w[ci][kh][kw] * pd45[42 + ci];
  double ss = 0.0;
  for (int i = 0; i < 3; ++i)
    for (int kh = 0; kh < 2; ++kh)
      for (int kw = 0; kw < 2; ++kw)
        for (int j = 0; j < 3; ++j)
          for (int kh2 = 0; kh2 < 2; ++kh2)
            for (int kw2 = 0; kw2 < 2; ++kw2) {
              int a = i, b2 = j, dh = kh2 - kh, dw = kw2 - kw;
              if (dh < 0 || (dh == 0 && dw < 0)) {
                const int tt = a; a = b2; b2 = tt; dh = -dh; dw = -dw;
              }
              double cv;
              if (dh == 1) cv = pd45[(a * 3 + b2) * 3 + dw + 1];
              else if (dw == 1) cv = pd45[27 + a * 3 + b2];
              else {
                const int lo = (a < b2) ? a : b2, hi = (a < b2) ? b2 : a;
                cv = pd45[36 + lo * (5 - lo) / 2 + hi];
              }
              ss += w[i][kh][kw] * w[j][kh2][kw2] * cv;
            }
  const double Npos = 3240000.0;  // 64*225*225
  const double b = (double)b1[co];
  const double mu = sum_s / Npos + b;
  const double E2 = (ss + 2.0 * b * sum_s) / Npos + b * b;
  const double var = E2 - mu * mu;
  const double rstd = 1.0 / sqrt(var + 1e-5);
  const double sc = (double)g1[co] * rstd;
  scale[co] = (float)sc;
  shift[co] = (float)((double)be1[co] - mu * sc);
}

// ---------------- conv1: record loads + MFMA + sel pool (no stats) ----------
// grid (14,14,64), 256 thr. 16x16 tile of the 224x224 pooled region.
__global__ __launch_bounds__(256)
void k_conv1(const u16* __restrict__ rec, const u16* __restrict__ wt1,
             const float* __restrict__ b1, const float* __restrict__ g1,
             u16* __restrict__ sel1) {
  const int bx = blockIdx.x, by = blockIdx.y, n = blockIdx.z;
  const int ow0 = bx * 16, oh0 = by * 16;
  const int t = threadIdx.x, lane = t & 63, wv = t >> 6;
  const int g = lane >> 4, li = lane & 15;
  const int kh = g >> 1, kw = g & 1;
  const sh8_t A1 = *reinterpret_cast<const sh8_t*>(wt1 + li * 32 + g * 8);
  const sh8_t A2 = *reinterpret_cast<const sh8_t*>(wt1 + 512 + li * 32 + g * 8);
  const int iw = ow0 + li + kw - 1;      // [-1, 223]
  const bool iwv = iw >= 0;
  f4_t acc[4];
  #pragma unroll
  for (int r = 0; r < 4; ++r) acc[r] = (f4_t)0.f;
  #pragma unroll
  for (int r = 0; r < 4; ++r) {
    const int ih = oh0 + wv * 4 + r + kh - 1;  // [-1, 223]
    sh8_t B = (sh8_t)(short)0;
    if (iwv && ih >= 0)
      B = *reinterpret_cast<const sh8_t*>(rec + (size_t)((n * 224 + ih) * 224 + iw) * 8);
    acc[r] = __builtin_amdgcn_mfma_f32_16x16x32_bf16(A1, B, acc[r], 0, 0, 0);
    acc[r] = __builtin_amdgcn_mfma_f32_16x16x32_bf16(A2, B, acc[r], 0, 0, 0);
  }
  const f4_t bias = *reinterpret_cast<const f4_t*>(b1 + 4 * g);
  const f4_t gam  = *reinterpret_cast<const f4_t*>(g1 + 4 * g);
  f4_t y[4];
  #pragma unroll
  for (int r = 0; r < 4; ++r) y[r] = acc[r] + bias;
  #pragma unroll
  for (int rp = 0; rp < 2; ++rp) {
    f4_t v;
    #pragma unroll
    for (int j = 0; j < 4; ++j) {
      const float a = y[2 * rp][j], b = y[2 * rp + 1][j];
      v[j] = (gam[j] >= 0.f) ? fmaxf(a, b) : fminf(a, b);
    }
    f4_t o;
    #pragma unroll
    for (int j = 0; j < 4; ++j) o[j] = __shfl_xor(v[j], 1);
    if ((li & 1) == 0) {
      u16 pk[4];
      #pragma unroll
      for (int j = 0; j < 4; ++j)
        pk[j] = f2bf((gam[j] >= 0.f) ? fmaxf(v[j], o[j]) : fminf(v[j], o[j]));
      const int po = 8 * by + 2 * wv + rp, qo = 8 * bx + (li >> 1);
      uint2 w;
      w.x = (u32)pk[0] | ((u32)pk[1] << 16);
      w.y = (u32)pk[2] | ((u32)pk[3] << 16);
      *reinterpret_cast<uint2*>(sel1 + ((size_t)((n * 112 + po) * 112 + qo)) * 16 + 4 * g) = w;
    }
  }
}

// ------------- BN finalize stage 1: parallel chunk reduce -------------------
__global__ __launch_bounds__(256)
void k_fin1(const float* __restrict__ part, int P, int chunk, int S,
            double* __restrict__ p2) {
  const int c = blockIdx.x, s = blockIdx.y;
  const int start = s * chunk;
  const int end = min(P, start + chunk);
  __shared__ double rs[256], rq[256];
  double accs[2];
  #pragma unroll
  for (int mom = 0; mom < 2; ++mom) {
    const float* base = part + (size_t)(c * 2 + mom) * P;
    double a0 = 0.0, a1 = 0.0, a2 = 0.0, a3 = 0.0;
    int i = start + threadIdx.x * 4;
    for (; i + 3 < end; i += 1024) {
      const float4 v = ldg4(base + i);
      a0 += v.x; a1 += v.y; a2 += v.z; a3 += v.w;
    }
    for (int j = i; j < end && j < i + 4; ++j) a0 += base[j];
    accs[mom] = (a0 + a1) + (a2 + a3);
  }
  rs[threadIdx.x] = accs[0]; rq[threadIdx.x] = accs[1];
  __syncthreads();
  for (int off = 128; off > 0; off >>= 1) {
    if (threadIdx.x < off) {
      rs[threadIdx.x] += rs[threadIdx.x + off];
      rq[threadIdx.x] += rq[threadIdx.x + off];
    }
    __syncthreads();
  }
  if (threadIdx.x == 0) {
    p2[(size_t)(c * 2 + 0) * S + s] = rs[0];
    p2[(size_t)(c * 2 + 1) * S + s] = rq[0];
  }
}

// ------------- BN finalize stage 2 ------------------------------------------
__global__ __launch_bounds__(64)
void k_fin2(const double* __restrict__ p2, int S, double count,
            const float* __restrict__ g, const float* __restrict__ bta,
            float* __restrict__ scale, float* __restrict__ shift) {
  const int c = blockIdx.x, t = threadIdx.x;
  double s = 0.0, sq = 0.0;
  if (t < S) {
    s  = p2[(size_t)(c * 2 + 0) * S + t];
    sq = p2[(size_t)(c * 2 + 1) * S + t];
  }
  #pragma unroll
  for (int m = 1; m < 64; m <<= 1) {
    s  += __shfl_xor(s, m);
    sq += __shfl_xor(sq, m);
  }
  if (t == 0) {
    const double mean = s / count;
    const double var  = sq / count - mean * mean;
    const double rstd = 1.0 / sqrt(var + 1e-5);
    const double sc = (double)g[c] * rstd;
    scale[c] = (float)sc;
    shift[c] = (float)((double)bta[c] - mean * sc);
  }
}

// ------------- bnrelu: x = relu(sc*sel + sh), NHWC ---------------------------
template<int CH, int P>
__global__ __launch_bounds__(256)
void k_bnrelu(const u16* __restrict__ sel, const float* __restrict__ scale,
              const float* __restrict__ shift, u16* __restrict__ xout) {
  constexpr int G = CH / 8;
  const int idx = blockIdx.x * 256 + threadIdx.x;
  const int cg = idx & (G - 1);
  int rest = idx / G;
  const int qo = rest % P; rest /= P;
  const int po = rest % P;
  const int n = rest / P;
  const size_t base = ((size_t)((n * P + po) * P + qo)) * CH + cg * 8;
  const int4 vs = *reinterpret_cast<const int4*>(sel + base);
  const u32* a = reinterpret_cast<const u32*>(&vs);
  u16 o[8];
  #pragma unroll
  for (int j = 0; j < 8; ++j) {
    const int c = cg * 8 + j;
    const float sc = scale[c], sh = shift[c];
    const u16 raw = (u16)(a[j >> 1] >> ((j & 1) * 16));
    o[j] = f2bf(fmaxf(fmaf(bf2f(raw), sc, sh), 0.f));
  }
  u32 pk[4];
  #pragma unroll
  for (int k = 0; k < 4; ++k) pk[k] = (u32)o[2 * k] | ((u32)o[2 * k + 1] << 16);
  *reinterpret_cast<int4*>(xout + base) = make_int4(pk[0], pk[1], pk[2], pk[3]);
}

// ------------- conv2: bf16 MFMA + stats + sel pool ---------------------------
__global__ __launch_bounds__(256)
void k_conv2(const u16* __restrict__ x1, const u16* __restrict__ wt2,
             const float* __restrict__ b2, const float* __restrict__ g2,
             u16* __restrict__ sel2, float* __restrict__ part) {
  const int ow0 = blockIdx.x * 16, oh0 = blockIdx.y * 16, n = blockIdx.z;
  const int t = threadIdx.x, lane = t & 63, wv = t >> 6;
  const int g = lane >> 4, li = lane & 15;
  __shared__ __align__(16) unsigned char tile[18 * 640];
  for (int idx = t; idx < 720; idx += 256) {
    const int rr = idx / 40, rem = idx - rr * 40, p = rem >> 1, c = rem & 1;
    const int ih = oh0 - 1 + rr, iw = ow0 - 1 + p;
    int4 v = make_int4(0, 0, 0, 0);
    if ((unsigned)ih < 112u && (unsigned)iw < 112u)
      v = *reinterpret_cast<const int4*>(x1 + ((size_t)((n * 112 + ih) * 112 + iw) * 16 + c * 8));
    *reinterpret_cast<int4*>(tile + ((rr * 640 + p * 32 + c * 16) ^ (((p >> 2) & 1) << 4))) = v;
  }
  sh8_t W[2][3][2];
  #pragma unroll
  for (int cot = 0; cot < 2; ++cot)
    #pragma unroll
    for (int kh = 0; kh < 3; ++kh)
      #pragma unroll
      for (int m = 0; m < 2; ++m)
        W[cot][kh][m] = *reinterpret_cast<const sh8_t*>(
            wt2 + ((cot * 16 + li) * 192 + kh * 64 + m * 32 + g * 8));
  f4_t acc[4][2];
  #pragma unroll
  for (int r = 0; r < 4; ++r) { acc[r][0] = (f4_t)0.f; acc[r][1] = (f4_t)0.f; }
  __syncthreads();
  const int rowb = 4 * wv;
  #pragma unroll
  for (int ihr = 0; ihr < 6; ++ihr) {
    const int row = rowb + ihr;
    #pragma unroll
    for (int m = 0; m < 2; ++m) {
      const int p = li + 2 * m + (g >> 1);
      const sh8_t B = *reinterpret_cast<const sh8_t*>(
          tile + ((row * 640 + p * 32 + (g & 1) * 16) ^ (((p >> 2) & 1) << 4)));
      #pragma unroll
      for (int kh = 0; kh < 3; ++kh) {
        const int r = ihr - kh;
        if (r >= 0 && r < 4) {
          acc[r][0] = __builtin_amdgcn_mfma_f32_16x16x32_bf16(W[0][kh][m], B, acc[r][0], 0, 0, 0);
          acc[r][1] = __builtin_amdgcn_mfma_f32_16x16x32_bf16(W[1][kh][m], B, acc[r][1], 0, 0, 0);
        }
      }
    }
  }
  f4_t bias[2], gam[2], ssum[2], ssq[2];
  bias[0] = *reinterpret_cast<const f4_t*>(b2 + 4 * g);
  bias[1] = *reinterpret_cast<const f4_t*>(b2 + 16 + 4 * g);
  gam[0]  = *reinterpret_cast<const f4_t*>(g2 + 4 * g);
  gam[1]  = *reinterpret_cast<const f4_t*>(g2 + 16 + 4 * g);
  ssum[0] = (f4_t)0.f; ssum[1] = (f4_t)0.f; ssq[0] = (f4_t)0.f; ssq[1] = (f4_t)0.f;
  #pragma unroll
  for (int r = 0; r < 4; ++r)
    #pragma unroll
    for (int cot = 0; cot < 2; ++cot) {
      acc[r][cot] += bias[cot];
      ssum[cot] += acc[r][cot];
      ssq[cot] += acc[r][cot] * acc[r][cot];
    }
  #pragma unroll
  for (int msk = 1; msk < 16; msk <<= 1)
    #pragma unroll
    for (int cot = 0; cot < 2; ++cot)
      #pragma unroll
      for (int j = 0; j < 4; ++j) {
        ssum[cot][j] += __shfl_xor(ssum[cot][j], msk);
        ssq[cot][j]  += __shfl_xor(ssq[cot][j], msk);
      }
  if (li == 0) {
    const int slot = (((n * 7 + (int)blockIdx.y) * 7 + (int)blockIdx.x)) * 4 + wv;  // 12544
    #pragma unroll
    for (int cot = 0; cot < 2; ++cot)
      #pragma unroll
      for (int j = 0; j < 4; ++j) {
        const int co = cot * 16 + 4 * g + j;
        part[(size_t)(co * 2 + 0) * 12544 + slot] = ssum[cot][j];
        part[(size_t)(co * 2 + 1) * 12544 + slot] = ssq[cot][j];
      }
  }
  const int pob = 8 * (int)blockIdx.y + 2 * wv;
  const int qo = 8 * (int)blockIdx.x + (li >> 1);
  #pragma unroll
  for (int rp = 0; rp < 2; ++rp)
    #pragma unroll
    for (int cot = 0; cot < 2; ++cot) {
      f4_t v;
      #pragma unroll
      for (int j = 0; j < 4; ++j) {
        const float a = acc[2 * rp][cot][j], b = acc[2 * rp + 1][cot][j];
        v[j] = (gam[cot][j] >= 0.f) ? fmaxf(a, b) : fminf(a, b);
      }
      f4_t o;
      #pragma unroll
      for (int j = 0; j < 4; ++j) o[j] = __shfl_xor(v[j], 1);
      if ((li & 1) == 0) {
        u16 pk[4];
        #pragma unroll
        for (int j = 0; j < 4; ++j)
          pk[j] = f2bf((gam[cot][j] >= 0.f) ? fmaxf(v[j], o[j]) : fminf(v[j], o[j]));
        const size_t off = ((size_t)((n * 56 + pob + rp) * 56 + qo)) * 32 + cot * 16 + 4 * g;
        uint2 w;
        w.x = (u32)pk[0] | ((u32)pk[1] << 16);
        w.y = (u32)pk[2] | ((u32)pk[3] << 16);
        *reinterpret_cast<uint2*>(sel2 + off) = w;
      }
    }
}

// ------------- conv3: bf16 MFMA + stats + sel pool ---------------------------
__global__ __launch_bounds__(256)
void k_conv3(const u16* __restrict__ x2, const u16* __restrict__ wt3,
             const float* __restrict__ b3, const float* __restrict__ g3,
             u16* __restrict__ sel3, float* __restrict__ part) {
  const int ow0 = blockIdx.x * 16, oh0 = blockIdx.y * 8, n = blockIdx.z;
  const int t = threadIdx.x, lane = t & 63, wv = t >> 6;
  const int rh = wv & 1, ch = wv >> 1;
  const int g = lane >> 4, li = lane & 15;
  __shared__ __align__(16) unsigned char tile[10 * 1152];
  for (int idx = t; idx < 720; idx += 256) {
    const int rr = idx / 72, rem = idx - rr * 72, p = rem >> 2, c = rem & 3;
    const int ih = oh0 - 1 + rr, iw = ow0 - 1 + p;
    int4 v = make_int4(0, 0, 0, 0);
    if ((unsigned)ih < 56u && (unsigned)iw < 56u)
      v = *reinterpret_cast<const int4*>(x2 + ((size_t)((n * 56 + ih) * 56 + iw) * 32 + c * 8));
    *reinterpret_cast<int4*>(tile + ((rr * 1152 + p * 64 + c * 16) ^ (((p >> 1) & 3) << 4))) = v;
  }
  sh8_t W[2][3][3];
  #pragma unroll
  for (int c2 = 0; c2 < 2; ++c2)
    #pragma unroll
    for (int kh = 0; kh < 3; ++kh)
      #pragma unroll
      for (int kw = 0; kw < 3; ++kw)
        W[c2][kh][kw] = *reinterpret_cast<const sh8_t*>(
            wt3 + ((size_t)(ch * 32 + c2 * 16 + li) * 288 + (kh * 3 + kw) * 32 + g * 8));
  f4_t acc[4][2];
  #pragma unroll
  for (int r = 0; r < 4; ++r) { acc[r][0] = (f4_t)0.f; acc[r][1] = (f4_t)0.f; }
  __syncthreads();
  const int rowb = 4 * rh;
  #pragma unroll
  for (int ihr = 0; ihr < 6; ++ihr) {
    const int row = rowb + ihr;
    #pragma unroll
    for (int kw = 0; kw < 3; ++kw) {
      const int p = li + kw;
      const sh8_t B = *reinterpret_cast<const sh8_t*>(
          tile + ((row * 1152 + p * 64 + g * 16) ^ (((p >> 1) & 3) << 4)));
      #pragma unroll
      for (int kh = 0; kh < 3; ++kh) {
        const int r = ihr - kh;
        if (r >= 0 && r < 4) {
          acc[r][0] = __builtin_amdgcn_mfma_f32_16x16x32_bf16(W[0][kh][kw], B, acc[r][0], 0, 0, 0);
          acc[r][1] = __builtin_amdgcn_mfma_f32_16x16x32_bf16(W[1][kh][kw], B, acc[r][1], 0, 0, 0);
        }
      }
    }
  }
  const int ow = ow0 + li;
  const bool valid = ow < 56;
  f4_t bias[2], gam[2], ssum[2], ssq[2];
  bias[0] = *reinterpret_cast<const f4_t*>(b3 + ch * 32 + 4 * g);
  bias[1] = *reinterpret_cast<const f4_t*>(b3 + ch * 32 + 16 + 4 * g);
  gam[0]  = *reinterpret_cast<const f4_t*>(g3 + ch * 32 + 4 * g);
  gam[1]  = *reinterpret_cast<const f4_t*>(g3 + ch * 32 + 16 + 4 * g);
  ssum[0] = (f4_t)0.f; ssum[1] = (f4_t)0.f; ssq[0] = (f4_t)0.f; ssq[1] = (f4_t)0.f;
  #pragma unroll
  for (int r = 0; r < 4; ++r)
    #pragma unroll
    for (int c2 = 0; c2 < 2; ++c2) {
      acc[r][c2] += bias[c2];
      if (valid) {
        ssum[c2] += acc[r][c2];
        ssq[c2] += acc[r][c2] * acc[r][c2];
      }
    }
  #pragma unroll
  for (int msk = 1; msk < 16; msk <<= 1)
    #pragma unroll
    for (int c2 = 0; c2 < 2; ++c2)
      #pragma unroll
      for (int j = 0; j < 4; ++j) {
        ssum[c2][j] += __shfl_xor(ssum[c2][j], msk);
        ssq[c2][j]  += __shfl_xor(ssq[c2][j], msk);
      }
  if (li == 0) {
    const int slot = (((n * 7 + (int)blockIdx.y) * 4 + (int)blockIdx.x)) * 2 + rh;  // 3584
    #pragma unroll
    for (int c2 = 0; c2 < 2; ++c2)
      #pragma unroll
      for (int j = 0; j < 4; ++j) {
        const int co = ch * 32 + c2 * 16 + 4 * g + j;
        part[(size_t)(co * 2 + 0) * 3584 + slot] = ssum[c2][j];
        part[(size_t)(co * 2 + 1) * 3584 + slot] = ssq[c2][j];
      }
  }
  const int pob = 4 * (int)blockIdx.y + 2 * rh;
  const int qo = 8 * (int)blockIdx.x + (li >> 1);
  #pragma unroll
  for (int rp = 0; rp < 2; ++rp)
    #pragma unroll
    for (int c2 = 0; c2 < 2; ++c2) {
      f4_t v;
      #pragma unroll
      for (int j = 0; j < 4; ++j) {
        const float a = acc[2 * rp][c2][j], b = acc[2 * rp + 1][c2][j];
        v[j] = (gam[c2][j] >= 0.f) ? fmaxf(a, b) : fminf(a, b);
      }
      f4_t o;
      #pragma unroll
      for (int j = 0; j < 4; ++j) o[j] = __shfl_xor(v[j], 1);
      if (((li & 1) == 0) && (ow + 1 < 56)) {
        u16 pk[4];
        #pragma unroll
        for (int j = 0; j < 4; ++j)
          pk[j] = f2bf((gam[c2][j] >= 0.f) ? fmaxf(v[j], o[j]) : fminf(v[j], o[j]));
        const size_t off = ((size_t)((n * 28 + pob + rp) * 28 + qo)) * 64 + ch * 32 + c2 * 16 + 4 * g;
        uint2 w;
        w.x = (u32)pk[0] | ((u32)pk[1] << 16);
        w.y = (u32)pk[2] | ((u32)pk[3] << 16);
        *reinterpret_cast<uint2*>(sel3 + off) = w;
      }
    }
}

// ------------- bnrelu3 + NHWC->NCHW transpose for fc1 -----------------------
__global__ __launch_bounds__(256)
void k_bnrelu3t(const u16* __restrict__ sel3, const float* __restrict__ scale,
                const float* __restrict__ shift, u16* __restrict__ x3t) {
  const int n = blockIdx.y;
  const int c = threadIdx.x & 63, pq = threadIdx.x >> 6;
  const int po = blockIdx.x * 4 + pq;
  const float sc = scale[c], sh = shift[c];
  const size_t row0 = ((size_t)(n * 28 + po)) * 28 * 64 + c;
  #pragma unroll
  for (int q4 = 0; q4 < 7; ++q4) {
    u16 pk[4];
    #pragma unroll
    for (int i = 0; i < 4; ++i) {
      const int qo = q4 * 4 + i;
      const u16 raw = sel3[row0 + (size_t)qo * 64];
      pk[i] = f2bf(fmaxf(fmaf(bf2f(raw), sc, sh), 0.f));
    }
    uint2 w;
    w.x = (u32)pk[0] | ((u32)pk[1] << 16);
    w.y = (u32)pk[2] | ((u32)pk[3] << 16);
    *reinterpret_cast<uint2*>(x3t + (((size_t)(n * 64 + c) * 28 + po) * 28 + q4 * 4)) = w;
  }
}

// ------------- fc1: zero-LDS MFMA K-split GEMM (56 splits x 896 k) ----------
__global__ __launch_bounds__(256)
void k_fc1(const u16* __restrict__ x3t, const float* __restrict__ w,
           float* __restrict__ partial) {
  const int kc = blockIdx.x, nt = blockIdx.y;
  const int t = threadIdx.x, lane = t & 63, wv = t >> 6;
  const int g = lane >> 4, li = lane & 15;
  const int n0 = nt * 64 + wv * 16;
  const float* wrow = w + (size_t)(n0 + li) * 50176 + kc * 896;
  const u16* xbase = x3t + kc * 896;
  f4_t acc[4];
  #pragma unroll
  for (int mf = 0; mf < 4; ++mf) acc[mf] = (f4_t)0.f;
  #pragma unroll 4
  for (int ks = 0; ks < 28; ++ks) {
    const int kb = ks * 32 + g * 8;
    const float4 wa = ldg4(wrow + kb);
    const float4 wb = ldg4(wrow + kb + 4);
    float wf[8] = {wa.x, wa.y, wa.z, wa.w, wb.x, wb.y, wb.z, wb.w};
    sh8_t hi, lo;
    #pragma unroll
    for (int j = 0; j < 8; ++j) {
      const u16 h = f2bf(wf[j]);
      hi[j] = (short)h;
      lo[j] = (short)f2bf(wf[j] - bf2f(h));
    }
    #pragma unroll
    for (int mf = 0; mf < 4; ++mf) {
      const sh8_t B = *reinterpret_cast<const sh8_t*>(
          xbase + (size_t)(mf * 16 + li) * 50176 + kb);
      acc[mf] = __builtin_amdgcn_mfma_f32_16x16x32_bf16(hi, B, acc[mf], 0, 0, 0);
      acc[mf] = __builtin_amdgcn_mfma_f32_16x16x32_bf16(lo, B, acc[mf], 0, 0, 0);
    }
  }
  float* pb = partial + (size_t)kc * 16384;
  #pragma unroll
  for (int mf = 0; mf < 4; ++mf)
    #pragma unroll
    for (int j = 0; j < 4; ++j)
      pb[(size_t)(n0 + 4 * g + j) * 64 + mf * 16 + li] = acc[mf][j];
}

__global__ __launch_bounds__(256)
void k_fc1_reduce(const float* __restrict__ partial, const float* __restrict__ b1f,
                  float* __restrict__ h1) {
  const int idx = blockIdx.x * 256 + threadIdx.x;  // 16384
  const int nn = idx >> 6, m = idx & 63;
  float a[8];
  #pragma unroll
  for (int u = 0; u < 8; ++u) a[u] = 0.f;
  #pragma unroll
  for (int k = 0; k < 56; k += 8)
    #pragma unroll
    for (int u = 0; u < 8; ++u)
      a[u] += partial[(size_t)(k + u) * 16384 + idx];
  const float s = b1f[nn] + (((a[0] + a[1]) + (a[2] + a[3])) +
                             ((a[4] + a[5]) + (a[6] + a[7])));
  h1[(size_t)m * 256 + nn] = fmaxf(s, 0.f);
}

__global__ __launch_bounds__(320)
void k_fc2(const float* __restrict__ h1, const float* __restrict__ w2f,
           const float* __restrict__ b2f, float* __restrict__ out) {
  const int t = threadIdx.x;
  const int m = t / 5, o = t - m * 5;
  const float* hr = h1 + (size_t)m * 256;
  const float* wr = w2f + (size_t)o * 256;
  float a0 = 0.f, a1 = 0.f, a2 = 0.f, a3 = 0.f;
  #pragma unroll
  for (int j = 0; j < 256; j += 16) {
    const float4 h0 = ldg4(hr + j),      w0 = ldg4(wr + j);
    const float4 h1v = ldg4(hr + j + 4),  w1v = ldg4(wr + j + 4);
    const float4 h2 = ldg4(hr + j + 8),  w2 = ldg4(wr + j + 8);
    const float4 h3 = ldg4(hr + j + 12), w3 = ldg4(wr + j + 12);
    a0 = fmaf(h0.x, w0.x, fmaf(h0.y, w0.y, fmaf(h0.z, w0.z, fmaf(h0.w, w0.w, a0))));
    a1 = fmaf(h1v.x, w1v.x, fmaf(h1v.y, w1v.y, fmaf(h1v.z, w1v.z, fmaf(h1v.w, w1v.w, a1))));
    a2 = fmaf(h2.x, w2.x, fmaf(h2.y, w2.y, fmaf(h2.z, w2.z, fmaf(h2.w, w2.w, a2))));
    a3 = fmaf(h3.x, w3.x, fmaf(h3.y, w3.y, fmaf(h3.z, w3.z, fmaf(h3.w, w3.w, a3))));
  }
  out[m * 5 + o] = b2f[o] + ((a0 + a1) + (a2 + a3));
}

// ---------------------------------------------------------------------------
extern "C" void kernel_launch(void* const* d_in, const int* in_sizes, int n_in,
                              void* d_out, int out_size, void* d_ws, size_t ws_size,
                              hipStream_t stream) {
  (void)in_sizes; (void)n_in; (void)out_size; (void)ws_size;
  const float* d   = (const float*)d_in[0];
  const float* w1  = (const float*)d_in[1];
  const float* b1  = (const float*)d_in[2];
  const float* g1  = (const float*)d_in[3];
  const float* be1 = (const float*)d_in[4];
  const float* w2  = (const float*)d_in[5];
  const float* b2  = (const float*)d_in[6];
  const float* g2  = (const float*)d_in[7];
  const float* be2 = (const float*)d_in[8];
  const float* w3  = (const float*)d_in[9];
  const float* b3  = (const float*)d_in[10];
  const float* g3  = (const float*)d_in[11];
  const float* be3 = (const float*)d_in[12];
  const float* fw1 = (const float*)d_in[13];
  const float* fb1 = (const float*)d_in[14];
  const float* fw2 = (const float*)d_in[15];
  const float* fb2 = (const float*)d_in[16];
  float* out = (float*)d_out;
  float* ws  = (float*)d_ws;

  u16* sel1 = (u16*)(ws + WS_SEL1);
  u16* x1   = (u16*)(ws + WS_X1);
  u16* rec  = (u16*)(ws + WS_REC);   // aliases X1+X2+SEL2 (all written later)
  u16* x2   = (u16*)(ws + WS_X2);
  u16* sel2 = (u16*)(ws + WS_SEL2);
  u16* x3t  = (u16*)(ws + WS_X3T);
  u16* sel3 = (u16*)(ws + WS_SEL3);
  u16* wt1  = (u16*)(ws + WS_WT1);
  u16* wt2  = (u16*)(ws + WS_WT2);
  u16* wt3  = (u16*)(ws + WS_WT3);
  float* cp = ws + WS_CP;
  float* p2 = ws + WS_P2;
  float* p3 = ws + WS_P3;
  double* pd = (double*)(ws + WS_PD);  // pd45 first, then reused by fin1
  float* st = ws + WS_ST;
  float* fcp = ws + WS_FCP;
  float* h1 = ws + WS_H1;

  k_prep_w<<<100, 256, 0, stream>>>(w1, w2, w3, wt1, wt2, wt3);
  // layer 1: corr (stats source + records), analytic stats, conv+pool, bnrelu
  k_corr<<<1568, 256, 0, stream>>>(d, rec, cp);
  k_corr_fin<<<45, 256, 0, stream>>>(cp, pd);
  k_stats1<<<1, 64, 0, stream>>>(pd, w1, b1, g1, be1, st + 0, st + 16);
  k_conv1<<<dim3(14, 14, 64), 256, 0, stream>>>(rec, wt1, b1, g1, sel1);
  k_bnrelu<16, 112><<<6272, 256, 0, stream>>>(sel1, st + 0, st + 16, x1);
  // layer 2
  k_conv2<<<dim3(7, 7, 64), 256, 0, stream>>>(x1, wt2, b2, g2, sel2, p2);
  k_fin1<<<dim3(32, 16), 256, 0, stream>>>(p2, 12544, 784, 16, pd);
  k_fin2<<<32, 64, 0, stream>>>(pd, 16, 802816.0, g2, be2, st + 32, st + 64);
  k_bnrelu<32, 56><<<3136, 256, 0, stream>>>(sel2, st + 32, st + 64, x2);
  // layer 3
  k_conv3<<<dim3(4, 7, 64), 256, 0, stream>>>(x2, wt3, b3, g3, sel3, p3);
  k_fin1<<<dim3(64, 8), 256, 0, stream>>>(p3, 3584, 448, 8, pd);
  k_fin2<<<64, 64, 0, stream>>>(pd, 8, 200704.0, g3, be3, st + 96, st + 160);
  k_bnrelu3t<<<dim3(7, 64), 256, 0, stream>>>(sel3, st + 96, st + 160, x3t);
  // fc
  k_fc1<<<dim3(56, 4), 256, 0, stream>>>(x3t, fw1, fcp);
  k_fc1_reduce<<<64, 256, 0, stream>>>(fcp, fb1, h1);
  k_fc2<<<1, 320, 0, stream>>>(h1, fw2, fb2, out);
}

// Round 14
// 170.670 us; speedup vs baseline: 1.2536x; 1.2062x over previous
//
#include <hip/hip_runtime.h>
#include <cstdint>
#include <cstddef>

// ---------------------------------------------------------------------------
// Plant_Identifier CNN forward.
// R14: REVERT analytic-stats experiment (k_corr latency-bound at ~62us in 3
//      variants; gate triggered). Layer 1 = R10's fused conv1 (in-register
//      hi/lo build + stats + sel pool, 61us measured best).
//      NEW: bnrelu1/bnrelu2 kernels deleted — BN+ReLU folded into the next
//      conv's LDS staging (bit-identical numerics, saves two HBM round trips
//      + two launches).
// R10: sel-trick (sign(gamma) known pre-stats -> single pooled buffer).
// conv2/3: bf16 MFMA implicit-GEMM, fused stats + sel pool, BN-inline stage.
// fc1: zero-LDS MFMA K-split. All reductions deterministic.
// ---------------------------------------------------------------------------

typedef __attribute__((ext_vector_type(8))) short sh8_t;   // 8 x bf16
typedef __attribute__((ext_vector_type(4))) float f4_t;    // mfma acc
typedef unsigned short u16;
typedef unsigned int u32;

// workspace layout (float units) — no aliasing
#define WS_SEL1 ((size_t)0)          // sel1 bf16 [64,112,112,16] (6,422,528)
#define WS_SEL2 ((size_t)6422528)    // sel2 bf16 [64,56,56,32]   (3,211,264)
#define WS_X3T  ((size_t)9633792)    // x3t  bf16 [64,64,28,28]   (1,605,632)
#define WS_SEL3 ((size_t)11239424)   // sel3 bf16 [64,28,28,64]   (1,605,632)
#define WS_WT1  ((size_t)12845056)   // 512
#define WS_WT2  ((size_t)12845568)   // 3,072
#define WS_WT3  ((size_t)12848640)   // 9,216
#define WS_P1   ((size_t)12857856)   // 16*2*57600 = 1,843,200
#define WS_P2   ((size_t)14701056)   // 32*2*12544 = 802,816
#define WS_P3   ((size_t)15503872)   // 64*2*3584  = 458,752
#define WS_PD   ((size_t)15962624)   // 4,096
#define WS_ST   ((size_t)15966720)   // 224
#define WS_FCP  ((size_t)15966944)   // 917,504
#define WS_H1   ((size_t)16884448)   // 16,384
// total 16,900,832 floats = 67.6 MB

static __device__ __forceinline__ float4 ldg4(const float* p) {
  return *reinterpret_cast<const float4*>(p);
}
static __device__ __forceinline__ float bf2f(u16 u) {
  union { u32 i; float f; } c; c.i = ((u32)u) << 16; return c.f;
}
static __device__ __forceinline__ u16 f2bf(float f) {
  union { float f; u32 i; } c; c.f = f;
  const u32 x = c.i;
  return (u16)((x + 0x7fffu + ((x >> 16) & 1u)) >> 16);   // RNE
}

// ---------------- weight prep -----------------------------------------------
__global__ __launch_bounds__(256)
void k_prep_w(const float* __restrict__ w1, const float* __restrict__ w2,
              const float* __restrict__ w3, u16* __restrict__ wt1,
              u16* __restrict__ wt2, u16* __restrict__ wt3) {
  const int t = blockIdx.x * 256 + threadIdx.x;  // 25600 total
  if (t < 1024) {
    const int half = t >> 9;
    const int u = t & 511;
    const int co = u >> 5, k = u & 31;
    const int g = k >> 3, j = k & 7;
    const int kh = g >> 1, kw = g & 1;
    const int ci = (j < 4) ? j : j - 4;
    bool active = (j != 3) && (j != 7);
    if (half == 1) active = active && (j < 4);
    float val = 0.f;
    if (active) {
      const float w = w1[((co * 3 + ci) * 2 + kh) * 2 + kw];
      const u16 h = f2bf(w);
      val = (half == 0) ? bf2f(h) : (w - bf2f(h));
    }
    wt1[t] = f2bf(val);
  } else if (t < 7168) {  // wt2 [co32][kh3][kwp4][ci16], kw=3 zero-padded
    const int u = t - 1024;
    const int ci = u & 15, kwp = (u >> 4) & 3, kh = (u >> 6) % 3, co = u / 192;
    float v = 0.f;
    if (kwp < 3) v = w2[((co * 16 + ci) * 3 + kh) * 3 + kwp];
    wt2[u] = f2bf(v);
  } else {                // wt3 [co64][kh3][kw3][ci32]
    const int u = t - 7168;
    const int ci = u & 31, kw = (u >> 5) % 3, kh = (u / 96) % 3, co = u / 288;
    wt3[u] = f2bf(w3[((co * 32 + ci) * 3 + kh) * 3 + kw]);
  }
}

// ---------------- conv1 MFMA: in-register B build, stats + sel pool ---------
// grid (15,15,64), 256 thr. 16x16 output tile of the 225x225 pre-pool map.
__global__ __launch_bounds__(256)
void k_conv1(const float* __restrict__ d, const u16* __restrict__ wt1,
             const float* __restrict__ b1, const float* __restrict__ g1,
             u16* __restrict__ sel1, float* __restrict__ part) {
  const int bx = blockIdx.x, by = blockIdx.y, n = blockIdx.z;
  const int ow0 = bx * 16, oh0 = by * 16;
  const int t = threadIdx.x, lane = t & 63, wv = t >> 6;
  const int g = lane >> 4, li = lane & 15;
  const int kh = g >> 1, kw = g & 1;
  const sh8_t A1 = *reinterpret_cast<const sh8_t*>(wt1 + li * 32 + g * 8);
  const sh8_t A2 = *reinterpret_cast<const sh8_t*>(wt1 + 512 + li * 32 + g * 8);
  const int iw = ow0 + li + kw - 1;
  const bool iwv = (unsigned)iw < 224u;
  const float* dbase = d + (size_t)n * 3 * 50176 + iw;
  f4_t acc[4];
  #pragma unroll
  for (int r = 0; r < 4; ++r) acc[r] = (f4_t)0.f;
  #pragma unroll
  for (int r = 0; r < 4; ++r) {
    const int ih = oh0 + wv * 4 + r + kh - 1;
    float v0 = 0.f, v1 = 0.f, v2 = 0.f;
    if (iwv && (unsigned)ih < 224u) {
      const float* p = dbase + (size_t)ih * 224;
      v0 = p[0]; v1 = p[50176]; v2 = p[100352];
    }
    const u16 h0 = f2bf(v0), h1 = f2bf(v1), h2 = f2bf(v2);
    const u16 l0 = f2bf(v0 - bf2f(h0));
    const u16 l1 = f2bf(v1 - bf2f(h1));
    const u16 l2 = f2bf(v2 - bf2f(h2));
    union { sh8_t v; u32 w[4]; } B;
    B.w[0] = (u32)h0 | ((u32)h1 << 16);
    B.w[1] = (u32)h2;
    B.w[2] = (u32)l0 | ((u32)l1 << 16);
    B.w[3] = (u32)l2;
    acc[r] = __builtin_amdgcn_mfma_f32_16x16x32_bf16(A1, B.v, acc[r], 0, 0, 0);
    acc[r] = __builtin_amdgcn_mfma_f32_16x16x32_bf16(A2, B.v, acc[r], 0, 0, 0);
  }
  // D: col = li (pixel ow), row = 4g+j (co). y = acc + bias.
  const f4_t bias = *reinterpret_cast<const f4_t*>(b1 + 4 * g);
  const f4_t gam  = *reinterpret_cast<const f4_t*>(g1 + 4 * g);
  f4_t y[4];
  #pragma unroll
  for (int r = 0; r < 4; ++r) y[r] = acc[r] + bias;
  const int ow = ow0 + li;
  // stats over valid 225x225
  {
    f4_t ssum = (f4_t)0.f, ssq = (f4_t)0.f;
    #pragma unroll
    for (int r = 0; r < 4; ++r) {
      const int oh = oh0 + wv * 4 + r;
      if (oh <= 224 && ow <= 224) { ssum += y[r]; ssq += y[r] * y[r]; }
    }
    #pragma unroll
    for (int m = 1; m < 16; m <<= 1)
      #pragma unroll
      for (int j = 0; j < 4; ++j) {
        ssum[j] += __shfl_xor(ssum[j], m);
        ssq[j]  += __shfl_xor(ssq[j], m);
      }
    if (li == 0) {
      const int slot = ((n * 15 + by) * 15 + bx) * 4 + wv;  // P1 = 57600
      #pragma unroll
      for (int j = 0; j < 4; ++j) {
        part[(size_t)((4 * g + j) * 2 + 0) * 57600 + slot] = ssum[j];
        part[(size_t)((4 * g + j) * 2 + 1) * 57600 + slot] = ssq[j];
      }
    }
  }
  // sel pool: per channel, window extremum matching sign(gamma)
  if (bx < 14 && by < 14) {
    #pragma unroll
    for (int rp = 0; rp < 2; ++rp) {
      f4_t v;
      #pragma unroll
      for (int j = 0; j < 4; ++j) {
        const float a = y[2 * rp][j], b = y[2 * rp + 1][j];
        v[j] = (gam[j] >= 0.f) ? fmaxf(a, b) : fminf(a, b);
      }
      f4_t o;
      #pragma unroll
      for (int j = 0; j < 4; ++j) o[j] = __shfl_xor(v[j], 1);
      if ((li & 1) == 0) {
        u16 pk[4];
        #pragma unroll
        for (int j = 0; j < 4; ++j)
          pk[j] = f2bf((gam[j] >= 0.f) ? fmaxf(v[j], o[j]) : fminf(v[j], o[j]));
        const int po = 8 * by + 2 * wv + rp, qo = 8 * bx + (li >> 1);
        const size_t off = ((size_t)((n * 112 + po) * 112 + qo)) * 16 + 4 * g;
        uint2 w;
        w.x = (u32)pk[0] | ((u32)pk[1] << 16);
        w.y = (u32)pk[2] | ((u32)pk[3] << 16);
        *reinterpret_cast<uint2*>(sel1 + off) = w;
      }
    }
  }
}

// ------------- BN finalize stage 1: parallel chunk reduce -------------------
__global__ __launch_bounds__(256)
void k_fin1(const float* __restrict__ part, int P, int chunk, int S,
            double* __restrict__ p2) {
  const int c = blockIdx.x, s = blockIdx.y;
  const int start = s * chunk;
  const int end = min(P, start + chunk);
  __shared__ double rs[256], rq[256];
  double accs[2];
  #pragma unroll
  for (int mom = 0; mom < 2; ++mom) {
    const float* base = part + (size_t)(c * 2 + mom) * P;
    double a0 = 0.0, a1 = 0.0, a2 = 0.0, a3 = 0.0;
    int i = start + threadIdx.x * 4;
    for (; i + 3 < end; i += 1024) {
      const float4 v = ldg4(base + i);
      a0 += v.x; a1 += v.y; a2 += v.z; a3 += v.w;
    }
    for (int j = i; j < end && j < i + 4; ++j) a0 += base[j];
    accs[mom] = (a0 + a1) + (a2 + a3);
  }
  rs[threadIdx.x] = accs[0]; rq[threadIdx.x] = accs[1];
  __syncthreads();
  for (int off = 128; off > 0; off >>= 1) {
    if (threadIdx.x < off) {
      rs[threadIdx.x] += rs[threadIdx.x + off];
      rq[threadIdx.x] += rq[threadIdx.x + off];
    }
    __syncthreads();
  }
  if (threadIdx.x == 0) {
    p2[(size_t)(c * 2 + 0) * S + s] = rs[0];
    p2[(size_t)(c * 2 + 1) * S + s] = rq[0];
  }
}

// ------------- BN finalize stage 2 ------------------------------------------
__global__ __launch_bounds__(64)
void k_fin2(const double* __restrict__ p2, int S, double count,
            const float* __restrict__ g, const float* __restrict__ bta,
            float* __restrict__ scale, float* __restrict__ shift) {
  const int c = blockIdx.x, t = threadIdx.x;
  double s = 0.0, sq = 0.0;
  if (t < S) {
    s  = p2[(size_t)(c * 2 + 0) * S + t];
    sq = p2[(size_t)(c * 2 + 1) * S + t];
  }
  #pragma unroll
  for (int m = 1; m < 64; m <<= 1) {
    s  += __shfl_xor(s, m);
    sq += __shfl_xor(sq, m);
  }
  if (t == 0) {
    const double mean = s / count;
    const double var  = sq / count - mean * mean;
    const double rstd = 1.0 / sqrt(var + 1e-5);
    const double sc = (double)g[c] * rstd;
    scale[c] = (float)sc;
    shift[c] = (float)((double)bta[c] - mean * sc);
  }
}

// ------------- conv2: BN1-inline staging + bf16 MFMA + stats + sel pool -----
// bn1: scale at bn1[0..15], shift at bn1[16..31].
__global__ __launch_bounds__(256)
void k_conv2(const u16* __restrict__ sel1, const float* __restrict__ bn1,
             const u16* __restrict__ wt2, const float* __restrict__ b2,
             const float* __restrict__ g2, u16* __restrict__ sel2,
             float* __restrict__ part) {
  const int ow0 = blockIdx.x * 16, oh0 = blockIdx.y * 16, n = blockIdx.z;
  const int t = threadIdx.x, lane = t & 63, wv = t >> 6;
  const int g = lane >> 4, li = lane & 15;
  __shared__ __align__(16) unsigned char tile[18 * 640];
  for (int idx = t; idx < 720; idx += 256) {
    const int rr = idx / 40, rem = idx - rr * 40, p = rem >> 1, c = rem & 1;
    const int ih = oh0 - 1 + rr, iw = ow0 - 1 + p;
    int4 v = make_int4(0, 0, 0, 0);
    if ((unsigned)ih < 112u && (unsigned)iw < 112u) {
      const int4 s = *reinterpret_cast<const int4*>(
          sel1 + ((size_t)((n * 112 + ih) * 112 + iw) * 16 + c * 8));
      const u32* a = reinterpret_cast<const u32*>(&s);
      const float4 scA = ldg4(bn1 + c * 8),      scB = ldg4(bn1 + c * 8 + 4);
      const float4 shA = ldg4(bn1 + 16 + c * 8), shB = ldg4(bn1 + 16 + c * 8 + 4);
      const float sc[8] = {scA.x, scA.y, scA.z, scA.w, scB.x, scB.y, scB.z, scB.w};
      const float sh[8] = {shA.x, shA.y, shA.z, shA.w, shB.x, shB.y, shB.z, shB.w};
      u16 o[8];
      #pragma unroll
      for (int j = 0; j < 8; ++j) {
        const u16 raw = (u16)(a[j >> 1] >> ((j & 1) * 16));
        o[j] = f2bf(fmaxf(fmaf(bf2f(raw), sc[j], sh[j]), 0.f));
      }
      v.x = (u32)o[0] | ((u32)o[1] << 16);
      v.y = (u32)o[2] | ((u32)o[3] << 16);
      v.z = (u32)o[4] | ((u32)o[5] << 16);
      v.w = (u32)o[6] | ((u32)o[7] << 16);
    }
    *reinterpret_cast<int4*>(tile + ((rr * 640 + p * 32 + c * 16) ^ (((p >> 2) & 1) << 4))) = v;
  }
  sh8_t W[2][3][2];
  #pragma unroll
  for (int cot = 0; cot < 2; ++cot)
    #pragma unroll
    for (int kh = 0; kh < 3; ++kh)
      #pragma unroll
      for (int m = 0; m < 2; ++m)
        W[cot][kh][m] = *reinterpret_cast<const sh8_t*>(
            wt2 + ((cot * 16 + li) * 192 + kh * 64 + m * 32 + g * 8));
  f4_t acc[4][2];
  #pragma unroll
  for (int r = 0; r < 4; ++r) { acc[r][0] = (f4_t)0.f; acc[r][1] = (f4_t)0.f; }
  __syncthreads();
  const int rowb = 4 * wv;
  #pragma unroll
  for (int ihr = 0; ihr < 6; ++ihr) {
    const int row = rowb + ihr;
    #pragma unroll
    for (int m = 0; m < 2; ++m) {
      const int p = li + 2 * m + (g >> 1);
      const sh8_t B = *reinterpret_cast<const sh8_t*>(
          tile + ((row * 640 + p * 32 + (g & 1) * 16) ^ (((p >> 2) & 1) << 4)));
      #pragma unroll
      for (int kh = 0; kh < 3; ++kh) {
        const int r = ihr - kh;
        if (r >= 0 && r < 4) {
          acc[r][0] = __builtin_amdgcn_mfma_f32_16x16x32_bf16(W[0][kh][m], B, acc[r][0], 0, 0, 0);
          acc[r][1] = __builtin_amdgcn_mfma_f32_16x16x32_bf16(W[1][kh][m], B, acc[r][1], 0, 0, 0);
        }
      }
    }
  }
  f4_t bias[2], gam[2], ssum[2], ssq[2];
  bias[0] = *reinterpret_cast<const f4_t*>(b2 + 4 * g);
  bias[1] = *reinterpret_cast<const f4_t*>(b2 + 16 + 4 * g);
  gam[0]  = *reinterpret_cast<const f4_t*>(g2 + 4 * g);
  gam[1]  = *reinterpret_cast<const f4_t*>(g2 + 16 + 4 * g);
  ssum[0] = (f4_t)0.f; ssum[1] = (f4_t)0.f; ssq[0] = (f4_t)0.f; ssq[1] = (f4_t)0.f;
  #pragma unroll
  for (int r = 0; r < 4; ++r)
    #pragma unroll
    for (int cot = 0; cot < 2; ++cot) {
      acc[r][cot] += bias[cot];
      ssum[cot] += acc[r][cot];
      ssq[cot] += acc[r][cot] * acc[r][cot];
    }
  #pragma unroll
  for (int msk = 1; msk < 16; msk <<= 1)
    #pragma unroll
    for (int cot = 0; cot < 2; ++cot)
      #pragma unroll
      for (int j = 0; j < 4; ++j) {
        ssum[cot][j] += __shfl_xor(ssum[cot][j], msk);
        ssq[cot][j]  += __shfl_xor(ssq[cot][j], msk);
      }
  if (li == 0) {
    const int slot = (((n * 7 + (int)blockIdx.y) * 7 + (int)blockIdx.x)) * 4 + wv;  // 12544
    #pragma unroll
    for (int cot = 0; cot < 2; ++cot)
      #pragma unroll
      for (int j = 0; j < 4; ++j) {
        const int co = cot * 16 + 4 * g + j;
        part[(size_t)(co * 2 + 0) * 12544 + slot] = ssum[cot][j];
        part[(size_t)(co * 2 + 1) * 12544 + slot] = ssq[cot][j];
      }
  }
  const int pob = 8 * (int)blockIdx.y + 2 * wv;
  const int qo = 8 * (int)blockIdx.x + (li >> 1);
  #pragma unroll
  for (int rp = 0; rp < 2; ++rp)
    #pragma unroll
    for (int cot = 0; cot < 2; ++cot) {
      f4_t v;
      #pragma unroll
      for (int j = 0; j < 4; ++j) {
        const float a = acc[2 * rp][cot][j], b = acc[2 * rp + 1][cot][j];
        v[j] = (gam[cot][j] >= 0.f) ? fmaxf(a, b) : fminf(a, b);
      }
      f4_t o;
      #pragma unroll
      for (int j = 0; j < 4; ++j) o[j] = __shfl_xor(v[j], 1);
      if ((li & 1) == 0) {
        u16 pk[4];
        #pragma unroll
        for (int j = 0; j < 4; ++j)
          pk[j] = f2bf((gam[cot][j] >= 0.f) ? fmaxf(v[j], o[j]) : fminf(v[j], o[j]));
        const size_t off = ((size_t)((n * 56 + pob + rp) * 56 + qo)) * 32 + cot * 16 + 4 * g;
        uint2 w;
        w.x = (u32)pk[0] | ((u32)pk[1] << 16);
        w.y = (u32)pk[2] | ((u32)pk[3] << 16);
        *reinterpret_cast<uint2*>(sel2 + off) = w;
      }
    }
}

// ------------- conv3: BN2-inline staging + bf16 MFMA + stats + sel pool -----
// bn2: scale at bn2[0..31], shift at bn2[32..63].
__global__ __launch_bounds__(256)
void k_conv3(const u16* __restrict__ sel2, const float* __restrict__ bn2,
             const u16* __restrict__ wt3, const float* __restrict__ b3,
             const float* __restrict__ g3, u16* __restrict__ sel3,
             float* __restrict__ part) {
  const int ow0 = blockIdx.x * 16, oh0 = blockIdx.y * 8, n = blockIdx.z;
  const int t = threadIdx.x, lane = t & 63, wv = t >> 6;
  const int rh = wv & 1, ch = wv >> 1;
  const int g = lane >> 4, li = lane & 15;
  __shared__ __align__(16) unsigned char tile[10 * 1152];
  for (int idx = t; idx < 720; idx += 256) {
    const int rr = idx / 72, rem = idx - rr * 72, p = rem >> 2, c = rem & 3;
    const int ih = oh0 - 1 + rr, iw = ow0 - 1 + p;
    int4 v = make_int4(0, 0, 0, 0);
    if ((unsigned)ih < 56u && (unsigned)iw < 56u) {
      const int4 s = *reinterpret_cast<const int4*>(
          sel2 + ((size_t)((n * 56 + ih) * 56 + iw) * 32 + c * 8));
      const u32* a = reinterpret_cast<const u32*>(&s);
      const float4 scA = ldg4(bn2 + c * 8),      scB = ldg4(bn2 + c * 8 + 4);
      const float4 shA = ldg4(bn2 + 32 + c * 8), shB = ldg4(bn2 + 32 + c * 8 + 4);
      const float sc[8] = {scA.x, scA.y, scA.z, scA.w, scB.x, scB.y, scB.z, scB.w};
      const float sh[8] = {shA.x, shA.y, shA.z, shA.w, shB.x, shB.y, shB.z, shB.w};
      u16 o[8];
      #pragma unroll
      for (int j = 0; j < 8; ++j) {
        const u16 raw = (u16)(a[j >> 1] >> ((j & 1) * 16));
        o[j] = f2bf(fmaxf(fmaf(bf2f(raw), sc[j], sh[j]), 0.f));
      }
      v.x = (u32)o[0] | ((u32)o[1] << 16);
      v.y = (u32)o[2] | ((u32)o[3] << 16);
      v.z = (u32)o[4] | ((u32)o[5] << 16);
      v.w = (u32)o[6] | ((u32)o[7] << 16);
    }
    *reinterpret_cast<int4*>(tile + ((rr * 1152 + p * 64 + c * 16) ^ (((p >> 1) & 3) << 4))) = v;
  }
  sh8_t W[2][3][3];
  #pragma unroll
  for (int c2 = 0; c2 < 2; ++c2)
    #pragma unroll
    for (int kh = 0; kh < 3; ++kh)
      #pragma unroll
      for (int kw = 0; kw < 3; ++kw)
        W[c2][kh][kw] = *reinterpret_cast<const sh8_t*>(
            wt3 + ((size_t)(ch * 32 + c2 * 16 + li) * 288 + (kh * 3 + kw) * 32 + g * 8));
  f4_t acc[4][2];
  #pragma unroll
  for (int r = 0; r < 4; ++r) { acc[r][0] = (f4_t)0.f; acc[r][1] = (f4_t)0.f; }
  __syncthreads();
  const int rowb = 4 * rh;
  #pragma unroll
  for (int ihr = 0; ihr < 6; ++ihr) {
    const int row = rowb + ihr;
    #pragma unroll
    for (int kw = 0; kw < 3; ++kw) {
      const int p = li + kw;
      const sh8_t B = *reinterpret_cast<const sh8_t*>(
          tile + ((row * 1152 + p * 64 + g * 16) ^ (((p >> 1) & 3) << 4)));
      #pragma unroll
      for (int kh = 0; kh < 3; ++kh) {
        const int r = ihr - kh;
        if (r >= 0 && r < 4) {
          acc[r][0] = __builtin_amdgcn_mfma_f32_16x16x32_bf16(W[0][kh][kw], B, acc[r][0], 0, 0, 0);
          acc[r][1] = __builtin_amdgcn_mfma_f32_16x16x32_bf16(W[1][kh][kw], B, acc[r][1], 0, 0, 0);
        }
      }
    }
  }
  const int ow = ow0 + li;
  const bool valid = ow < 56;
  f4_t bias[2], gam[2], ssum[2], ssq[2];
  bias[0] = *reinterpret_cast<const f4_t*>(b3 + ch * 32 + 4 * g);
  bias[1] = *reinterpret_cast<const f4_t*>(b3 + ch * 32 + 16 + 4 * g);
  gam[0]  = *reinterpret_cast<const f4_t*>(g3 + ch * 32 + 4 * g);
  gam[1]  = *reinterpret_cast<const f4_t*>(g3 + ch * 32 + 16 + 4 * g);
  ssum[0] = (f4_t)0.f; ssum[1] = (f4_t)0.f; ssq[0] = (f4_t)0.f; ssq[1] = (f4_t)0.f;
  #pragma unroll
  for (int r = 0; r < 4; ++r)
    #pragma unroll
    for (int c2 = 0; c2 < 2; ++c2) {
      acc[r][c2] += bias[c2];
      if (valid) {
        ssum[c2] += acc[r][c2];
        ssq[c2] += acc[r][c2] * acc[r][c2];
      }
    }
  #pragma unroll
  for (int msk = 1; msk < 16; msk <<= 1)
    #pragma unroll
    for (int c2 = 0; c2 < 2; ++c2)
      #pragma unroll
      for (int j = 0; j < 4; ++j) {
        ssum[c2][j] += __shfl_xor(ssum[c2][j], msk);
        ssq[c2][j]  += __shfl_xor(ssq[c2][j], msk);
      }
  if (li == 0) {
    const int slot = (((n * 7 + (int)blockIdx.y) * 4 + (int)blockIdx.x)) * 2 + rh;  // 3584
    #pragma unroll
    for (int c2 = 0; c2 < 2; ++c2)
      #pragma unroll
      for (int j = 0; j < 4; ++j) {
        const int co = ch * 32 + c2 * 16 + 4 * g + j;
        part[(size_t)(co * 2 + 0) * 3584 + slot] = ssum[c2][j];
        part[(size_t)(co * 2 + 1) * 3584 + slot] = ssq[c2][j];
      }
  }
  const int pob = 4 * (int)blockIdx.y + 2 * rh;
  const int qo = 8 * (int)blockIdx.x + (li >> 1);
  #pragma unroll
  for (int rp = 0; rp < 2; ++rp)
    #pragma unroll
    for (int c2 = 0; c2 < 2; ++c2) {
      f4_t v;
      #pragma unroll
      for (int j = 0; j < 4; ++j) {
        const float a = acc[2 * rp][c2][j], b = acc[2 * rp + 1][c2][j];
        v[j] = (gam[c2][j] >= 0.f) ? fmaxf(a, b) : fminf(a, b);
      }
      f4_t o;
      #pragma unroll
      for (int j = 0; j < 4; ++j) o[j] = __shfl_xor(v[j], 1);
      if (((li & 1) == 0) && (ow + 1 < 56)) {
        u16 pk[4];
        #pragma unroll
        for (int j = 0; j < 4; ++j)
          pk[j] = f2bf((gam[c2][j] >= 0.f) ? fmaxf(v[j], o[j]) : fminf(v[j], o[j]));
        const size_t off = ((size_t)((n * 28 + pob + rp) * 28 + qo)) * 64 + ch * 32 + c2 * 16 + 4 * g;
        uint2 w;
        w.x = (u32)pk[0] | ((u32)pk[1] << 16);
        w.y = (u32)pk[2] | ((u32)pk[3] << 16);
        *reinterpret_cast<uint2*>(sel3 + off) = w;
      }
    }
}

// ------------- bnrelu3 + NHWC->NCHW transpose for fc1 -----------------------
__global__ __launch_bounds__(256)
void k_bnrelu3t(const u16* __restrict__ sel3, const float* __restrict__ scale,
                const float* __restrict__ shift, u16* __restrict__ x3t) {
  const int n = blockIdx.y;
  const int c = threadIdx.x & 63, pq = threadIdx.x >> 6;
  const int po = blockIdx.x * 4 + pq;
  const float sc = scale[c], sh = shift[c];
  const size_t row0 = ((size_t)(n * 28 + po)) * 28 * 64 + c;
  #pragma unroll
  for (int q4 = 0; q4 < 7; ++q4) {
    u16 pk[4];
    #pragma unroll
    for (int i = 0; i < 4; ++i) {
      const int qo = q4 * 4 + i;
      const u16 raw = sel3[row0 + (size_t)qo * 64];
      pk[i] = f2bf(fmaxf(fmaf(bf2f(raw), sc, sh), 0.f));
    }
    uint2 w;
    w.x = (u32)pk[0] | ((u32)pk[1] << 16);
    w.y = (u32)pk[2] | ((u32)pk[3] << 16);
    *reinterpret_cast<uint2*>(x3t + (((size_t)(n * 64 + c) * 28 + po) * 28 + q4 * 4)) = w;
  }
}

// ------------- fc1: zero-LDS MFMA K-split GEMM (56 splits x 896 k) ----------
__global__ __launch_bounds__(256)
void k_fc1(const u16* __restrict__ x3t, const float* __restrict__ w,
           float* __restrict__ partial) {
  const int kc = blockIdx.x, nt = blockIdx.y;
  const int t = threadIdx.x, lane = t & 63, wv = t >> 6;
  const int g = lane >> 4, li = lane & 15;
  const int n0 = nt * 64 + wv * 16;
  const float* wrow = w + (size_t)(n0 + li) * 50176 + kc * 896;
  const u16* xbase = x3t + kc * 896;
  f4_t acc[4];
  #pragma unroll
  for (int mf = 0; mf < 4; ++mf) acc[mf] = (f4_t)0.f;
  #pragma unroll 4
  for (int ks = 0; ks < 28; ++ks) {
    const int kb = ks * 32 + g * 8;
    const float4 wa = ldg4(wrow + kb);
    const float4 wb = ldg4(wrow + kb + 4);
    float wf[8] = {wa.x, wa.y, wa.z, wa.w, wb.x, wb.y, wb.z, wb.w};
    sh8_t hi, lo;
    #pragma unroll
    for (int j = 0; j < 8; ++j) {
      const u16 h = f2bf(wf[j]);
      hi[j] = (short)h;
      lo[j] = (short)f2bf(wf[j] - bf2f(h));
    }
    #pragma unroll
    for (int mf = 0; mf < 4; ++mf) {
      const sh8_t B = *reinterpret_cast<const sh8_t*>(
          xbase + (size_t)(mf * 16 + li) * 50176 + kb);
      acc[mf] = __builtin_amdgcn_mfma_f32_16x16x32_bf16(hi, B, acc[mf], 0, 0, 0);
      acc[mf] = __builtin_amdgcn_mfma_f32_16x16x32_bf16(lo, B, acc[mf], 0, 0, 0);
    }
  }
  float* pb = partial + (size_t)kc * 16384;
  #pragma unroll
  for (int mf = 0; mf < 4; ++mf)
    #pragma unroll
    for (int j = 0; j < 4; ++j)
      pb[(size_t)(n0 + 4 * g + j) * 64 + mf * 16 + li] = acc[mf][j];
}

__global__ __launch_bounds__(256)
void k_fc1_reduce(const float* __restrict__ partial, const float* __restrict__ b1f,
                  float* __restrict__ h1) {
  const int idx = blockIdx.x * 256 + threadIdx.x;  // 16384
  const int nn = idx >> 6, m = idx & 63;
  float a[8];
  #pragma unroll
  for (int u = 0; u < 8; ++u) a[u] = 0.f;
  #pragma unroll
  for (int k = 0; k < 56; k += 8)
    #pragma unroll
    for (int u = 0; u < 8; ++u)
      a[u] += partial[(size_t)(k + u) * 16384 + idx];
  const float s = b1f[nn] + (((a[0] + a[1]) + (a[2] + a[3])) +
                             ((a[4] + a[5]) + (a[6] + a[7])));
  h1[(size_t)m * 256 + nn] = fmaxf(s, 0.f);
}

__global__ __launch_bounds__(320)
void k_fc2(const float* __restrict__ h1, const float* __restrict__ w2f,
           const float* __restrict__ b2f, float* __restrict__ out) {
  const int t = threadIdx.x;
  const int m = t / 5, o = t - m * 5;
  const float* hr = h1 + (size_t)m * 256;
  const float* wr = w2f + (size_t)o * 256;
  float a0 = 0.f, a1 = 0.f, a2 = 0.f, a3 = 0.f;
  #pragma unroll
  for (int j = 0; j < 256; j += 16) {
    const float4 h0 = ldg4(hr + j),      w0 = ldg4(wr + j);
    const float4 h1v = ldg4(hr + j + 4),  w1v = ldg4(wr + j + 4);
    const float4 h2 = ldg4(hr + j + 8),  w2 = ldg4(wr + j + 8);
    const float4 h3 = ldg4(hr + j + 12), w3 = ldg4(wr + j + 12);
    a0 = fmaf(h0.x, w0.x, fmaf(h0.y, w0.y, fmaf(h0.z, w0.z, fmaf(h0.w, w0.w, a0))));
    a1 = fmaf(h1v.x, w1v.x, fmaf(h1v.y, w1v.y, fmaf(h1v.z, w1v.z, fmaf(h1v.w, w1v.w, a1))));
    a2 = fmaf(h2.x, w2.x, fmaf(h2.y, w2.y, fmaf(h2.z, w2.z, fmaf(h2.w, w2.w, a2))));
    a3 = fmaf(h3.x, w3.x, fmaf(h3.y, w3.y, fmaf(h3.z, w3.z, fmaf(h3.w, w3.w, a3))));
  }
  out[m * 5 + o] = b2f[o] + ((a0 + a1) + (a2 + a3));
}

// ---------------------------------------------------------------------------
extern "C" void kernel_launch(void* const* d_in, const int* in_sizes, int n_in,
                              void* d_out, int out_size, void* d_ws, size_t ws_size,
                              hipStream_t stream) {
  (void)in_sizes; (void)n_in; (void)out_size; (void)ws_size;
  const float* d   = (const float*)d_in[0];
  const float* w1  = (const float*)d_in[1];
  const float* b1  = (const float*)d_in[2];
  const float* g1  = (const float*)d_in[3];
  const float* be1 = (const float*)d_in[4];
  const float* w2  = (const float*)d_in[5];
  const float* b2  = (const float*)d_in[6];
  const float* g2  = (const float*)d_in[7];
  const float* be2 = (const float*)d_in[8];
  const float* w3  = (const float*)d_in[9];
  const float* b3  = (const float*)d_in[10];
  const float* g3  = (const float*)d_in[11];
  const float* be3 = (const float*)d_in[12];
  const float* fw1 = (const float*)d_in[13];
  const float* fb1 = (const float*)d_in[14];
  const float* fw2 = (const float*)d_in[15];
  const float* fb2 = (const float*)d_in[16];
  float* out = (float*)d_out;
  float* ws  = (float*)d_ws;

  u16* sel1 = (u16*)(ws + WS_SEL1);
  u16* sel2 = (u16*)(ws + WS_SEL2);
  u16* x3t  = (u16*)(ws + WS_X3T);
  u16* sel3 = (u16*)(ws + WS_SEL3);
  u16* wt1  = (u16*)(ws + WS_WT1);
  u16* wt2  = (u16*)(ws + WS_WT2);
  u16* wt3  = (u16*)(ws + WS_WT3);
  float* p1 = ws + WS_P1;
  float* p2 = ws + WS_P2;
  float* p3 = ws + WS_P3;
  double* pd = (double*)(ws + WS_PD);
  float* st = ws + WS_ST;
  float* fcp = ws + WS_FCP;
  float* h1 = ws + WS_H1;

  k_prep_w<<<100, 256, 0, stream>>>(w1, w2, w3, wt1, wt2, wt3);
  // layer 1: conv (stats + sel pool), BN finalize
  k_conv1<<<dim3(15, 15, 64), 256, 0, stream>>>(d, wt1, b1, g1, sel1, p1);
  k_fin1<<<dim3(16, 64), 256, 0, stream>>>(p1, 57600, 900, 64, pd);
  k_fin2<<<16, 64, 0, stream>>>(pd, 64, 3240000.0, g1, be1, st + 0, st + 16);
  // layer 2 (BN1 applied inline during staging)
  k_conv2<<<dim3(7, 7, 64), 256, 0, stream>>>(sel1, st + 0, wt2, b2, g2, sel2, p2);
  k_fin1<<<dim3(32, 16), 256, 0, stream>>>(p2, 12544, 784, 16, pd);
  k_fin2<<<32, 64, 0, stream>>>(pd, 16, 802816.0, g2, be2, st + 32, st + 64);
  // layer 3 (BN2 applied inline during staging)
  k_conv3<<<dim3(4, 7, 64), 256, 0, stream>>>(sel2, st + 32, wt3, b3, g3, sel3, p3);
  k_fin1<<<dim3(64, 8), 256, 0, stream>>>(p3, 3584, 448, 8, pd);
  k_fin2<<<64, 64, 0, stream>>>(pd, 8, 200704.0, g3, be3, st + 96, st + 160);
  k_bnrelu3t<<<dim3(7, 64), 256, 0, stream>>>(sel3, st + 96, st + 160, x3t);
  // fc
  k_fc1<<<dim3(56, 4), 256, 0, stream>>>(x3t, fw1, fcp);
  k_fc1_reduce<<<64, 256, 0, stream>>>(fcp, fb1, h1);
  k_fc2<<<1, 320, 0, stream>>>(h1, fw2, fb2, out);
}

// Round 15
// 160.892 us; speedup vs baseline: 1.3298x; 1.0608x over previous
//
#include <hip/hip_runtime.h>
#include <cstdint>
#include <cstddef>

// ---------------------------------------------------------------------------
// Plant_Identifier CNN forward.
// R15: all bf16 conversions through v_cvt_pk_bf16_f32 (HW RNE, bit-identical
//      to the manual f2bf) — conv1 B-build, pool packs, BN-inline staging,
//      fc1 hi/lo split. Bias folded into MFMA acc init. conv1 was pure
//      VALU-issue-bound (63% busy, ~800 inst/wave) on manual conversions.
// R14: bnrelu1/2 folded into next conv's staging; R10 sel-trick; fused conv1.
// conv2/3: bf16 MFMA implicit-GEMM, fused stats + sel pool, BN-inline stage.
// fc1: zero-LDS MFMA K-split. All reductions deterministic.
// ---------------------------------------------------------------------------

typedef __attribute__((ext_vector_type(8))) short sh8_t;   // 8 x bf16
typedef __attribute__((ext_vector_type(4))) float f4_t;    // mfma acc
typedef unsigned short u16;
typedef unsigned int u32;

// workspace layout (float units) — no aliasing
#define WS_SEL1 ((size_t)0)          // sel1 bf16 [64,112,112,16] (6,422,528)
#define WS_SEL2 ((size_t)6422528)    // sel2 bf16 [64,56,56,32]   (3,211,264)
#define WS_X3T  ((size_t)9633792)    // x3t  bf16 [64,64,28,28]   (1,605,632)
#define WS_SEL3 ((size_t)11239424)   // sel3 bf16 [64,28,28,64]   (1,605,632)
#define WS_WT1  ((size_t)12845056)   // 512
#define WS_WT2  ((size_t)12845568)   // 3,072
#define WS_WT3  ((size_t)12848640)   // 9,216
#define WS_P1   ((size_t)12857856)   // 16*2*57600 = 1,843,200
#define WS_P2   ((size_t)14701056)   // 32*2*12544 = 802,816
#define WS_P3   ((size_t)15503872)   // 64*2*3584  = 458,752
#define WS_PD   ((size_t)15962624)   // 4,096
#define WS_ST   ((size_t)15966720)   // 224
#define WS_FCP  ((size_t)15966944)   // 917,504
#define WS_H1   ((size_t)16884448)   // 16,384
// total 16,900,832 floats = 67.6 MB

static __device__ __forceinline__ float4 ldg4(const float* p) {
  return *reinterpret_cast<const float4*>(p);
}
static __device__ __forceinline__ float bf2f(u16 u) {
  union { u32 i; float f; } c; c.i = ((u32)u) << 16; return c.f;
}
static __device__ __forceinline__ u16 f2bf(float f) {
  union { float f; u32 i; } c; c.f = f;
  const u32 x = c.i;
  return (u16)((x + 0x7fffu + ((x >> 16) & 1u)) >> 16);   // RNE (host-side prep)
}
// HW packed f32->bf16 (RNE): dst.lo = bf16(a), dst.hi = bf16(b)
static __device__ __forceinline__ u32 cvtpk(float a, float b) {
  u32 r;
  asm("v_cvt_pk_bf16_f32 %0, %1, %2" : "=v"(r) : "v"(a), "v"(b));
  return r;
}
static __device__ __forceinline__ float asf(u32 u) {
  union { u32 i; float f; } c; c.i = u; return c.f;
}

// ---------------- weight prep -----------------------------------------------
__global__ __launch_bounds__(256)
void k_prep_w(const float* __restrict__ w1, const float* __restrict__ w2,
              const float* __restrict__ w3, u16* __restrict__ wt1,
              u16* __restrict__ wt2, u16* __restrict__ wt3) {
  const int t = blockIdx.x * 256 + threadIdx.x;  // 25600 total
  if (t < 1024) {
    const int half = t >> 9;
    const int u = t & 511;
    const int co = u >> 5, k = u & 31;
    const int g = k >> 3, j = k & 7;
    const int kh = g >> 1, kw = g & 1;
    const int ci = (j < 4) ? j : j - 4;
    bool active = (j != 3) && (j != 7);
    if (half == 1) active = active && (j < 4);
    float val = 0.f;
    if (active) {
      const float w = w1[((co * 3 + ci) * 2 + kh) * 2 + kw];
      const u16 h = f2bf(w);
      val = (half == 0) ? bf2f(h) : (w - bf2f(h));
    }
    wt1[t] = f2bf(val);
  } else if (t < 7168) {  // wt2 [co32][kh3][kwp4][ci16], kw=3 zero-padded
    const int u = t - 1024;
    const int ci = u & 15, kwp = (u >> 4) & 3, kh = (u >> 6) % 3, co = u / 192;
    float v = 0.f;
    if (kwp < 3) v = w2[((co * 16 + ci) * 3 + kh) * 3 + kwp];
    wt2[u] = f2bf(v);
  } else {                // wt3 [co64][kh3][kw3][ci32]
    const int u = t - 7168;
    const int ci = u & 31, kw = (u >> 5) % 3, kh = (u / 96) % 3, co = u / 288;
    wt3[u] = f2bf(w3[((co * 32 + ci) * 3 + kh) * 3 + kw]);
  }
}

// ---------------- conv1 MFMA: in-register B build, stats + sel pool ---------
// grid (15,15,64), 256 thr. 16x16 output tile of the 225x225 pre-pool map.
__global__ __launch_bounds__(256)
void k_conv1(const float* __restrict__ d, const u16* __restrict__ wt1,
             const float* __restrict__ b1, const float* __restrict__ g1,
             u16* __restrict__ sel1, float* __restrict__ part) {
  const int bx = blockIdx.x, by = blockIdx.y, n = blockIdx.z;
  const int ow0 = bx * 16, oh0 = by * 16;
  const int t = threadIdx.x, lane = t & 63, wv = t >> 6;
  const int g = lane >> 4, li = lane & 15;
  const int kh = g >> 1, kw = g & 1;
  const sh8_t A1 = *reinterpret_cast<const sh8_t*>(wt1 + li * 32 + g * 8);
  const sh8_t A2 = *reinterpret_cast<const sh8_t*>(wt1 + 512 + li * 32 + g * 8);
  const f4_t bias = *reinterpret_cast<const f4_t*>(b1 + 4 * g);
  const f4_t gam  = *reinterpret_cast<const f4_t*>(g1 + 4 * g);
  const int iw = ow0 + li + kw - 1;
  const bool iwv = (unsigned)iw < 224u;
  const float* dbase = d + (size_t)n * 3 * 50176 + iw;
  f4_t acc[4];
  #pragma unroll
  for (int r = 0; r < 4; ++r) acc[r] = bias;   // bias folded into C init
  #pragma unroll
  for (int r = 0; r < 4; ++r) {
    const int ih = oh0 + wv * 4 + r + kh - 1;
    float v0 = 0.f, v1 = 0.f, v2 = 0.f;
    if (iwv && (unsigned)ih < 224u) {
      const float* p = dbase + (size_t)ih * 224;
      v0 = p[0]; v1 = p[50176]; v2 = p[100352];
    }
    union { sh8_t v; u32 w[4]; } B;
    B.w[0] = cvtpk(v0, v1);
    B.w[1] = cvtpk(v2, 0.f);
    const float h0 = asf(B.w[0] << 16);
    const float h1 = asf(B.w[0] & 0xffff0000u);
    const float h2 = asf(B.w[1] << 16);
    B.w[2] = cvtpk(v0 - h0, v1 - h1);
    B.w[3] = cvtpk(v2 - h2, 0.f);
    acc[r] = __builtin_amdgcn_mfma_f32_16x16x32_bf16(A1, B.v, acc[r], 0, 0, 0);
    acc[r] = __builtin_amdgcn_mfma_f32_16x16x32_bf16(A2, B.v, acc[r], 0, 0, 0);
  }
  // D: col = li (pixel ow), row = 4g+j (co). y = acc (bias pre-added).
  const int ow = ow0 + li;
  // stats over valid 225x225
  {
    f4_t ssum = (f4_t)0.f, ssq = (f4_t)0.f;
    #pragma unroll
    for (int r = 0; r < 4; ++r) {
      const int oh = oh0 + wv * 4 + r;
      if (oh <= 224 && ow <= 224) { ssum += acc[r]; ssq += acc[r] * acc[r]; }
    }
    #pragma unroll
    for (int m = 1; m < 16; m <<= 1)
      #pragma unroll
      for (int j = 0; j < 4; ++j) {
        ssum[j] += __shfl_xor(ssum[j], m);
        ssq[j]  += __shfl_xor(ssq[j], m);
      }
    if (li == 0) {
      const int slot = ((n * 15 + by) * 15 + bx) * 4 + wv;  // P1 = 57600
      #pragma unroll
      for (int j = 0; j < 4; ++j) {
        part[(size_t)((4 * g + j) * 2 + 0) * 57600 + slot] = ssum[j];
        part[(size_t)((4 * g + j) * 2 + 1) * 57600 + slot] = ssq[j];
      }
    }
  }
  // sel pool: per channel, window extremum matching sign(gamma)
  if (bx < 14 && by < 14) {
    #pragma unroll
    for (int rp = 0; rp < 2; ++rp) {
      f4_t v;
      #pragma unroll
      for (int j = 0; j < 4; ++j) {
        const float a = acc[2 * rp][j], b = acc[2 * rp + 1][j];
        v[j] = (gam[j] >= 0.f) ? fmaxf(a, b) : fminf(a, b);
      }
      f4_t o;
      #pragma unroll
      for (int j = 0; j < 4; ++j) o[j] = __shfl_xor(v[j], 1);
      if ((li & 1) == 0) {
        float m[4];
        #pragma unroll
        for (int j = 0; j < 4; ++j)
          m[j] = (gam[j] >= 0.f) ? fmaxf(v[j], o[j]) : fminf(v[j], o[j]);
        const int po = 8 * by + 2 * wv + rp, qo = 8 * bx + (li >> 1);
        const size_t off = ((size_t)((n * 112 + po) * 112 + qo)) * 16 + 4 * g;
        uint2 w;
        w.x = cvtpk(m[0], m[1]);
        w.y = cvtpk(m[2], m[3]);
        *reinterpret_cast<uint2*>(sel1 + off) = w;
      }
    }
  }
}

// ------------- BN finalize stage 1: parallel chunk reduce -------------------
__global__ __launch_bounds__(256)
void k_fin1(const float* __restrict__ part, int P, int chunk, int S,
            double* __restrict__ p2) {
  const int c = blockIdx.x, s = blockIdx.y;
  const int start = s * chunk;
  const int end = min(P, start + chunk);
  __shared__ double rs[256], rq[256];
  double accs[2];
  #pragma unroll
  for (int mom = 0; mom < 2; ++mom) {
    const float* base = part + (size_t)(c * 2 + mom) * P;
    double a0 = 0.0, a1 = 0.0, a2 = 0.0, a3 = 0.0;
    int i = start + threadIdx.x * 4;
    for (; i + 3 < end; i += 1024) {
      const float4 v = ldg4(base + i);
      a0 += v.x; a1 += v.y; a2 += v.z; a3 += v.w;
    }
    for (int j = i; j < end && j < i + 4; ++j) a0 += base[j];
    accs[mom] = (a0 + a1) + (a2 + a3);
  }
  rs[threadIdx.x] = accs[0]; rq[threadIdx.x] = accs[1];
  __syncthreads();
  for (int off = 128; off > 0; off >>= 1) {
    if (threadIdx.x < off) {
      rs[threadIdx.x] += rs[threadIdx.x + off];
      rq[threadIdx.x] += rq[threadIdx.x + off];
    }
    __syncthreads();
  }
  if (threadIdx.x == 0) {
    p2[(size_t)(c * 2 + 0) * S + s] = rs[0];
    p2[(size_t)(c * 2 + 1) * S + s] = rq[0];
  }
}

// ------------- BN finalize stage 2 ------------------------------------------
__global__ __launch_bounds__(64)
void k_fin2(const double* __restrict__ p2, int S, double count,
            const float* __restrict__ g, const float* __restrict__ bta,
            float* __restrict__ scale, float* __restrict__ shift) {
  const int c = blockIdx.x, t = threadIdx.x;
  double s = 0.0, sq = 0.0;
  if (t < S) {
    s  = p2[(size_t)(c * 2 + 0) * S + t];
    sq = p2[(size_t)(c * 2 + 1) * S + t];
  }
  #pragma unroll
  for (int m = 1; m < 64; m <<= 1) {
    s  += __shfl_xor(s, m);
    sq += __shfl_xor(sq, m);
  }
  if (t == 0) {
    const double mean = s / count;
    const double var  = sq / count - mean * mean;
    const double rstd = 1.0 / sqrt(var + 1e-5);
    const double sc = (double)g[c] * rstd;
    scale[c] = (float)sc;
    shift[c] = (float)((double)bta[c] - mean * sc);
  }
}

// ------------- conv2: BN1-inline staging + bf16 MFMA + stats + sel pool -----
// bn1: scale at bn1[0..15], shift at bn1[16..31].
__global__ __launch_bounds__(256)
void k_conv2(const u16* __restrict__ sel1, const float* __restrict__ bn1,
             const u16* __restrict__ wt2, const float* __restrict__ b2,
             const float* __restrict__ g2, u16* __restrict__ sel2,
             float* __restrict__ part) {
  const int ow0 = blockIdx.x * 16, oh0 = blockIdx.y * 16, n = blockIdx.z;
  const int t = threadIdx.x, lane = t & 63, wv = t >> 6;
  const int g = lane >> 4, li = lane & 15;
  __shared__ __align__(16) unsigned char tile[18 * 640];
  for (int idx = t; idx < 720; idx += 256) {
    const int rr = idx / 40, rem = idx - rr * 40, p = rem >> 1, c = rem & 1;
    const int ih = oh0 - 1 + rr, iw = ow0 - 1 + p;
    int4 v = make_int4(0, 0, 0, 0);
    if ((unsigned)ih < 112u && (unsigned)iw < 112u) {
      const int4 s = *reinterpret_cast<const int4*>(
          sel1 + ((size_t)((n * 112 + ih) * 112 + iw) * 16 + c * 8));
      const u32* a = reinterpret_cast<const u32*>(&s);
      const float4 scA = ldg4(bn1 + c * 8),      scB = ldg4(bn1 + c * 8 + 4);
      const float4 shA = ldg4(bn1 + 16 + c * 8), shB = ldg4(bn1 + 16 + c * 8 + 4);
      const float sc[8] = {scA.x, scA.y, scA.z, scA.w, scB.x, scB.y, scB.z, scB.w};
      const float sh[8] = {shA.x, shA.y, shA.z, shA.w, shB.x, shB.y, shB.z, shB.w};
      float f[8];
      #pragma unroll
      for (int j = 0; j < 8; ++j) {
        const u16 raw = (u16)(a[j >> 1] >> ((j & 1) * 16));
        f[j] = fmaxf(fmaf(bf2f(raw), sc[j], sh[j]), 0.f);
      }
      v.x = cvtpk(f[0], f[1]);
      v.y = cvtpk(f[2], f[3]);
      v.z = cvtpk(f[4], f[5]);
      v.w = cvtpk(f[6], f[7]);
    }
    *reinterpret_cast<int4*>(tile + ((rr * 640 + p * 32 + c * 16) ^ (((p >> 2) & 1) << 4))) = v;
  }
  sh8_t W[2][3][2];
  #pragma unroll
  for (int cot = 0; cot < 2; ++cot)
    #pragma unroll
    for (int kh = 0; kh < 3; ++kh)
      #pragma unroll
      for (int m = 0; m < 2; ++m)
        W[cot][kh][m] = *reinterpret_cast<const sh8_t*>(
            wt2 + ((cot * 16 + li) * 192 + kh * 64 + m * 32 + g * 8));
  f4_t bias[2], gam[2];
  bias[0] = *reinterpret_cast<const f4_t*>(b2 + 4 * g);
  bias[1] = *reinterpret_cast<const f4_t*>(b2 + 16 + 4 * g);
  gam[0]  = *reinterpret_cast<const f4_t*>(g2 + 4 * g);
  gam[1]  = *reinterpret_cast<const f4_t*>(g2 + 16 + 4 * g);
  f4_t acc[4][2];
  #pragma unroll
  for (int r = 0; r < 4; ++r) { acc[r][0] = bias[0]; acc[r][1] = bias[1]; }
  __syncthreads();
  const int rowb = 4 * wv;
  #pragma unroll
  for (int ihr = 0; ihr < 6; ++ihr) {
    const int row = rowb + ihr;
    #pragma unroll
    for (int m = 0; m < 2; ++m) {
      const int p = li + 2 * m + (g >> 1);
      const sh8_t B = *reinterpret_cast<const sh8_t*>(
          tile + ((row * 640 + p * 32 + (g & 1) * 16) ^ (((p >> 2) & 1) << 4)));
      #pragma unroll
      for (int kh = 0; kh < 3; ++kh) {
        const int r = ihr - kh;
        if (r >= 0 && r < 4) {
          acc[r][0] = __builtin_amdgcn_mfma_f32_16x16x32_bf16(W[0][kh][m], B, acc[r][0], 0, 0, 0);
          acc[r][1] = __builtin_amdgcn_mfma_f32_16x16x32_bf16(W[1][kh][m], B, acc[r][1], 0, 0, 0);
        }
      }
    }
  }
  f4_t ssum[2], ssq[2];
  ssum[0] = (f4_t)0.f; ssum[1] = (f4_t)0.f; ssq[0] = (f4_t)0.f; ssq[1] = (f4_t)0.f;
  #pragma unroll
  for (int r = 0; r < 4; ++r)
    #pragma unroll
    for (int cot = 0; cot < 2; ++cot) {
      ssum[cot] += acc[r][cot];
      ssq[cot] += acc[r][cot] * acc[r][cot];
    }
  #pragma unroll
  for (int msk = 1; msk < 16; msk <<= 1)
    #pragma unroll
    for (int cot = 0; cot < 2; ++cot)
      #pragma unroll
      for (int j = 0; j < 4; ++j) {
        ssum[cot][j] += __shfl_xor(ssum[cot][j], msk);
        ssq[cot][j]  += __shfl_xor(ssq[cot][j], msk);
      }
  if (li == 0) {
    const int slot = (((n * 7 + (int)blockIdx.y) * 7 + (int)blockIdx.x)) * 4 + wv;  // 12544
    #pragma unroll
    for (int cot = 0; cot < 2; ++cot)
      #pragma unroll
      for (int j = 0; j < 4; ++j) {
        const int co = cot * 16 + 4 * g + j;
        part[(size_t)(co * 2 + 0) * 12544 + slot] = ssum[cot][j];
        part[(size_t)(co * 2 + 1) * 12544 + slot] = ssq[cot][j];
      }
  }
  const int pob = 8 * (int)blockIdx.y + 2 * wv;
  const int qo = 8 * (int)blockIdx.x + (li >> 1);
  #pragma unroll
  for (int rp = 0; rp < 2; ++rp)
    #pragma unroll
    for (int cot = 0; cot < 2; ++cot) {
      f4_t v;
      #pragma unroll
      for (int j = 0; j < 4; ++j) {
        const float a = acc[2 * rp][cot][j], b = acc[2 * rp + 1][cot][j];
        v[j] = (gam[cot][j] >= 0.f) ? fmaxf(a, b) : fminf(a, b);
      }
      f4_t o;
      #pragma unroll
      for (int j = 0; j < 4; ++j) o[j] = __shfl_xor(v[j], 1);
      if ((li & 1) == 0) {
        float m[4];
        #pragma unroll
        for (int j = 0; j < 4; ++j)
          m[j] = (gam[cot][j] >= 0.f) ? fmaxf(v[j], o[j]) : fminf(v[j], o[j]);
        const size_t off = ((size_t)((n * 56 + pob + rp) * 56 + qo)) * 32 + cot * 16 + 4 * g;
        uint2 w;
        w.x = cvtpk(m[0], m[1]);
        w.y = cvtpk(m[2], m[3]);
        *reinterpret_cast<uint2*>(sel2 + off) = w;
      }
    }
}

// ------------- conv3: BN2-inline staging + bf16 MFMA + stats + sel pool -----
// bn2: scale at bn2[0..31], shift at bn2[32..63].
__global__ __launch_bounds__(256)
void k_conv3(const u16* __restrict__ sel2, const float* __restrict__ bn2,
             const u16* __restrict__ wt3, const float* __restrict__ b3,
             const float* __restrict__ g3, u16* __restrict__ sel3,
             float* __restrict__ part) {
  const int ow0 = blockIdx.x * 16, oh0 = blockIdx.y * 8, n = blockIdx.z;
  const int t = threadIdx.x, lane = t & 63, wv = t >> 6;
  const int rh = wv & 1, ch = wv >> 1;
  const int g = lane >> 4, li = lane & 15;
  __shared__ __align__(16) unsigned char tile[10 * 1152];
  for (int idx = t; idx < 720; idx += 256) {
    const int rr = idx / 72, rem = idx - rr * 72, p = rem >> 2, c = rem & 3;
    const int ih = oh0 - 1 + rr, iw = ow0 - 1 + p;
    int4 v = make_int4(0, 0, 0, 0);
    if ((unsigned)ih < 56u && (unsigned)iw < 56u) {
      const int4 s = *reinterpret_cast<const int4*>(
          sel2 + ((size_t)((n * 56 + ih) * 56 + iw) * 32 + c * 8));
      const u32* a = reinterpret_cast<const u32*>(&s);
      const float4 scA = ldg4(bn2 + c * 8),      scB = ldg4(bn2 + c * 8 + 4);
      const float4 shA = ldg4(bn2 + 32 + c * 8), shB = ldg4(bn2 + 32 + c * 8 + 4);
      const float sc[8] = {scA.x, scA.y, scA.z, scA.w, scB.x, scB.y, scB.z, scB.w};
      const float sh[8] = {shA.x, shA.y, shA.z, shA.w, shB.x, shB.y, shB.z, shB.w};
      float f[8];
      #pragma unroll
      for (int j = 0; j < 8; ++j) {
        const u16 raw = (u16)(a[j >> 1] >> ((j & 1) * 16));
        f[j] = fmaxf(fmaf(bf2f(raw), sc[j], sh[j]), 0.f);
      }
      v.x = cvtpk(f[0], f[1]);
      v.y = cvtpk(f[2], f[3]);
      v.z = cvtpk(f[4], f[5]);
      v.w = cvtpk(f[6], f[7]);
    }
    *reinterpret_cast<int4*>(tile + ((rr * 1152 + p * 64 + c * 16) ^ (((p >> 1) & 3) << 4))) = v;
  }
  sh8_t W[2][3][3];
  #pragma unroll
  for (int c2 = 0; c2 < 2; ++c2)
    #pragma unroll
    for (int kh = 0; kh < 3; ++kh)
      #pragma unroll
      for (int kw = 0; kw < 3; ++kw)
        W[c2][kh][kw] = *reinterpret_cast<const sh8_t*>(
            wt3 + ((size_t)(ch * 32 + c2 * 16 + li) * 288 + (kh * 3 + kw) * 32 + g * 8));
  f4_t bias[2], gam[2];
  bias[0] = *reinterpret_cast<const f4_t*>(b3 + ch * 32 + 4 * g);
  bias[1] = *reinterpret_cast<const f4_t*>(b3 + ch * 32 + 16 + 4 * g);
  gam[0]  = *reinterpret_cast<const f4_t*>(g3 + ch * 32 + 4 * g);
  gam[1]  = *reinterpret_cast<const f4_t*>(g3 + ch * 32 + 16 + 4 * g);
  f4_t acc[4][2];
  #pragma unroll
  for (int r = 0; r < 4; ++r) { acc[r][0] = bias[0]; acc[r][1] = bias[1]; }
  __syncthreads();
  const int rowb = 4 * rh;
  #pragma unroll
  for (int ihr = 0; ihr < 6; ++ihr) {
    const int row = rowb + ihr;
    #pragma unroll
    for (int kw = 0; kw < 3; ++kw) {
      const int p = li + kw;
      const sh8_t B = *reinterpret_cast<const sh8_t*>(
          tile + ((row * 1152 + p * 64 + g * 16) ^ (((p >> 1) & 3) << 4)));
      #pragma unroll
      for (int kh = 0; kh < 3; ++kh) {
        const int r = ihr - kh;
        if (r >= 0 && r < 4) {
          acc[r][0] = __builtin_amdgcn_mfma_f32_16x16x32_bf16(W[0][kh][kw], B, acc[r][0], 0, 0, 0);
          acc[r][1] = __builtin_amdgcn_mfma_f32_16x16x32_bf16(W[1][kh][kw], B, acc[r][1], 0, 0, 0);
        }
      }
    }
  }
  const int ow = ow0 + li;
  const bool valid = ow < 56;
  f4_t ssum[2], ssq[2];
  ssum[0] = (f4_t)0.f; ssum[1] = (f4_t)0.f; ssq[0] = (f4_t)0.f; ssq[1] = (f4_t)0.f;
  #pragma unroll
  for (int r = 0; r < 4; ++r)
    #pragma unroll
    for (int c2 = 0; c2 < 2; ++c2) {
      if (valid) {
        ssum[c2] += acc[r][c2];
        ssq[c2] += acc[r][c2] * acc[r][c2];
      }
    }
  #pragma unroll
  for (int msk = 1; msk < 16; msk <<= 1)
    #pragma unroll
    for (int c2 = 0; c2 < 2; ++c2)
      #pragma unroll
      for (int j = 0; j < 4; ++j) {
        ssum[c2][j] += __shfl_xor(ssum[c2][j], msk);
        ssq[c2][j]  += __shfl_xor(ssq[c2][j], msk);
      }
  if (li == 0) {
    const int slot = (((n * 7 + (int)blockIdx.y) * 4 + (int)blockIdx.x)) * 2 + rh;  // 3584
    #pragma unroll
    for (int c2 = 0; c2 < 2; ++c2)
      #pragma unroll
      for (int j = 0; j < 4; ++j) {
        const int co = ch * 32 + c2 * 16 + 4 * g + j;
        part[(size_t)(co * 2 + 0) * 3584 + slot] = ssum[c2][j];
        part[(size_t)(co * 2 + 1) * 3584 + slot] = ssq[c2][j];
      }
  }
  const int pob = 4 * (int)blockIdx.y + 2 * rh;
  const int qo = 8 * (int)blockIdx.x + (li >> 1);
  #pragma unroll
  for (int rp = 0; rp < 2; ++rp)
    #pragma unroll
    for (int c2 = 0; c2 < 2; ++c2) {
      f4_t v;
      #pragma unroll
      for (int j = 0; j < 4; ++j) {
        const float a = acc[2 * rp][c2][j], b = acc[2 * rp + 1][c2][j];
        v[j] = (gam[c2][j] >= 0.f) ? fmaxf(a, b) : fminf(a, b);
      }
      f4_t o;
      #pragma unroll
      for (int j = 0; j < 4; ++j) o[j] = __shfl_xor(v[j], 1);
      if (((li & 1) == 0) && (ow + 1 < 56)) {
        float m[4];
        #pragma unroll
        for (int j = 0; j < 4; ++j)
          m[j] = (gam[c2][j] >= 0.f) ? fmaxf(v[j], o[j]) : fminf(v[j], o[j]);
        const size_t off = ((size_t)((n * 28 + pob + rp) * 28 + qo)) * 64 + ch * 32 + c2 * 16 + 4 * g;
        uint2 w;
        w.x = cvtpk(m[0], m[1]);
        w.y = cvtpk(m[2], m[3]);
        *reinterpret_cast<uint2*>(sel3 + off) = w;
      }
    }
}

// ------------- bnrelu3 + NHWC->NCHW transpose for fc1 -----------------------
__global__ __launch_bounds__(256)
void k_bnrelu3t(const u16* __restrict__ sel3, const float* __restrict__ scale,
                const float* __restrict__ shift, u16* __restrict__ x3t) {
  const int n = blockIdx.y;
  const int c = threadIdx.x & 63, pq = threadIdx.x >> 6;
  const int po = blockIdx.x * 4 + pq;
  const float sc = scale[c], sh = shift[c];
  const size_t row0 = ((size_t)(n * 28 + po)) * 28 * 64 + c;
  #pragma unroll
  for (int q4 = 0; q4 < 7; ++q4) {
    float f[4];
    #pragma unroll
    for (int i = 0; i < 4; ++i) {
      const int qo = q4 * 4 + i;
      const u16 raw = sel3[row0 + (size_t)qo * 64];
      f[i] = fmaxf(fmaf(bf2f(raw), sc, sh), 0.f);
    }
    uint2 w;
    w.x = cvtpk(f[0], f[1]);
    w.y = cvtpk(f[2], f[3]);
    *reinterpret_cast<uint2*>(x3t + (((size_t)(n * 64 + c) * 28 + po) * 28 + q4 * 4)) = w;
  }
}

// ------------- fc1: zero-LDS MFMA K-split GEMM (56 splits x 896 k) ----------
__global__ __launch_bounds__(256)
void k_fc1(const u16* __restrict__ x3t, const float* __restrict__ w,
           float* __restrict__ partial) {
  const int kc = blockIdx.x, nt = blockIdx.y;
  const int t = threadIdx.x, lane = t & 63, wv = t >> 6;
  const int g = lane >> 4, li = lane & 15;
  const int n0 = nt * 64 + wv * 16;
  const float* wrow = w + (size_t)(n0 + li) * 50176 + kc * 896;
  const u16* xbase = x3t + kc * 896;
  f4_t acc[4];
  #pragma unroll
  for (int mf = 0; mf < 4; ++mf) acc[mf] = (f4_t)0.f;
  #pragma unroll 4
  for (int ks = 0; ks < 28; ++ks) {
    const int kb = ks * 32 + g * 8;
    const float4 wa = ldg4(wrow + kb);
    const float4 wb = ldg4(wrow + kb + 4);
    const float wf[8] = {wa.x, wa.y, wa.z, wa.w, wb.x, wb.y, wb.z, wb.w};
    union { sh8_t v; u32 w[4]; } hi, lo;
    #pragma unroll
    for (int q = 0; q < 4; ++q) hi.w[q] = cvtpk(wf[2 * q], wf[2 * q + 1]);
    #pragma unroll
    for (int q = 0; q < 4; ++q) {
      const float he = asf(hi.w[q] << 16);
      const float ho = asf(hi.w[q] & 0xffff0000u);
      lo.w[q] = cvtpk(wf[2 * q] - he, wf[2 * q + 1] - ho);
    }
    #pragma unroll
    for (int mf = 0; mf < 4; ++mf) {
      const sh8_t B = *reinterpret_cast<const sh8_t*>(
          xbase + (size_t)(mf * 16 + li) * 50176 + kb);
      acc[mf] = __builtin_amdgcn_mfma_f32_16x16x32_bf16(hi.v, B, acc[mf], 0, 0, 0);
      acc[mf] = __builtin_amdgcn_mfma_f32_16x16x32_bf16(lo.v, B, acc[mf], 0, 0, 0);
    }
  }
  float* pb = partial + (size_t)kc * 16384;
  #pragma unroll
  for (int mf = 0; mf < 4; ++mf)
    #pragma unroll
    for (int j = 0; j < 4; ++j)
      pb[(size_t)(n0 + 4 * g + j) * 64 + mf * 16 + li] = acc[mf][j];
}

__global__ __launch_bounds__(256)
void k_fc1_reduce(const float* __restrict__ partial, const float* __restrict__ b1f,
                  float* __restrict__ h1) {
  const int idx = blockIdx.x * 256 + threadIdx.x;  // 16384
  const int nn = idx >> 6, m = idx & 63;
  float a[8];
  #pragma unroll
  for (int u = 0; u < 8; ++u) a[u] = 0.f;
  #pragma unroll
  for (int k = 0; k < 56; k += 8)
    #pragma unroll
    for (int u = 0; u < 8; ++u)
      a[u] += partial[(size_t)(k + u) * 16384 + idx];
  const float s = b1f[nn] + (((a[0] + a[1]) + (a[2] + a[3])) +
                             ((a[4] + a[5]) + (a[6] + a[7])));
  h1[(size_t)m * 256 + nn] = fmaxf(s, 0.f);
}

__global__ __launch_bounds__(320)
void k_fc2(const float* __restrict__ h1, const float* __restrict__ w2f,
           const float* __restrict__ b2f, float* __restrict__ out) {
  const int t = threadIdx.x;
  const int m = t / 5, o = t - m * 5;
  const float* hr = h1 + (size_t)m * 256;
  const float* wr = w2f + (size_t)o * 256;
  float a0 = 0.f, a1 = 0.f, a2 = 0.f, a3 = 0.f;
  #pragma unroll
  for (int j = 0; j < 256; j += 16) {
    const float4 h0 = ldg4(hr + j),      w0 = ldg4(wr + j);
    const float4 h1v = ldg4(hr + j + 4),  w1v = ldg4(wr + j + 4);
    const float4 h2 = ldg4(hr + j + 8),  w2 = ldg4(wr + j + 8);
    const float4 h3 = ldg4(hr + j + 12), w3 = ldg4(wr + j + 12);
    a0 = fmaf(h0.x, w0.x, fmaf(h0.y, w0.y, fmaf(h0.z, w0.z, fmaf(h0.w, w0.w, a0))));
    a1 = fmaf(h1v.x, w1v.x, fmaf(h1v.y, w1v.y, fmaf(h1v.z, w1v.z, fmaf(h1v.w, w1v.w, a1))));
    a2 = fmaf(h2.x, w2.x, fmaf(h2.y, w2.y, fmaf(h2.z, w2.z, fmaf(h2.w, w2.w, a2))));
    a3 = fmaf(h3.x, w3.x, fmaf(h3.y, w3.y, fmaf(h3.z, w3.z, fmaf(h3.w, w3.w, a3))));
  }
  out[m * 5 + o] = b2f[o] + ((a0 + a1) + (a2 + a3));
}

// ---------------------------------------------------------------------------
extern "C" void kernel_launch(void* const* d_in, const int* in_sizes, int n_in,
                              void* d_out, int out_size, void* d_ws, size_t ws_size,
                              hipStream_t stream) {
  (void)in_sizes; (void)n_in; (void)out_size; (void)ws_size;
  const float* d   = (const float*)d_in[0];
  const float* w1  = (const float*)d_in[1];
  const float* b1  = (const float*)d_in[2];
  const float* g1  = (const float*)d_in[3];
  const float* be1 = (const float*)d_in[4];
  const float* w2  = (const float*)d_in[5];
  const float* b2  = (const float*)d_in[6];
  const float* g2  = (const float*)d_in[7];
  const float* be2 = (const float*)d_in[8];
  const float* w3  = (const float*)d_in[9];
  const float* b3  = (const float*)d_in[10];
  const float* g3  = (const float*)d_in[11];
  const float* be3 = (const float*)d_in[12];
  const float* fw1 = (const float*)d_in[13];
  const float* fb1 = (const float*)d_in[14];
  const float* fw2 = (const float*)d_in[15];
  const float* fb2 = (const float*)d_in[16];
  float* out = (float*)d_out;
  float* ws  = (float*)d_ws;

  u16* sel1 = (u16*)(ws + WS_SEL1);
  u16* sel2 = (u16*)(ws + WS_SEL2);
  u16* x3t  = (u16*)(ws + WS_X3T);
  u16* sel3 = (u16*)(ws + WS_SEL3);
  u16* wt1  = (u16*)(ws + WS_WT1);
  u16* wt2  = (u16*)(ws + WS_WT2);
  u16* wt3  = (u16*)(ws + WS_WT3);
  float* p1 = ws + WS_P1;
  float* p2 = ws + WS_P2;
  float* p3 = ws + WS_P3;
  double* pd = (double*)(ws + WS_PD);
  float* st = ws + WS_ST;
  float* fcp = ws + WS_FCP;
  float* h1 = ws + WS_H1;

  k_prep_w<<<100, 256, 0, stream>>>(w1, w2, w3, wt1, wt2, wt3);
  // layer 1: conv (stats + sel pool), BN finalize
  k_conv1<<<dim3(15, 15, 64), 256, 0, stream>>>(d, wt1, b1, g1, sel1, p1);
  k_fin1<<<dim3(16, 64), 256, 0, stream>>>(p1, 57600, 900, 64, pd);
  k_fin2<<<16, 64, 0, stream>>>(pd, 64, 3240000.0, g1, be1, st + 0, st + 16);
  // layer 2 (BN1 applied inline during staging)
  k_conv2<<<dim3(7, 7, 64), 256, 0, stream>>>(sel1, st + 0, wt2, b2, g2, sel2, p2);
  k_fin1<<<dim3(32, 16), 256, 0, stream>>>(p2, 12544, 784, 16, pd);
  k_fin2<<<32, 64, 0, stream>>>(pd, 16, 802816.0, g2, be2, st + 32, st + 64);
  // layer 3 (BN2 applied inline during staging)
  k_conv3<<<dim3(4, 7, 64), 256, 0, stream>>>(sel2, st + 32, wt3, b3, g3, sel3, p3);
  k_fin1<<<dim3(64, 8), 256, 0, stream>>>(p3, 3584, 448, 8, pd);
  k_fin2<<<64, 64, 0, stream>>>(pd, 8, 200704.0, g3, be3, st + 96, st + 160);
  k_bnrelu3t<<<dim3(7, 64), 256, 0, stream>>>(sel3, st + 96, st + 160, x3t);
  // fc
  k_fc1<<<dim3(56, 4), 256, 0, stream>>>(x3t, fw1, fcp);
  k_fc1_reduce<<<64, 256, 0, stream>>>(fcp, fb1, h1);
  k_fc2<<<1, 320, 0, stream>>>(h1, fw2, fb2, out);
}